// Round 12
// baseline (1691.437 us; speedup 1.0000x reference)
//
#include <hip/hip_runtime.h>

using u16 = unsigned short;
using u32 = unsigned int;

#define TT 2048
#define DM 1024
#define NH 16
#define NKV 8
#define DHD 64
#define FFD 3584
#define NE 8

typedef __bf16 bf16x8 __attribute__((ext_vector_type(8)));
typedef float f32x4 __attribute__((ext_vector_type(4)));

// native casts -> v_cvt_pk_bf16_f32 (RNE, same results as bit trick)
__device__ __forceinline__ u16 f2bf(float x){
  return __builtin_bit_cast(u16, (__bf16)x);
}
__device__ __forceinline__ float bf2f(u16 h){
  return (float)__builtin_bit_cast(__bf16, h);
}
__device__ __forceinline__ f32x4 mfma16(bf16x8 a, bf16x8 b, f32x4 c){
  return __builtin_amdgcn_mfma_f32_16x16x32_bf16(a, b, c, 0, 0, 0);
}
__device__ __forceinline__ uint4 packhi8v(float4 a, float4 b){
  u16 h0=f2bf(a.x),h1=f2bf(a.y),h2=f2bf(a.z),h3=f2bf(a.w);
  u16 h4=f2bf(b.x),h5=f2bf(b.y),h6=f2bf(b.z),h7=f2bf(b.w);
  return make_uint4((u32)h0|((u32)h1<<16),(u32)h2|((u32)h3<<16),
                    (u32)h4|((u32)h5<<16),(u32)h6|((u32)h7<<16));
}
__device__ __forceinline__ uint4 packlo8v(float4 a, float4 b){
  u16 l0=f2bf(a.x-bf2f(f2bf(a.x))),l1=f2bf(a.y-bf2f(f2bf(a.y)));
  u16 l2=f2bf(a.z-bf2f(f2bf(a.z))),l3=f2bf(a.w-bf2f(f2bf(a.w)));
  u16 l4=f2bf(b.x-bf2f(f2bf(b.x))),l5=f2bf(b.y-bf2f(f2bf(b.y)));
  u16 l6=f2bf(b.z-bf2f(f2bf(b.z))),l7=f2bf(b.w-bf2f(f2bf(b.w)));
  return make_uint4((u32)l0|((u32)l1<<16),(u32)l2|((u32)l3<<16),
                    (u32)l4|((u32)l5<<16),(u32)l6|((u32)l7<<16));
}

// chunk-XOR swizzle: 16B chunk c (0..3) of row r stored at u16-offset SWC(r,c).
#define SWZR(r) ((((r)>>1) ^ ((r)>>3)) & 3)
#define SWC(r,c) ((((c) ^ SWZR(r))) * 8)

// async global->LDS, 16B per lane, LDS dest = wave-uniform base + lane*16
__device__ __forceinline__ void glds16(const u16* g, u16* l){
  __builtin_amdgcn_global_load_lds(
      (const __attribute__((address_space(1))) void*)g,
      (__attribute__((address_space(3))) void*)l,
      16, 0, 0);
}

// ---------------- embedding ----------------
__global__ __launch_bounds__(256) void k_embed(const int* __restrict__ x,
    const float* __restrict__ emb, float* __restrict__ h){
  int t = blockIdx.x;
  int d = threadIdx.x * 4;
  float4 v = *reinterpret_cast<const float4*>(emb + (size_t)x[t] * DM + d);
  *reinterpret_cast<float4*>(h + (size_t)t * DM + d) = v;
}

// ---------------- rmsnorm (split-bf16 out, or f32 out) ----------------
template<int OUTF32>
__global__ __launch_bounds__(256) void k_rmsnorm(const float* __restrict__ in,
    const float* __restrict__ w, u16* __restrict__ oh, u16* __restrict__ ol,
    float* __restrict__ of){
  int t = blockIdx.x;
  int d4 = threadIdx.x * 4;
  float4 xv = *reinterpret_cast<const float4*>(in + (size_t)t * DM + d4);
  float ss = xv.x*xv.x + xv.y*xv.y + xv.z*xv.z + xv.w*xv.w;
#pragma unroll
  for (int m = 1; m < 64; m <<= 1) ss += __shfl_xor(ss, m);
  __shared__ float sred[4];
  if ((threadIdx.x & 63) == 0) sred[threadIdx.x >> 6] = ss;
  __syncthreads();
  float tot = sred[0] + sred[1] + sred[2] + sred[3];
  float r = 1.0f / sqrtf(tot * (1.0f / DM) + 1e-5f);
  float vv[4] = {xv.x, xv.y, xv.z, xv.w};
#pragma unroll
  for (int jj = 0; jj < 4; jj++){
    float xn = (vv[jj] * r) * w[d4 + jj];
    size_t a = (size_t)t * DM + d4 + jj;
    if constexpr (OUTF32){
      of[a] = xn;
    } else {
      u16 hi = f2bf(xn);
      oh[a] = hi;
      ol[a] = f2bf(xn - bf2f(hi));
    }
  }
}

// ---------------- trig table (bit-identical to R8's in-rope math) ----------------
__global__ __launch_bounds__(256) void k_trig(float* __restrict__ ct, float* __restrict__ st){
  int idx = blockIdx.x * 256 + threadIdx.x;    // TT*32 entries
  int j = idx & 31;
  int s = idx >> 5;
  float xe = (float)j * 0.03125f;                 // exact: arange*2/64
  float yf = (float)pow(1.0e6, (double)xe);       // matches CR powf
  float fr = 1.0f / yf;
  float ang = (float)s * fr;                      // f32 mul like ref
  double ad = (double)ang;
  ct[idx] = (float)cos(ad);
  st[idx] = (float)sin(ad);
}

// ---------------- rope + split (table-driven) ----------------
template<int NHD>
__global__ __launch_bounds__(256) void k_rope(const float* __restrict__ in,
    const float* __restrict__ ct, const float* __restrict__ st,
    u16* __restrict__ oh, u16* __restrict__ ol){
  int idx = blockIdx.x * 256 + threadIdx.x;
  int j = idx & 31;
  int hd = (idx >> 5) % NHD;
  int s = idx / (32 * NHD);
  size_t base = ((size_t)s * NHD + hd) * 64 + 2 * j;
  float x1 = in[base], x2 = in[base + 1];
  int ti = (s << 5) | j;
  float c  = ct[ti];
  float sn = st[ti];
  float o1 = x1 * c - x2 * sn;
  float o2 = x1 * sn + x2 * c;
  u16 h1 = f2bf(o1), h2 = f2bf(o2);
  oh[base]     = h1; ol[base]     = f2bf(o1 - bf2f(h1));
  oh[base + 1] = h2; ol[base + 1] = f2bf(o2 - bf2f(h2));
}

// ---------------- plain f32 -> bf16 split ----------------
__global__ __launch_bounds__(256) void k_splitbuf(const float* __restrict__ in,
    u16* __restrict__ oh, u16* __restrict__ ol, int n){
  int i = blockIdx.x * 256 + threadIdx.x;
  if (i < n){
    float x = in[i];
    u16 hi = f2bf(x);
    oh[i] = hi;
    ol[i] = f2bf(x - bf2f(hi));
  }
}

// ---------------- gate + top2 ----------------
__global__ __launch_bounds__(256) void k_gate(const u16* __restrict__ xh,
    const u16* __restrict__ xl, const float* __restrict__ gw,
    int* __restrict__ topi, float* __restrict__ topw, int* __restrict__ cnt){
  int wv = threadIdx.x >> 6, lane = threadIdx.x & 63;
  int t = blockIdx.x * 4 + wv;
  float x[16];
#pragma unroll
  for (int i = 0; i < 16; i++){
    size_t a = (size_t)t * DM + lane + 64 * i;
    x[i] = bf2f(xh[a]) + bf2f(xl[a]);
  }
  float lgt[8];
#pragma unroll
  for (int e = 0; e < 8; e++){
    float s = 0.f;
#pragma unroll
    for (int i = 0; i < 16; i++) s += x[i] * gw[(size_t)e * DM + lane + 64 * i];
#pragma unroll
    for (int m = 1; m < 64; m <<= 1) s += __shfl_xor(s, m);
    lgt[e] = s;
  }
  float mx = lgt[0];
#pragma unroll
  for (int e = 1; e < 8; e++) mx = fmaxf(mx, lgt[e]);
  float p[8]; float sum = 0.f;
#pragma unroll
  for (int e = 0; e < 8; e++){ p[e] = expf(lgt[e] - mx); sum += p[e]; }
  float g[8];
#pragma unroll
  for (int e = 0; e < 8; e++) g[e] = p[e] / sum;   // match ref's top_k domain
  int t0 = 0; float b0 = g[0];
#pragma unroll
  for (int e = 1; e < 8; e++) if (g[e] > b0){ b0 = g[e]; t0 = e; }
  int t1 = -1; float b1 = -1.f;
#pragma unroll
  for (int e = 0; e < 8; e++) if (e != t0 && g[e] > b1){ b1 = g[e]; t1 = e; }
  float ssum = b0 + b1;
  float w0 = b0 / ssum, w1 = b1 / ssum;
  if (lane == 0 && t < TT){
    topi[2*t] = t0; topi[2*t+1] = t1;
    topw[2*t] = w0; topw[2*t+1] = w1;
    atomicAdd(&cnt[t0], 1);
    atomicAdd(&cnt[t1], 1);
  }
}

__global__ void k_zero8(int* cnt){ if (threadIdx.x < 8) cnt[threadIdx.x] = 0; }

__global__ void k_scan(const int* __restrict__ cnt, int* __restrict__ offp, int* __restrict__ cur){
  if (threadIdx.x == 0){
    int r = 0;
    for (int e = 0; e < 8; e++){ offp[e] = r; r += cnt[e]; }
  }
  if (threadIdx.x < 8) cur[threadIdx.x] = 0;
}

__global__ __launch_bounds__(256) void k_scatter(const int* __restrict__ topi,
    const float* __restrict__ topw, const int* __restrict__ offp, int* __restrict__ cur,
    int* __restrict__ ftok, float* __restrict__ fwt){
  int t = blockIdx.x * 256 + threadIdx.x;
  if (t < TT){
#pragma unroll
    for (int j = 0; j < 2; j++){
      int e = topi[2*t + j];
      int p = atomicAdd(&cur[e], 1);
      ftok[offp[e] + p] = t;
      fwt[offp[e] + p] = topw[2*t + j];
    }
  }
}

// ---------------- GEMM: raw-barrier schedule, A via global_load_lds (dbuf),
// B double-buffered in registers with counted vmcnt (T3/T4 minimal form) ----------------
#define GLDSA(BUF, KK) do { \
    glds16(Ah + gaA0 + (KK), (u16*)&Ash[BUF][awr0][0]); \
    glds16(Ah + gaA1 + (KK), (u16*)&Ash[BUF][awr1][0]); \
    if constexpr (SPLIT){ \
      glds16(Al + gaA0 + (KK), (u16*)&Asl[BUF][awr0][0]); \
      glds16(Al + gaA1 + (KK), (u16*)&Asl[BUF][awr1][0]); \
    } \
  } while(0)

#define GPRELOADB(S, KK) do { \
    if constexpr (BLAYOUT == 0){ \
      const float* bp_ = Bw + (size_t)(n0 + br0) * K + (KK) + cb8; \
      S##B0 = *reinterpret_cast<const float4*>(bp_); \
      S##B1 = *reinterpret_cast<const float4*>(bp_ + 4); \
      if constexpr (TN == 128){ \
        const float* bp2_ = Bw + (size_t)(n0 + br1) * K + (KK) + cb8; \
        S##B2 = *reinterpret_cast<const float4*>(bp2_); \
        S##B3 = *reinterpret_cast<const float4*>(bp2_ + 4); \
      } \
      if constexpr (DUAL){ \
        const float* bq_ = B3w + (size_t)(n0 + br0) * K + (KK) + cb8; \
        S##B2 = *reinterpret_cast<const float4*>(bq_); \
        S##B3 = *reinterpret_cast<const float4*>(bq_ + 4); \
      } \
    } else { \
      S##B0 = *reinterpret_cast<const float4*>(Bw + (size_t)((KK) + kk1) * Nq + n0 + nn1); \
      S##B1 = *reinterpret_cast<const float4*>(Bw + (size_t)((KK) + 16 + kk1) * Nq + n0 + nn1); \
    } \
  } while(0)

#define GSTOREB(S) do { \
    if constexpr (BLAYOUT == 0){ \
      *reinterpret_cast<uint4*>(&Bh1[br0][swB0]) = packhi8v(S##B0, S##B1); \
      if constexpr (SPLIT) *reinterpret_cast<uint4*>(&Bl1[br0][swB0]) = packlo8v(S##B0, S##B1); \
      if constexpr (TN == 128){ \
        *reinterpret_cast<uint4*>(&Bh1[br1][swB1]) = packhi8v(S##B2, S##B3); \
        if constexpr (SPLIT) *reinterpret_cast<uint4*>(&Bl1[br1][swB1]) = packlo8v(S##B2, S##B3); \
      } \
      if constexpr (DUAL){ \
        *reinterpret_cast<uint4*>(&Bh3[br0][swB0]) = packhi8v(S##B2, S##B3); \
        if constexpr (SPLIT) *reinterpret_cast<uint4*>(&Bl3[br0][swB0]) = packlo8v(S##B2, S##B3); \
      } \
    } else { \
      const float* q0 = reinterpret_cast<const float*>(&S##B0); \
      const float* q1 = reinterpret_cast<const float*>(&S##B1); \
      const int ch0 = kk1 >> 3, off0 = kk1 & 7; \
      _Pragma("unroll") \
      for (int j = 0; j < 4; j++){ \
        int row = nn1 + j; \
        int c0 = SWC(row, ch0) + off0; \
        int c1 = SWC(row, ch0 + 2) + off0; \
        u16 h0 = f2bf(q0[j]); \
        Bh1[row][c0] = h0; \
        if constexpr (SPLIT) Bl1[row][c0] = f2bf(q0[j] - bf2f(h0)); \
        u16 h1 = f2bf(q1[j]); \
        Bh1[row][c1] = h1; \
        if constexpr (SPLIT) Bl1[row][c1] = f2bf(q1[j] - bf2f(h1)); \
      } \
    } \
  } while(0)

// counted wait: preserve the newest NBLD loads (the other B set) in flight;
// ensures the A-glds and this step's B set are complete.
#define WAITN() do { \
    if constexpr (NBLD == 4) asm volatile("s_waitcnt vmcnt(4) lgkmcnt(0)" ::: "memory"); \
    else                     asm volatile("s_waitcnt vmcnt(2) lgkmcnt(0)" ::: "memory"); \
  } while(0)
#define WAIT0() asm volatile("s_waitcnt vmcnt(0) lgkmcnt(0)" ::: "memory")

#define MFMA_PHASE(CURB) do { \
    bf16x8 af[4], afl[4]; \
    _Pragma("unroll") \
    for (int m = 0; m < 4; m++){ \
      int Ra = wr*64 + m*16 + lr; \
      int sa = SWC(Ra, lg); \
      af[m] = *reinterpret_cast<const bf16x8*>(&Ash[CURB][Ra][sa]); \
      if constexpr (SPLIT) \
        afl[m] = *reinterpret_cast<const bf16x8*>(&Asl[CURB][Ra][sa]); \
    } \
    _Pragma("unroll") \
    for (int n = 0; n < NF; n++){ \
      int Rb = wc*(TN/2) + n*16 + lr; \
      int sb = SWC(Rb, lg); \
      bf16x8 b1 = *reinterpret_cast<const bf16x8*>(&Bh1[Rb][sb]); \
      _Pragma("unroll") \
      for (int m = 0; m < 4; m++) acc[m][n] = mfma16(af[m], b1, acc[m][n]); \
      if constexpr (SPLIT){ \
        bf16x8 bl = *reinterpret_cast<const bf16x8*>(&Bl1[Rb][sb]); \
        _Pragma("unroll") \
        for (int m = 0; m < 4; m++){ \
          acc[m][n] = mfma16(af[m], bl, acc[m][n]); \
          acc[m][n] = mfma16(afl[m], b1, acc[m][n]); \
        } \
      } \
      if constexpr (DUAL){ \
        bf16x8 b3 = *reinterpret_cast<const bf16x8*>(&Bh3[Rb][sb]); \
        _Pragma("unroll") \
        for (int m = 0; m < 4; m++) acc3[m][n] = mfma16(af[m], b3, acc3[m][n]); \
        if constexpr (SPLIT){ \
          bf16x8 b3l = *reinterpret_cast<const bf16x8*>(&Bl3[Rb][sb]); \
          _Pragma("unroll") \
          for (int m = 0; m < 4; m++){ \
            acc3[m][n] = mfma16(af[m], b3l, acc3[m][n]); \
            acc3[m][n] = mfma16(afl[m], b3, acc3[m][n]); \
          } \
        } \
      } \
    } \
  } while(0)

template<int BLAYOUT, int EPI, int SPLIT, int DUAL, int TN, int KS>
__global__ __launch_bounds__(256) void k_gemm(
    const u16* __restrict__ Ah, const u16* __restrict__ Al,
    const float* __restrict__ Bw, const float* __restrict__ B3w,
    const float* __restrict__ Bw2, const float* __restrict__ Bw3,
    size_t strideB, int N, int K,
    float* __restrict__ Cf, int ldc,
    float* __restrict__ Cf2, float* __restrict__ Cf3,
    u16* __restrict__ Ch, u16* __restrict__ Cl,
    const int* __restrict__ cntp, const int* __restrict__ offp,
    const int* __restrict__ ftok, const float* __restrict__ fwt)
{
  static_assert(!(DUAL && TN != 64), "DUAL uses TN=64");
  static_assert(!(BLAYOUT == 1 && TN != 64), "BLAYOUT=1 uses TN=64");
  constexpr int NBLD = (BLAYOUT == 0 && (DUAL || TN == 128)) ? 4 : 2;
  int cnt = TT, off = 0, ks = 0;
  if constexpr (EPI == 2 || EPI == 3){
    int e = blockIdx.z / KS;
    ks = blockIdx.z % KS;
    cnt = cntp[e]; off = offp[e];
    if ((int)blockIdx.y * 128 >= cnt) return;
    Bw += (size_t)e * strideB;
    if constexpr (DUAL) B3w += (size_t)e * strideB;
  } else if constexpr (KS > 1){
    ks = blockIdx.z;
  }
  __shared__ u16 Ash[2][128][32];                 // A hi, double-buffered
  __shared__ u16 Asl[SPLIT ? 2 : 1][SPLIT ? 128 : 1][32];
  __shared__ u16 Bh1[TN][32];
  __shared__ u16 Bl1[SPLIT ? TN : 1][32];
  __shared__ u16 Bh3[DUAL ? TN : 1][32];
  __shared__ u16 Bl3[(DUAL && SPLIT) ? TN : 1][32];

  const int tid = threadIdx.x;
  const int m0 = blockIdx.y * 128;

  // output/N selection (fused QKV uses blockIdx.x ranges)
  int n0, Nq = N, ldq = ldc;
  float* Cq = Cf;
  if constexpr (EPI == 4){
    int bx = blockIdx.x;
    if (bx < 16){       n0 = bx * 64;        Nq = 1024; ldq = 1024; Cq = Cf;  }
    else if (bx < 24){  n0 = (bx - 16) * 64; Nq = 512;  ldq = 512;  Cq = Cf2; Bw = Bw2; }
    else {              n0 = (bx - 24) * 64; Nq = 512;  ldq = 512;  Cq = Cf3; Bw = Bw3; }
  } else {
    n0 = blockIdx.x * TN;
  }

  const int wid = tid >> 6, lane = tid & 63;
  const int wr = wid >> 1, wc = wid & 1;
  const int lr = lane & 15, lg = lane >> 4;
  constexpr int NF = TN / 32;

  // A gload_lds setup: wave wid stages rows [wid*32, wid*32+32), 2 instrs of 16 rows.
  const int awr0 = wid * 32;
  const int awr1 = wid * 32 + 16;
  const int rA0 = awr0 + (lane >> 2);
  const int rA1 = awr1 + (lane >> 2);
  const int cA0 = (lane & 3) ^ SWZR(rA0);
  const int cA1 = (lane & 3) ^ SWZR(rA1);
  int grA0, grA1;
  {
    int g0 = m0 + rA0, g1 = m0 + rA1;
    if constexpr (EPI == 2){
      grA0 = ftok[off + (g0 < cnt ? g0 : cnt - 1)];
      grA1 = ftok[off + (g1 < cnt ? g1 : cnt - 1)];
    } else if constexpr (EPI == 3){
      grA0 = off + (g0 < cnt ? g0 : cnt - 1);
      grA1 = off + (g1 < cnt ? g1 : cnt - 1);
    } else {
      grA0 = g0; grA1 = g1;
    }
  }
  const size_t gaA0 = (size_t)grA0 * K + cA0 * 8;
  const size_t gaA1 = (size_t)grA1 * K + cA1 * 8;

  // B staging (BLAYOUT=0)
  const int br0 = tid >> 2;
  const int br1 = br0 + 64;
  const int cb8 = (tid & 3) * 8;
  const int swB0 = SWC(br0, tid & 3), swB1 = SWC(br1, tid & 3);
  // BLAYOUT=1 indices
  const int kk1 = tid >> 4;
  const int nn1 = (tid & 15) * 4;

  f32x4 acc[4][NF];
  f32x4 acc3[DUAL ? 4 : 1][NF];
#pragma unroll
  for (int m = 0; m < 4; m++)
#pragma unroll
    for (int n = 0; n < NF; n++){
      acc[m][n] = f32x4{0.f,0.f,0.f,0.f};
      if constexpr (DUAL) acc3[m][n] = f32x4{0.f,0.f,0.f,0.f};
    }

  // TWO named B staging sets (depth-2; no arrays, no lambdas -> no scratch)
  float4 aB0{}, aB1{}, aB2{}, aB3{};
  float4 bB0{}, bB1{}, bB2{}, bB3{};

  const int kbeg = ks * (K / KS);
  const int kend = kbeg + (K / KS);

  GLDSA(0, kbeg);                 // A(k0) -> buf0 (async)
  GPRELOADB(a, kbeg);             // B(k0) -> set a
  if (kbeg + 32 < kend) GPRELOADB(b, kbeg + 32);   // B(k0+32) -> set b
  int cur = 0;
  for (int k0 = kbeg; k0 < kend; k0 += 64){
    {
      const bool pre = (k0 + 64 < kend);
      GSTOREB(a);
      if (pre) WAITN(); else WAIT0();   // A(k) in LDS + B writes visible; other B set stays in flight
      __builtin_amdgcn_s_barrier();
      if (k0 + 32 < kend) GLDSA(cur ^ 1, k0 + 32);
      if (pre) GPRELOADB(a, k0 + 64);   // B(k+2) streams during MFMA(k) and step k+1
      MFMA_PHASE(cur);
      __builtin_amdgcn_s_barrier();
      cur ^= 1;
    }
    if (k0 + 32 < kend){
      const bool pre = (k0 + 96 < kend);
      GSTOREB(b);
      if (pre) WAITN(); else WAIT0();
      __builtin_amdgcn_s_barrier();
      if (k0 + 64 < kend) GLDSA(cur ^ 1, k0 + 64);
      if (pre) GPRELOADB(b, k0 + 96);
      MFMA_PHASE(cur);
      __builtin_amdgcn_s_barrier();
      cur ^= 1;
    }
  }

  // --- epilogue ---
#pragma unroll
  for (int m = 0; m < 4; m++)
#pragma unroll
    for (int n = 0; n < NF; n++)
#pragma unroll
      for (int r = 0; r < 4; r++){
        int row = m0 + wr*64 + m*16 + lg*4 + r;   // C/D: row=(lane>>4)*4+reg, col=lane&15 [m89]
        int col = n0 + wc*(TN/2) + n*16 + lr;
        float v = acc[m][n][r];
        if constexpr (EPI == 0){
          Cf[(size_t)row * ldc + col] = v;
        } else if constexpr (EPI == 1){
          if constexpr (KS > 1) atomicAdd(&Cf[(size_t)row * ldc + col], v);
          else                  Cf[(size_t)row * ldc + col] += v;
        } else if constexpr (EPI == 2){
          if (row < cnt){
            float a3 = acc3[m][n][r];
            float s = v / (1.0f + expf(-v));   // silu
            float y = s * a3;
            u16 hi = f2bf(y);
            size_t oa = (size_t)(off + row) * ldc + col;
            Ch[oa] = hi;
            Cl[oa] = f2bf(y - bf2f(hi));
          }
        } else if constexpr (EPI == 3){
          if (row < cnt){
            int tok = ftok[off + row];
            float wgt = fwt[off + row];
            atomicAdd(&Cf[(size_t)tok * ldc + col], wgt * v);
          }
        } else {
          if constexpr (KS > 1) atomicAdd(&Cq[(size_t)row * ldq + col], v);
          else                  Cq[(size_t)row * ldq + col] = v;
        }
      }
}

// ---------------- flash attention (split bf16x3) ----------------
__global__ __launch_bounds__(256) void k_attn(
    const u16* __restrict__ qh, const u16* __restrict__ ql,
    const u16* __restrict__ kh, const u16* __restrict__ kl,
    const u16* __restrict__ vh, const u16* __restrict__ vl,
    u16* __restrict__ aoh, u16* __restrict__ aol)
{
  const int h  = blockIdx.y;
  const int q0 = blockIdx.x * 64;
  const int hk = h >> 1;                 // GQA: repeat factor 2
  const int tid = threadIdx.x;
  const int wv = tid >> 6, lane = tid & 63;
  const int lr = lane & 15, lg = lane >> 4;
  const int qw0 = q0 + wv * 16;

  __shared__ u16 Khs[32][72], Kls[32][72];      // 144B rows, 16B aligned
  __shared__ u16 Vhs[64][40], Vls[64][40];      // transposed: [d][k], 80B rows
  __shared__ u16 Phs[4][16][40], Pls[4][16][40];

  bf16x8 qfh[2], qfl[2];
#pragma unroll
  for (int dc = 0; dc < 2; dc++){
    size_t qa = ((size_t)(qw0 + lr) * NH + h) * 64 + dc*32 + lg*8;
    qfh[dc] = *reinterpret_cast<const bf16x8*>(qh + qa);
    qfl[dc] = *reinterpret_cast<const bf16x8*>(ql + qa);
  }
  f32x4 oacc[4];
  float mrun[4], lrun[4];
#pragma unroll
  for (int r = 0; r < 4; r++){ mrun[r] = -1e30f; lrun[r] = 0.f; }
#pragma unroll
  for (int g = 0; g < 4; g++) oacc[g] = f32x4{0.f,0.f,0.f,0.f};

  const int nt = q0 / 32 + 2;
  for (int kt = 0; kt < nt; kt++){
    int kg = kt * 32;
    {
      int kk = tid >> 3, c8 = (tid & 7) * 8;
      size_t ka = ((size_t)(kg + kk) * NKV + hk) * 64 + c8;
      *reinterpret_cast<uint4*>(&Khs[kk][c8]) = *reinterpret_cast<const uint4*>(kh + ka);
      *reinterpret_cast<uint4*>(&Kls[kk][c8]) = *reinterpret_cast<const uint4*>(kl + ka);
      uint4 v1 = *reinterpret_cast<const uint4*>(vh + ka);
      uint4 v2 = *reinterpret_cast<const uint4*>(vl + ka);
      const u16* p1 = reinterpret_cast<const u16*>(&v1);
      const u16* p2 = reinterpret_cast<const u16*>(&v2);
#pragma unroll
      for (int j = 0; j < 8; j++){ Vhs[c8 + j][kk] = p1[j]; Vls[c8 + j][kk] = p2[j]; }
    }
    __syncthreads();

    f32x4 sc[2];
    sc[0] = f32x4{0.f,0.f,0.f,0.f};
    sc[1] = f32x4{0.f,0.f,0.f,0.f};
#pragma unroll
    for (int c = 0; c < 2; c++){
#pragma unroll
      for (int dc = 0; dc < 2; dc++){
        bf16x8 bh = *reinterpret_cast<const bf16x8*>(&Khs[c*16 + lr][dc*32 + lg*8]);
        bf16x8 bl = *reinterpret_cast<const bf16x8*>(&Kls[c*16 + lr][dc*32 + lg*8]);
        sc[c] = mfma16(qfh[dc], bh, sc[c]);
        sc[c] = mfma16(qfh[dc], bl, sc[c]);
        sc[c] = mfma16(qfl[dc], bh, sc[c]);
      }
    }
    float pnew[2][4], corr[4];
#pragma unroll
    for (int r = 0; r < 4; r++){
      int row = qw0 + lg*4 + r;
      float s0 = (kg + lr      <= row) ? sc[0][r] * 0.125f : -1e30f;
      float s1 = (kg + 16 + lr <= row) ? sc[1][r] * 0.125f : -1e30f;
      float tm = fmaxf(s0, s1);
#pragma unroll
      for (int m = 1; m < 16; m <<= 1) tm = fmaxf(tm, __shfl_xor(tm, m));
      float mnew = fmaxf(mrun[r], tm);
      corr[r] = expf(mrun[r] - mnew);
      float p0 = expf(s0 - mnew);
      float p1 = expf(s1 - mnew);
      pnew[0][r] = p0; pnew[1][r] = p1;
      float sm = p0 + p1;
#pragma unroll
      for (int m = 1; m < 16; m <<= 1) sm += __shfl_xor(sm, m);
      lrun[r] = lrun[r] * corr[r] + sm;
      mrun[r] = mnew;
    }
#pragma unroll
    for (int g = 0; g < 4; g++){
      f32x4 t = oacc[g];
#pragma unroll
      for (int r = 0; r < 4; r++) t[r] *= corr[r];
      oacc[g] = t;
    }
#pragma unroll
    for (int c = 0; c < 2; c++)
#pragma unroll
      for (int r = 0; r < 4; r++){
        float p = pnew[c][r];
        u16 hi = f2bf(p);
        Phs[wv][lg*4 + r][c*16 + lr] = hi;
        Pls[wv][lg*4 + r][c*16 + lr] = f2bf(p - bf2f(hi));
      }
    asm volatile("s_waitcnt lgkmcnt(0)" ::: "memory");
    __builtin_amdgcn_sched_barrier(0);
    bf16x8 pah = *reinterpret_cast<const bf16x8*>(&Phs[wv][lr][lg*8]);
    bf16x8 pal = *reinterpret_cast<const bf16x8*>(&Pls[wv][lr][lg*8]);
#pragma unroll
    for (int g = 0; g < 4; g++){
      bf16x8 vb1 = *reinterpret_cast<const bf16x8*>(&Vhs[g*16 + lr][lg*8]);
      bf16x8 vb2 = *reinterpret_cast<const bf16x8*>(&Vls[g*16 + lr][lg*8]);
      oacc[g] = mfma16(pah, vb1, oacc[g]);
      oacc[g] = mfma16(pah, vb2, oacc[g]);
      oacc[g] = mfma16(pal, vb1, oacc[g]);
    }
    __syncthreads();
  }
#pragma unroll
  for (int g = 0; g < 4; g++)
#pragma unroll
    for (int r = 0; r < 4; r++){
      int row = qw0 + lg*4 + r;
      float v = oacc[g][r] / lrun[r];
      u16 hi = f2bf(v);
      size_t oa = ((size_t)row * NH + h) * 64 + g*16 + lr;
      aoh[oa] = hi;
      aol[oa] = f2bf(v - bf2f(hi));
    }
}

// ---------------- launch ----------------
extern "C" void kernel_launch(void* const* d_in, const int* in_sizes, int n_in,
                              void* d_out, int out_size, void* d_ws, size_t ws_size,
                              hipStream_t stream){
  const int*   x     = (const int*)d_in[0];
  const float* emb   = (const float*)d_in[1];
  const float* lnw   = (const float*)d_in[2];
  const float* fflnw = (const float*)d_in[3];
  const float* wq    = (const float*)d_in[4];
  const float* wk    = (const float*)d_in[5];
  const float* wvp   = (const float*)d_in[6];
  const float* wo    = (const float*)d_in[7];
  const float* gw    = (const float*)d_in[8];
  const float* w1    = (const float*)d_in[9];
  const float* w2    = (const float*)d_in[10];
  const float* w3    = (const float*)d_in[11];
  const float* dnw   = (const float*)d_in[12];
  float* out = (float*)d_out;

  char* p = (char*)d_ws;
  auto alloc = [&](size_t bytes)->char*{
    char* r = p; p += (bytes + 255) & ~(size_t)255; return r;
  };
  float* h    = (float*)alloc((size_t)TT * DM * 4);
  float* qbuf = (float*)alloc((size_t)TT * 1024 * 4);
  float* kbuf = (float*)alloc((size_t)TT * 512 * 4);
  float* vbuf = (float*)alloc((size_t)TT * 512 * 4);
  u16* xnh = (u16*)alloc((size_t)TT * DM * 2);
  u16* xnl = (u16*)alloc((size_t)TT * DM * 2);
  u16* qhb = (u16*)alloc((size_t)TT * 1024 * 2);
  u16* qlb = (u16*)alloc((size_t)TT * 1024 * 2);
  u16* khb = (u16*)alloc((size_t)TT * 512 * 2);
  u16* klb = (u16*)alloc((size_t)TT * 512 * 2);
  u16* vhb = (u16*)alloc((size_t)TT * 512 * 2);
  u16* vlb = (u16*)alloc((size_t)TT * 512 * 2);
  u16* aoh = (u16*)alloc((size_t)TT * 1024 * 2);
  u16* aol = (u16*)alloc((size_t)TT * 1024 * 2);
  u16* acth = (u16*)alloc((size_t)2 * TT * FFD * 2);
  u16* actl = (u16*)alloc((size_t)2 * TT * FFD * 2);
  int*   topi = (int*)alloc((size_t)2 * TT * 4);
  float* topw = (float*)alloc((size_t)2 * TT * 4);
  int* cnt  = (int*)alloc(64);
  int* offe = (int*)alloc(64);
  int* cur  = (int*)alloc(64);
  int*   ftok = (int*)alloc((size_t)2 * TT * 4);
  float* fwt  = (float*)alloc((size_t)2 * TT * 4);
  // trig tables ALIASED into aoh/aol (dead during rope phase; attn rewrites them
  // later each layer, so recompute per layer). Keeps ws footprint == R8 (proven).
  float* ctab = (float*)aoh;
  float* stab = (float*)aol;

  k_embed<<<TT, 256, 0, stream>>>(x, emb, h);

  for (int i = 0; i < 2; i++){
    const float* wq_i = wq + (size_t)i * DM * 1024;
    const float* wk_i = wk + (size_t)i * DM * 512;
    const float* wv_i = wvp + (size_t)i * DM * 512;
    const float* wo_i = wo + (size_t)i * 1024 * DM;
    const float* w1_i = w1 + (size_t)i * NE * FFD * DM;
    const float* w2_i = w2 + (size_t)i * NE * DM * FFD;
    const float* w3_i = w3 + (size_t)i * NE * FFD * DM;

    k_rmsnorm<0><<<TT, 256, 0, stream>>>(h, lnw + i * DM, xnh, xnl, nullptr);

    // fused QKV with K-split 2: zero outputs, atomicAdd epilogue (1024 blocks)
    hipMemsetAsync(qbuf, 0, (size_t)TT * 1024 * 4, stream);
    hipMemsetAsync(kbuf, 0, (size_t)TT * 512 * 4, stream);
    hipMemsetAsync(vbuf, 0, (size_t)TT * 512 * 4, stream);
    k_gemm<1,4,1,0,64,2><<<dim3(32,16,2), 256, 0, stream>>>(xnh, xnl,
        wq_i, nullptr, wk_i, wv_i, 0, 1024, DM,
        qbuf, 1024, kbuf, vbuf, nullptr, nullptr, nullptr, nullptr, nullptr, nullptr);

    // trig tables into aoh/aol space (dead here; clobbered by attn below)
    k_trig<<<TT * 32 / 256, 256, 0, stream>>>(ctab, stab);
    k_rope<16><<<4096, 256, 0, stream>>>(qbuf, ctab, stab, qhb, qlb);
    k_rope<8><<<2048, 256, 0, stream>>>(kbuf, ctab, stab, khb, klb);
    k_splitbuf<<<4096, 256, 0, stream>>>(vbuf, vhb, vlb, TT * 512);

    k_attn<<<dim3(32,16,1), 256, 0, stream>>>(qhb, qlb, khb, klb, vhb, vlb, aoh, aol);

    // WO with K-split 2 (atomicAdd residual add)
    k_gemm<1,1,1,0,64,2><<<dim3(16,16,2), 256, 0, stream>>>(aoh, aol,
        wo_i, nullptr, nullptr, nullptr, 0, DM, 1024,
        h, DM, nullptr, nullptr, nullptr, nullptr, nullptr, nullptr, nullptr, nullptr);

    k_rmsnorm<0><<<TT, 256, 0, stream>>>(h, fflnw + i * DM, xnh, xnl, nullptr);

    k_zero8<<<1, 64, 0, stream>>>(cnt);
    k_gate<<<TT/4, 256, 0, stream>>>(xnh, xnl, gw + (size_t)i * NE * DM, topi, topw, cnt);
    k_scan<<<1, 64, 0, stream>>>(cnt, offe, cur);
    k_scatter<<<8, 256, 0, stream>>>(topi, topw, offe, cur, ftok, fwt);

    if (i == 0){
      k_gemm<0,2,1,1,64,1><<<dim3(FFD/64,16,8), 256, 0, stream>>>(xnh, xnl,
          w1_i, w3_i, nullptr, nullptr, (size_t)FFD * DM, FFD, DM,
          nullptr, FFD, nullptr, nullptr, acth, actl, cnt, offe, ftok, fwt);
      k_gemm<0,3,1,0,128,4><<<dim3(DM/128,16,32), 256, 0, stream>>>(acth, actl,
          w2_i, nullptr, nullptr, nullptr, (size_t)DM * FFD, DM, FFD,
          h, DM, nullptr, nullptr, nullptr, nullptr, cnt, offe, ftok, fwt);
    } else {
      k_gemm<0,2,0,1,64,1><<<dim3(FFD/64,16,8), 256, 0, stream>>>(xnh, xnl,
          w1_i, w3_i, nullptr, nullptr, (size_t)FFD * DM, FFD, DM,
          nullptr, FFD, nullptr, nullptr, acth, actl, cnt, offe, ftok, fwt);
      k_gemm<0,3,0,0,128,4><<<dim3(DM/128,16,32), 256, 0, stream>>>(acth, actl,
          w2_i, nullptr, nullptr, nullptr, (size_t)DM * FFD, DM, FFD,
          h, DM, nullptr, nullptr, nullptr, nullptr, cnt, offe, ftok, fwt);
    }
  }

  k_rmsnorm<1><<<TT, 256, 0, stream>>>(h, dnw, nullptr, nullptr, out);
}

// Round 13
// 1494.994 us; speedup vs baseline: 1.1314x; 1.1314x over previous
//
#include <hip/hip_runtime.h>

using u16 = unsigned short;
using u32 = unsigned int;

#define TT 2048
#define DM 1024
#define NH 16
#define NKV 8
#define DHD 64
#define FFD 3584
#define NE 8

typedef __bf16 bf16x8 __attribute__((ext_vector_type(8)));
typedef float f32x4 __attribute__((ext_vector_type(4)));

// native casts -> v_cvt_pk_bf16_f32 (RNE, same results as bit trick)
__device__ __forceinline__ u16 f2bf(float x){
  return __builtin_bit_cast(u16, (__bf16)x);
}
__device__ __forceinline__ float bf2f(u16 h){
  return (float)__builtin_bit_cast(__bf16, h);
}
__device__ __forceinline__ f32x4 mfma16(bf16x8 a, bf16x8 b, f32x4 c){
  return __builtin_amdgcn_mfma_f32_16x16x32_bf16(a, b, c, 0, 0, 0);
}
__device__ __forceinline__ uint4 packhi8v(float4 a, float4 b){
  u16 h0=f2bf(a.x),h1=f2bf(a.y),h2=f2bf(a.z),h3=f2bf(a.w);
  u16 h4=f2bf(b.x),h5=f2bf(b.y),h6=f2bf(b.z),h7=f2bf(b.w);
  return make_uint4((u32)h0|((u32)h1<<16),(u32)h2|((u32)h3<<16),
                    (u32)h4|((u32)h5<<16),(u32)h6|((u32)h7<<16));
}
__device__ __forceinline__ uint4 packlo8v(float4 a, float4 b){
  u16 l0=f2bf(a.x-bf2f(f2bf(a.x))),l1=f2bf(a.y-bf2f(f2bf(a.y)));
  u16 l2=f2bf(a.z-bf2f(f2bf(a.z))),l3=f2bf(a.w-bf2f(f2bf(a.w)));
  u16 l4=f2bf(b.x-bf2f(f2bf(b.x))),l5=f2bf(b.y-bf2f(f2bf(b.y)));
  u16 l6=f2bf(b.z-bf2f(f2bf(b.z))),l7=f2bf(b.w-bf2f(f2bf(b.w)));
  return make_uint4((u32)l0|((u32)l1<<16),(u32)l2|((u32)l3<<16),
                    (u32)l4|((u32)l5<<16),(u32)l6|((u32)l7<<16));
}

// chunk-XOR swizzle: 16B chunk c (0..3) of row r stored at u16-offset SWC(r,c).
#define SWZR(r) ((((r)>>1) ^ ((r)>>3)) & 3)
#define SWC(r,c) ((((c) ^ SWZR(r))) * 8)

// async global->LDS, 16B per lane, LDS dest = wave-uniform base + lane*16
__device__ __forceinline__ void glds16(const u16* g, u16* l){
  __builtin_amdgcn_global_load_lds(
      (const __attribute__((address_space(1))) void*)g,
      (__attribute__((address_space(3))) void*)l,
      16, 0, 0);
}

// ---------------- embedding ----------------
__global__ __launch_bounds__(256) void k_embed(const int* __restrict__ x,
    const float* __restrict__ emb, float* __restrict__ h){
  int t = blockIdx.x;
  int d = threadIdx.x * 4;
  float4 v = *reinterpret_cast<const float4*>(emb + (size_t)x[t] * DM + d);
  *reinterpret_cast<float4*>(h + (size_t)t * DM + d) = v;
}

// ---------------- rmsnorm (split-bf16 out, or f32 out) ----------------
template<int OUTF32>
__global__ __launch_bounds__(256) void k_rmsnorm(const float* __restrict__ in,
    const float* __restrict__ w, u16* __restrict__ oh, u16* __restrict__ ol,
    float* __restrict__ of){
  int t = blockIdx.x;
  int d4 = threadIdx.x * 4;
  float4 xv = *reinterpret_cast<const float4*>(in + (size_t)t * DM + d4);
  float ss = xv.x*xv.x + xv.y*xv.y + xv.z*xv.z + xv.w*xv.w;
#pragma unroll
  for (int m = 1; m < 64; m <<= 1) ss += __shfl_xor(ss, m);
  __shared__ float sred[4];
  if ((threadIdx.x & 63) == 0) sred[threadIdx.x >> 6] = ss;
  __syncthreads();
  float tot = sred[0] + sred[1] + sred[2] + sred[3];
  float r = 1.0f / sqrtf(tot * (1.0f / DM) + 1e-5f);
  float vv[4] = {xv.x, xv.y, xv.z, xv.w};
#pragma unroll
  for (int jj = 0; jj < 4; jj++){
    float xn = (vv[jj] * r) * w[d4 + jj];
    size_t a = (size_t)t * DM + d4 + jj;
    if constexpr (OUTF32){
      of[a] = xn;
    } else {
      u16 hi = f2bf(xn);
      oh[a] = hi;
      ol[a] = f2bf(xn - bf2f(hi));
    }
  }
}

// ---------------- trig table (bit-identical to R8's in-rope math) ----------------
__global__ __launch_bounds__(256) void k_trig(float* __restrict__ ct, float* __restrict__ st){
  int idx = blockIdx.x * 256 + threadIdx.x;    // TT*32 entries
  int j = idx & 31;
  int s = idx >> 5;
  float xe = (float)j * 0.03125f;                 // exact: arange*2/64
  float yf = (float)pow(1.0e6, (double)xe);       // matches CR powf
  float fr = 1.0f / yf;
  float ang = (float)s * fr;                      // f32 mul like ref
  double ad = (double)ang;
  ct[idx] = (float)cos(ad);
  st[idx] = (float)sin(ad);
}

// ---------------- rope + split (table-driven) ----------------
template<int NHD>
__global__ __launch_bounds__(256) void k_rope(const float* __restrict__ in,
    const float* __restrict__ ct, const float* __restrict__ st,
    u16* __restrict__ oh, u16* __restrict__ ol){
  int idx = blockIdx.x * 256 + threadIdx.x;
  int j = idx & 31;
  int hd = (idx >> 5) % NHD;
  int s = idx / (32 * NHD);
  size_t base = ((size_t)s * NHD + hd) * 64 + 2 * j;
  float x1 = in[base], x2 = in[base + 1];
  int ti = (s << 5) | j;
  float c  = ct[ti];
  float sn = st[ti];
  float o1 = x1 * c - x2 * sn;
  float o2 = x1 * sn + x2 * c;
  u16 h1 = f2bf(o1), h2 = f2bf(o2);
  oh[base]     = h1; ol[base]     = f2bf(o1 - bf2f(h1));
  oh[base + 1] = h2; ol[base + 1] = f2bf(o2 - bf2f(h2));
}

// ---------------- plain f32 -> bf16 split ----------------
__global__ __launch_bounds__(256) void k_splitbuf(const float* __restrict__ in,
    u16* __restrict__ oh, u16* __restrict__ ol, int n){
  int i = blockIdx.x * 256 + threadIdx.x;
  if (i < n){
    float x = in[i];
    u16 hi = f2bf(x);
    oh[i] = hi;
    ol[i] = f2bf(x - bf2f(hi));
  }
}

// ---------------- gate + top2 ----------------
__global__ __launch_bounds__(256) void k_gate(const u16* __restrict__ xh,
    const u16* __restrict__ xl, const float* __restrict__ gw,
    int* __restrict__ topi, float* __restrict__ topw, int* __restrict__ cnt){
  int wv = threadIdx.x >> 6, lane = threadIdx.x & 63;
  int t = blockIdx.x * 4 + wv;
  float x[16];
#pragma unroll
  for (int i = 0; i < 16; i++){
    size_t a = (size_t)t * DM + lane + 64 * i;
    x[i] = bf2f(xh[a]) + bf2f(xl[a]);
  }
  float lgt[8];
#pragma unroll
  for (int e = 0; e < 8; e++){
    float s = 0.f;
#pragma unroll
    for (int i = 0; i < 16; i++) s += x[i] * gw[(size_t)e * DM + lane + 64 * i];
#pragma unroll
    for (int m = 1; m < 64; m <<= 1) s += __shfl_xor(s, m);
    lgt[e] = s;
  }
  float mx = lgt[0];
#pragma unroll
  for (int e = 1; e < 8; e++) mx = fmaxf(mx, lgt[e]);
  float p[8]; float sum = 0.f;
#pragma unroll
  for (int e = 0; e < 8; e++){ p[e] = expf(lgt[e] - mx); sum += p[e]; }
  float g[8];
#pragma unroll
  for (int e = 0; e < 8; e++) g[e] = p[e] / sum;   // match ref's top_k domain
  int t0 = 0; float b0 = g[0];
#pragma unroll
  for (int e = 1; e < 8; e++) if (g[e] > b0){ b0 = g[e]; t0 = e; }
  int t1 = -1; float b1 = -1.f;
#pragma unroll
  for (int e = 0; e < 8; e++) if (e != t0 && g[e] > b1){ b1 = g[e]; t1 = e; }
  float ssum = b0 + b1;
  float w0 = b0 / ssum, w1 = b1 / ssum;
  if (lane == 0 && t < TT){
    topi[2*t] = t0; topi[2*t+1] = t1;
    topw[2*t] = w0; topw[2*t+1] = w1;
    atomicAdd(&cnt[t0], 1);
    atomicAdd(&cnt[t1], 1);
  }
}

__global__ void k_zero8(int* cnt){ if (threadIdx.x < 8) cnt[threadIdx.x] = 0; }

__global__ void k_scan(const int* __restrict__ cnt, int* __restrict__ offp, int* __restrict__ cur){
  if (threadIdx.x == 0){
    int r = 0;
    for (int e = 0; e < 8; e++){ offp[e] = r; r += cnt[e]; }
  }
  if (threadIdx.x < 8) cur[threadIdx.x] = 0;
}

__global__ __launch_bounds__(256) void k_scatter(const int* __restrict__ topi,
    const float* __restrict__ topw, const int* __restrict__ offp, int* __restrict__ cur,
    int* __restrict__ ftok, float* __restrict__ fwt){
  int t = blockIdx.x * 256 + threadIdx.x;
  if (t < TT){
#pragma unroll
    for (int j = 0; j < 2; j++){
      int e = topi[2*t + j];
      int p = atomicAdd(&cur[e], 1);
      ftok[offp[e] + p] = t;
      fwt[offp[e] + p] = topw[2*t + j];
    }
  }
}

// ---------------- GEMM: raw-barrier schedule, A via global_load_lds (dbuf), B LDS-staged ----------------
// (R11 structure — known-good — plus T5 s_setprio around the MFMA cluster)
#define GLDSA(BUF, KK) do { \
    glds16(Ah + gaA0 + (KK), (u16*)&Ash[BUF][awr0][0]); \
    glds16(Ah + gaA1 + (KK), (u16*)&Ash[BUF][awr1][0]); \
    if constexpr (SPLIT){ \
      glds16(Al + gaA0 + (KK), (u16*)&Asl[BUF][awr0][0]); \
      glds16(Al + gaA1 + (KK), (u16*)&Asl[BUF][awr1][0]); \
    } \
  } while(0)

#define GPRELOADB(KK) do { \
    if constexpr (BLAYOUT == 0){ \
      const float* bp_ = Bw + (size_t)(n0 + br0) * K + (KK) + cb8; \
      pB0 = *reinterpret_cast<const float4*>(bp_); \
      pB1 = *reinterpret_cast<const float4*>(bp_ + 4); \
      if constexpr (TN == 128){ \
        const float* bp2_ = Bw + (size_t)(n0 + br1) * K + (KK) + cb8; \
        pB2 = *reinterpret_cast<const float4*>(bp2_); \
        pB3 = *reinterpret_cast<const float4*>(bp2_ + 4); \
      } \
      if constexpr (DUAL){ \
        const float* bq_ = B3w + (size_t)(n0 + br0) * K + (KK) + cb8; \
        pB2 = *reinterpret_cast<const float4*>(bq_); \
        pB3 = *reinterpret_cast<const float4*>(bq_ + 4); \
      } \
    } else { \
      pB0 = *reinterpret_cast<const float4*>(Bw + (size_t)((KK) + kk1) * Nq + n0 + nn1); \
      pB1 = *reinterpret_cast<const float4*>(Bw + (size_t)((KK) + 16 + kk1) * Nq + n0 + nn1); \
    } \
  } while(0)

#define GSTOREB() do { \
    if constexpr (BLAYOUT == 0){ \
      *reinterpret_cast<uint4*>(&Bh1[br0][swB0]) = packhi8v(pB0, pB1); \
      if constexpr (SPLIT) *reinterpret_cast<uint4*>(&Bl1[br0][swB0]) = packlo8v(pB0, pB1); \
      if constexpr (TN == 128){ \
        *reinterpret_cast<uint4*>(&Bh1[br1][swB1]) = packhi8v(pB2, pB3); \
        if constexpr (SPLIT) *reinterpret_cast<uint4*>(&Bl1[br1][swB1]) = packlo8v(pB2, pB3); \
      } \
      if constexpr (DUAL){ \
        *reinterpret_cast<uint4*>(&Bh3[br0][swB0]) = packhi8v(pB2, pB3); \
        if constexpr (SPLIT) *reinterpret_cast<uint4*>(&Bl3[br0][swB0]) = packlo8v(pB2, pB3); \
      } \
    } else { \
      const float* q0 = reinterpret_cast<const float*>(&pB0); \
      const float* q1 = reinterpret_cast<const float*>(&pB1); \
      const int ch0 = kk1 >> 3, off0 = kk1 & 7; \
      _Pragma("unroll") \
      for (int j = 0; j < 4; j++){ \
        int row = nn1 + j; \
        int c0 = SWC(row, ch0) + off0; \
        int c1 = SWC(row, ch0 + 2) + off0; \
        u16 h0 = f2bf(q0[j]); \
        Bh1[row][c0] = h0; \
        if constexpr (SPLIT) Bl1[row][c0] = f2bf(q0[j] - bf2f(h0)); \
        u16 h1 = f2bf(q1[j]); \
        Bh1[row][c1] = h1; \
        if constexpr (SPLIT) Bl1[row][c1] = f2bf(q1[j] - bf2f(h1)); \
      } \
    } \
  } while(0)

#define MFMA_PHASE(CURB) do { \
    bf16x8 af[4], afl[4]; \
    _Pragma("unroll") \
    for (int m = 0; m < 4; m++){ \
      int Ra = wr*64 + m*16 + lr; \
      int sa = SWC(Ra, lg); \
      af[m] = *reinterpret_cast<const bf16x8*>(&Ash[CURB][Ra][sa]); \
      if constexpr (SPLIT) \
        afl[m] = *reinterpret_cast<const bf16x8*>(&Asl[CURB][Ra][sa]); \
    } \
    __builtin_amdgcn_s_setprio(1); \
    _Pragma("unroll") \
    for (int n = 0; n < NF; n++){ \
      int Rb = wc*(TN/2) + n*16 + lr; \
      int sb = SWC(Rb, lg); \
      bf16x8 b1 = *reinterpret_cast<const bf16x8*>(&Bh1[Rb][sb]); \
      _Pragma("unroll") \
      for (int m = 0; m < 4; m++) acc[m][n] = mfma16(af[m], b1, acc[m][n]); \
      if constexpr (SPLIT){ \
        bf16x8 bl = *reinterpret_cast<const bf16x8*>(&Bl1[Rb][sb]); \
        _Pragma("unroll") \
        for (int m = 0; m < 4; m++){ \
          acc[m][n] = mfma16(af[m], bl, acc[m][n]); \
          acc[m][n] = mfma16(afl[m], b1, acc[m][n]); \
        } \
      } \
      if constexpr (DUAL){ \
        bf16x8 b3 = *reinterpret_cast<const bf16x8*>(&Bh3[Rb][sb]); \
        _Pragma("unroll") \
        for (int m = 0; m < 4; m++) acc3[m][n] = mfma16(af[m], b3, acc3[m][n]); \
        if constexpr (SPLIT){ \
          bf16x8 b3l = *reinterpret_cast<const bf16x8*>(&Bl3[Rb][sb]); \
          _Pragma("unroll") \
          for (int m = 0; m < 4; m++){ \
            acc3[m][n] = mfma16(af[m], b3l, acc3[m][n]); \
            acc3[m][n] = mfma16(afl[m], b3, acc3[m][n]); \
          } \
        } \
      } \
    } \
    __builtin_amdgcn_s_setprio(0); \
  } while(0)

template<int BLAYOUT, int EPI, int SPLIT, int DUAL, int TN, int KS>
__global__ __launch_bounds__(256) void k_gemm(
    const u16* __restrict__ Ah, const u16* __restrict__ Al,
    const float* __restrict__ Bw, const float* __restrict__ B3w,
    const float* __restrict__ Bw2, const float* __restrict__ Bw3,
    size_t strideB, int N, int K,
    float* __restrict__ Cf, int ldc,
    float* __restrict__ Cf2, float* __restrict__ Cf3,
    u16* __restrict__ Ch, u16* __restrict__ Cl,
    const int* __restrict__ cntp, const int* __restrict__ offp,
    const int* __restrict__ ftok, const float* __restrict__ fwt)
{
  static_assert(!(DUAL && TN != 64), "DUAL uses TN=64");
  static_assert(!(BLAYOUT == 1 && TN != 64), "BLAYOUT=1 uses TN=64");
  int cnt = TT, off = 0, ks = 0;
  if constexpr (EPI == 2 || EPI == 3){
    int e = blockIdx.z / KS;
    ks = blockIdx.z % KS;
    cnt = cntp[e]; off = offp[e];
    if ((int)blockIdx.y * 128 >= cnt) return;
    Bw += (size_t)e * strideB;
    if constexpr (DUAL) B3w += (size_t)e * strideB;
  } else if constexpr (KS > 1){
    ks = blockIdx.z;
  }
  __shared__ u16 Ash[2][128][32];                 // A hi, double-buffered
  __shared__ u16 Asl[SPLIT ? 2 : 1][SPLIT ? 128 : 1][32];
  __shared__ u16 Bh1[TN][32];
  __shared__ u16 Bl1[SPLIT ? TN : 1][32];
  __shared__ u16 Bh3[DUAL ? TN : 1][32];
  __shared__ u16 Bl3[(DUAL && SPLIT) ? TN : 1][32];

  const int tid = threadIdx.x;
  const int m0 = blockIdx.y * 128;

  // output/N selection (fused QKV uses blockIdx.x ranges)
  int n0, Nq = N, ldq = ldc;
  float* Cq = Cf;
  if constexpr (EPI == 4){
    int bx = blockIdx.x;
    if (bx < 16){       n0 = bx * 64;        Nq = 1024; ldq = 1024; Cq = Cf;  }
    else if (bx < 24){  n0 = (bx - 16) * 64; Nq = 512;  ldq = 512;  Cq = Cf2; Bw = Bw2; }
    else {              n0 = (bx - 24) * 64; Nq = 512;  ldq = 512;  Cq = Cf3; Bw = Bw3; }
  } else {
    n0 = blockIdx.x * TN;
  }

  const int wid = tid >> 6, lane = tid & 63;
  const int wr = wid >> 1, wc = wid & 1;
  const int lr = lane & 15, lg = lane >> 4;
  constexpr int NF = TN / 32;

  // A gload_lds setup: wave wid stages rows [wid*32, wid*32+32), 2 instrs of 16 rows.
  // LDS dest linear (base + lane*16); swizzle folded into per-lane GLOBAL chunk.
  const int awr0 = wid * 32;              // wave-uniform LDS row base, instr 0
  const int awr1 = wid * 32 + 16;         // instr 1
  const int rA0 = awr0 + (lane >> 2);
  const int rA1 = awr1 + (lane >> 2);
  const int cA0 = (lane & 3) ^ SWZR(rA0);
  const int cA1 = (lane & 3) ^ SWZR(rA1);
  int grA0, grA1;
  {
    int g0 = m0 + rA0, g1 = m0 + rA1;
    if constexpr (EPI == 2){
      grA0 = ftok[off + (g0 < cnt ? g0 : cnt - 1)];
      grA1 = ftok[off + (g1 < cnt ? g1 : cnt - 1)];
    } else if constexpr (EPI == 3){
      grA0 = off + (g0 < cnt ? g0 : cnt - 1);
      grA1 = off + (g1 < cnt ? g1 : cnt - 1);
    } else {
      grA0 = g0; grA1 = g1;
    }
  }
  const size_t gaA0 = (size_t)grA0 * K + cA0 * 8;
  const size_t gaA1 = (size_t)grA1 * K + cA1 * 8;

  // B staging (BLAYOUT=0)
  const int br0 = tid >> 2;
  const int br1 = br0 + 64;
  const int cb8 = (tid & 3) * 8;
  const int swB0 = SWC(br0, tid & 3), swB1 = SWC(br1, tid & 3);
  // BLAYOUT=1 indices
  const int kk1 = tid >> 4;
  const int nn1 = (tid & 15) * 4;

  f32x4 acc[4][NF];
  f32x4 acc3[DUAL ? 4 : 1][NF];
#pragma unroll
  for (int m = 0; m < 4; m++)
#pragma unroll
    for (int n = 0; n < NF; n++){
      acc[m][n] = f32x4{0.f,0.f,0.f,0.f};
      if constexpr (DUAL) acc3[m][n] = f32x4{0.f,0.f,0.f,0.f};
    }

  // named B staging registers (no arrays, no lambdas -> no scratch)
  float4 pB0{}, pB1{}, pB2{}, pB3{};

  const int kbeg = ks * (K / KS);
  const int kend = kbeg + (K / KS);

  GLDSA(0, kbeg);          // A(k0) -> buf0 (async)
  GPRELOADB(kbeg);         // B(k0) -> regs
  int cur = 0;
  for (int k0 = kbeg; k0 < kend; k0 += 32){
    GSTOREB();             // compiler waits vmcnt for B regs (drains older A-glds too)
    asm volatile("s_waitcnt vmcnt(0) lgkmcnt(0)" ::: "memory");  // A(k) in LDS, B writes visible
    __builtin_amdgcn_s_barrier();
    if (k0 + 32 < kend){
      GLDSA(cur ^ 1, k0 + 32);   // A(k+1) streams during MFMA (buf^1 free: last read pre-barrier)
      GPRELOADB(k0 + 32);        // B(k+1) -> regs, in flight across barrier 2
    }
    MFMA_PHASE(cur);
    __builtin_amdgcn_s_barrier();  // raw: no vmcnt drain -> prefetches stay in flight
    cur ^= 1;
  }

  // --- epilogue ---
#pragma unroll
  for (int m = 0; m < 4; m++)
#pragma unroll
    for (int n = 0; n < NF; n++)
#pragma unroll
      for (int r = 0; r < 4; r++){
        int row = m0 + wr*64 + m*16 + lg*4 + r;   // C/D: row=(lane>>4)*4+reg, col=lane&15 [m89]
        int col = n0 + wc*(TN/2) + n*16 + lr;
        float v = acc[m][n][r];
        if constexpr (EPI == 0){
          Cf[(size_t)row * ldc + col] = v;
        } else if constexpr (EPI == 1){
          if constexpr (KS > 1) atomicAdd(&Cf[(size_t)row * ldc + col], v);
          else                  Cf[(size_t)row * ldc + col] += v;
        } else if constexpr (EPI == 2){
          if (row < cnt){
            float a3 = acc3[m][n][r];
            float s = v / (1.0f + expf(-v));   // silu
            float y = s * a3;
            u16 hi = f2bf(y);
            size_t oa = (size_t)(off + row) * ldc + col;
            Ch[oa] = hi;
            Cl[oa] = f2bf(y - bf2f(hi));
          }
        } else if constexpr (EPI == 3){
          if (row < cnt){
            int tok = ftok[off + row];
            float wgt = fwt[off + row];
            atomicAdd(&Cf[(size_t)tok * ldc + col], wgt * v);
          }
        } else {
          if constexpr (KS > 1) atomicAdd(&Cq[(size_t)row * ldq + col], v);
          else                  Cq[(size_t)row * ldq + col] = v;
        }
      }
}

// ---------------- flash attention (split bf16x3) ----------------
__global__ __launch_bounds__(256) void k_attn(
    const u16* __restrict__ qh, const u16* __restrict__ ql,
    const u16* __restrict__ kh, const u16* __restrict__ kl,
    const u16* __restrict__ vh, const u16* __restrict__ vl,
    u16* __restrict__ aoh, u16* __restrict__ aol)
{
  const int h  = blockIdx.y;
  const int q0 = blockIdx.x * 64;
  const int hk = h >> 1;                 // GQA: repeat factor 2
  const int tid = threadIdx.x;
  const int wv = tid >> 6, lane = tid & 63;
  const int lr = lane & 15, lg = lane >> 4;
  const int qw0 = q0 + wv * 16;

  __shared__ u16 Khs[32][72], Kls[32][72];      // 144B rows, 16B aligned
  __shared__ u16 Vhs[64][40], Vls[64][40];      // transposed: [d][k], 80B rows
  __shared__ u16 Phs[4][16][40], Pls[4][16][40];

  bf16x8 qfh[2], qfl[2];
#pragma unroll
  for (int dc = 0; dc < 2; dc++){
    size_t qa = ((size_t)(qw0 + lr) * NH + h) * 64 + dc*32 + lg*8;
    qfh[dc] = *reinterpret_cast<const bf16x8*>(qh + qa);
    qfl[dc] = *reinterpret_cast<const bf16x8*>(ql + qa);
  }
  f32x4 oacc[4];
  float mrun[4], lrun[4];
#pragma unroll
  for (int r = 0; r < 4; r++){ mrun[r] = -1e30f; lrun[r] = 0.f; }
#pragma unroll
  for (int g = 0; g < 4; g++) oacc[g] = f32x4{0.f,0.f,0.f,0.f};

  const int nt = q0 / 32 + 2;
  for (int kt = 0; kt < nt; kt++){
    int kg = kt * 32;
    {
      int kk = tid >> 3, c8 = (tid & 7) * 8;
      size_t ka = ((size_t)(kg + kk) * NKV + hk) * 64 + c8;
      *reinterpret_cast<uint4*>(&Khs[kk][c8]) = *reinterpret_cast<const uint4*>(kh + ka);
      *reinterpret_cast<uint4*>(&Kls[kk][c8]) = *reinterpret_cast<const uint4*>(kl + ka);
      uint4 v1 = *reinterpret_cast<const uint4*>(vh + ka);
      uint4 v2 = *reinterpret_cast<const uint4*>(vl + ka);
      const u16* p1 = reinterpret_cast<const u16*>(&v1);
      const u16* p2 = reinterpret_cast<const u16*>(&v2);
#pragma unroll
      for (int j = 0; j < 8; j++){ Vhs[c8 + j][kk] = p1[j]; Vls[c8 + j][kk] = p2[j]; }
    }
    __syncthreads();

    f32x4 sc[2];
    sc[0] = f32x4{0.f,0.f,0.f,0.f};
    sc[1] = f32x4{0.f,0.f,0.f,0.f};
#pragma unroll
    for (int c = 0; c < 2; c++){
#pragma unroll
      for (int dc = 0; dc < 2; dc++){
        bf16x8 bh = *reinterpret_cast<const bf16x8*>(&Khs[c*16 + lr][dc*32 + lg*8]);
        bf16x8 bl = *reinterpret_cast<const bf16x8*>(&Kls[c*16 + lr][dc*32 + lg*8]);
        sc[c] = mfma16(qfh[dc], bh, sc[c]);
        sc[c] = mfma16(qfh[dc], bl, sc[c]);
        sc[c] = mfma16(qfl[dc], bh, sc[c]);
      }
    }
    float pnew[2][4], corr[4];
#pragma unroll
    for (int r = 0; r < 4; r++){
      int row = qw0 + lg*4 + r;
      float s0 = (kg + lr      <= row) ? sc[0][r] * 0.125f : -1e30f;
      float s1 = (kg + 16 + lr <= row) ? sc[1][r] * 0.125f : -1e30f;
      float tm = fmaxf(s0, s1);
#pragma unroll
      for (int m = 1; m < 16; m <<= 1) tm = fmaxf(tm, __shfl_xor(tm, m));
      float mnew = fmaxf(mrun[r], tm);
      corr[r] = expf(mrun[r] - mnew);
      float p0 = expf(s0 - mnew);
      float p1 = expf(s1 - mnew);
      pnew[0][r] = p0; pnew[1][r] = p1;
      float sm = p0 + p1;
#pragma unroll
      for (int m = 1; m < 16; m <<= 1) sm += __shfl_xor(sm, m);
      lrun[r] = lrun[r] * corr[r] + sm;
      mrun[r] = mnew;
    }
#pragma unroll
    for (int g = 0; g < 4; g++){
      f32x4 t = oacc[g];
#pragma unroll
      for (int r = 0; r < 4; r++) t[r] *= corr[r];
      oacc[g] = t;
    }
#pragma unroll
    for (int c = 0; c < 2; c++)
#pragma unroll
      for (int r = 0; r < 4; r++){
        float p = pnew[c][r];
        u16 hi = f2bf(p);
        Phs[wv][lg*4 + r][c*16 + lr] = hi;
        Pls[wv][lg*4 + r][c*16 + lr] = f2bf(p - bf2f(hi));
      }
    asm volatile("s_waitcnt lgkmcnt(0)" ::: "memory");
    __builtin_amdgcn_sched_barrier(0);
    bf16x8 pah = *reinterpret_cast<const bf16x8*>(&Phs[wv][lr][lg*8]);
    bf16x8 pal = *reinterpret_cast<const bf16x8*>(&Pls[wv][lr][lg*8]);
#pragma unroll
    for (int g = 0; g < 4; g++){
      bf16x8 vb1 = *reinterpret_cast<const bf16x8*>(&Vhs[g*16 + lr][lg*8]);
      bf16x8 vb2 = *reinterpret_cast<const bf16x8*>(&Vls[g*16 + lr][lg*8]);
      oacc[g] = mfma16(pah, vb1, oacc[g]);
      oacc[g] = mfma16(pah, vb2, oacc[g]);
      oacc[g] = mfma16(pal, vb1, oacc[g]);
    }
    __syncthreads();
  }
#pragma unroll
  for (int g = 0; g < 4; g++)
#pragma unroll
    for (int r = 0; r < 4; r++){
      int row = qw0 + lg*4 + r;
      float v = oacc[g][r] / lrun[r];
      u16 hi = f2bf(v);
      size_t oa = ((size_t)row * NH + h) * 64 + g*16 + lr;
      aoh[oa] = hi;
      aol[oa] = f2bf(v - bf2f(hi));
    }
}

// ---------------- launch ----------------
extern "C" void kernel_launch(void* const* d_in, const int* in_sizes, int n_in,
                              void* d_out, int out_size, void* d_ws, size_t ws_size,
                              hipStream_t stream){
  const int*   x     = (const int*)d_in[0];
  const float* emb   = (const float*)d_in[1];
  const float* lnw   = (const float*)d_in[2];
  const float* fflnw = (const float*)d_in[3];
  const float* wq    = (const float*)d_in[4];
  const float* wk    = (const float*)d_in[5];
  const float* wvp   = (const float*)d_in[6];
  const float* wo    = (const float*)d_in[7];
  const float* gw    = (const float*)d_in[8];
  const float* w1    = (const float*)d_in[9];
  const float* w2    = (const float*)d_in[10];
  const float* w3    = (const float*)d_in[11];
  const float* dnw   = (const float*)d_in[12];
  float* out = (float*)d_out;

  char* p = (char*)d_ws;
  auto alloc = [&](size_t bytes)->char*{
    char* r = p; p += (bytes + 255) & ~(size_t)255; return r;
  };
  float* h    = (float*)alloc((size_t)TT * DM * 4);
  float* qbuf = (float*)alloc((size_t)TT * 1024 * 4);
  float* kbuf = (float*)alloc((size_t)TT * 512 * 4);
  float* vbuf = (float*)alloc((size_t)TT * 512 * 4);
  u16* xnh = (u16*)alloc((size_t)TT * DM * 2);
  u16* xnl = (u16*)alloc((size_t)TT * DM * 2);
  u16* qhb = (u16*)alloc((size_t)TT * 1024 * 2);
  u16* qlb = (u16*)alloc((size_t)TT * 1024 * 2);
  u16* khb = (u16*)alloc((size_t)TT * 512 * 2);
  u16* klb = (u16*)alloc((size_t)TT * 512 * 2);
  u16* vhb = (u16*)alloc((size_t)TT * 512 * 2);
  u16* vlb = (u16*)alloc((size_t)TT * 512 * 2);
  u16* aoh = (u16*)alloc((size_t)TT * 1024 * 2);
  u16* aol = (u16*)alloc((size_t)TT * 1024 * 2);
  u16* acth = (u16*)alloc((size_t)2 * TT * FFD * 2);
  u16* actl = (u16*)alloc((size_t)2 * TT * FFD * 2);
  int*   topi = (int*)alloc((size_t)2 * TT * 4);
  float* topw = (float*)alloc((size_t)2 * TT * 4);
  int* cnt  = (int*)alloc(64);
  int* offe = (int*)alloc(64);
  int* cur  = (int*)alloc(64);
  int*   ftok = (int*)alloc((size_t)2 * TT * 4);
  float* fwt  = (float*)alloc((size_t)2 * TT * 4);
  // trig tables ALIASED into aoh/aol (dead during rope phase; attn rewrites them
  // later each layer, so recompute per layer). Keeps ws footprint == R8 (proven).
  float* ctab = (float*)aoh;
  float* stab = (float*)aol;

  k_embed<<<TT, 256, 0, stream>>>(x, emb, h);

  for (int i = 0; i < 2; i++){
    const float* wq_i = wq + (size_t)i * DM * 1024;
    const float* wk_i = wk + (size_t)i * DM * 512;
    const float* wv_i = wvp + (size_t)i * DM * 512;
    const float* wo_i = wo + (size_t)i * 1024 * DM;
    const float* w1_i = w1 + (size_t)i * NE * FFD * DM;
    const float* w2_i = w2 + (size_t)i * NE * DM * FFD;
    const float* w3_i = w3 + (size_t)i * NE * FFD * DM;

    k_rmsnorm<0><<<TT, 256, 0, stream>>>(h, lnw + i * DM, xnh, xnl, nullptr);

    // fused QKV with K-split 2: zero outputs, atomicAdd epilogue (1024 blocks)
    hipMemsetAsync(qbuf, 0, (size_t)TT * 1024 * 4, stream);
    hipMemsetAsync(kbuf, 0, (size_t)TT * 512 * 4, stream);
    hipMemsetAsync(vbuf, 0, (size_t)TT * 512 * 4, stream);
    k_gemm<1,4,1,0,64,2><<<dim3(32,16,2), 256, 0, stream>>>(xnh, xnl,
        wq_i, nullptr, wk_i, wv_i, 0, 1024, DM,
        qbuf, 1024, kbuf, vbuf, nullptr, nullptr, nullptr, nullptr, nullptr, nullptr);

    // trig tables into aoh/aol space (dead here; clobbered by attn below)
    k_trig<<<TT * 32 / 256, 256, 0, stream>>>(ctab, stab);
    k_rope<16><<<4096, 256, 0, stream>>>(qbuf, ctab, stab, qhb, qlb);
    k_rope<8><<<2048, 256, 0, stream>>>(kbuf, ctab, stab, khb, klb);
    k_splitbuf<<<4096, 256, 0, stream>>>(vbuf, vhb, vlb, TT * 512);

    k_attn<<<dim3(32,16,1), 256, 0, stream>>>(qhb, qlb, khb, klb, vhb, vlb, aoh, aol);

    // WO with K-split 2 (atomicAdd residual add)
    k_gemm<1,1,1,0,64,2><<<dim3(16,16,2), 256, 0, stream>>>(aoh, aol,
        wo_i, nullptr, nullptr, nullptr, 0, DM, 1024,
        h, DM, nullptr, nullptr, nullptr, nullptr, nullptr, nullptr, nullptr, nullptr);

    k_rmsnorm<0><<<TT, 256, 0, stream>>>(h, fflnw + i * DM, xnh, xnl, nullptr);

    k_zero8<<<1, 64, 0, stream>>>(cnt);
    k_gate<<<TT/4, 256, 0, stream>>>(xnh, xnl, gw + (size_t)i * NE * DM, topi, topw, cnt);
    k_scan<<<1, 64, 0, stream>>>(cnt, offe, cur);
    k_scatter<<<8, 256, 0, stream>>>(topi, topw, offe, cur, ftok, fwt);

    if (i == 0){
      k_gemm<0,2,1,1,64,1><<<dim3(FFD/64,16,8), 256, 0, stream>>>(xnh, xnl,
          w1_i, w3_i, nullptr, nullptr, (size_t)FFD * DM, FFD, DM,
          nullptr, FFD, nullptr, nullptr, acth, actl, cnt, offe, ftok, fwt);
      k_gemm<0,3,1,0,128,4><<<dim3(DM/128,16,32), 256, 0, stream>>>(acth, actl,
          w2_i, nullptr, nullptr, nullptr, (size_t)DM * FFD, DM, FFD,
          h, DM, nullptr, nullptr, nullptr, nullptr, cnt, offe, ftok, fwt);
    } else {
      k_gemm<0,2,0,1,64,1><<<dim3(FFD/64,16,8), 256, 0, stream>>>(xnh, xnl,
          w1_i, w3_i, nullptr, nullptr, (size_t)FFD * DM, FFD, DM,
          nullptr, FFD, nullptr, nullptr, acth, actl, cnt, offe, ftok, fwt);
      k_gemm<0,3,0,0,128,4><<<dim3(DM/128,16,32), 256, 0, stream>>>(acth, actl,
          w2_i, nullptr, nullptr, nullptr, (size_t)DM * FFD, DM, FFD,
          h, DM, nullptr, nullptr, nullptr, nullptr, cnt, offe, ftok, fwt);
    }
  }

  k_rmsnorm<1><<<TT, 256, 0, stream>>>(h, dnw, nullptr, nullptr, out);
}

// Round 14
// 1469.425 us; speedup vs baseline: 1.1511x; 1.0174x over previous
//
#include <hip/hip_runtime.h>

using u16 = unsigned short;
using u32 = unsigned int;

#define TT 2048
#define DM 1024
#define NH 16
#define NKV 8
#define DHD 64
#define FFD 3584
#define NE 8

typedef __bf16 bf16x8 __attribute__((ext_vector_type(8)));
typedef float f32x4 __attribute__((ext_vector_type(4)));

// native casts -> v_cvt_pk_bf16_f32 (RNE, same results as bit trick)
__device__ __forceinline__ u16 f2bf(float x){
  return __builtin_bit_cast(u16, (__bf16)x);
}
__device__ __forceinline__ float bf2f(u16 h){
  return (float)__builtin_bit_cast(__bf16, h);
}
__device__ __forceinline__ f32x4 mfma16(bf16x8 a, bf16x8 b, f32x4 c){
  return __builtin_amdgcn_mfma_f32_16x16x32_bf16(a, b, c, 0, 0, 0);
}
__device__ __forceinline__ uint4 packhi8v(float4 a, float4 b){
  u16 h0=f2bf(a.x),h1=f2bf(a.y),h2=f2bf(a.z),h3=f2bf(a.w);
  u16 h4=f2bf(b.x),h5=f2bf(b.y),h6=f2bf(b.z),h7=f2bf(b.w);
  return make_uint4((u32)h0|((u32)h1<<16),(u32)h2|((u32)h3<<16),
                    (u32)h4|((u32)h5<<16),(u32)h6|((u32)h7<<16));
}
__device__ __forceinline__ uint4 packlo8v(float4 a, float4 b){
  u16 l0=f2bf(a.x-bf2f(f2bf(a.x))),l1=f2bf(a.y-bf2f(f2bf(a.y)));
  u16 l2=f2bf(a.z-bf2f(f2bf(a.z))),l3=f2bf(a.w-bf2f(f2bf(a.w)));
  u16 l4=f2bf(b.x-bf2f(f2bf(b.x))),l5=f2bf(b.y-bf2f(f2bf(b.y)));
  u16 l6=f2bf(b.z-bf2f(f2bf(b.z))),l7=f2bf(b.w-bf2f(f2bf(b.w)));
  return make_uint4((u32)l0|((u32)l1<<16),(u32)l2|((u32)l3<<16),
                    (u32)l4|((u32)l5<<16),(u32)l6|((u32)l7<<16));
}

// chunk-XOR swizzle: 16B chunk c (0..3) of row r stored at u16-offset SWC(r,c).
#define SWZR(r) ((((r)>>1) ^ ((r)>>3)) & 3)
#define SWC(r,c) ((((c) ^ SWZR(r))) * 8)

// async global->LDS, 16B per lane, LDS dest = wave-uniform base + lane*16
__device__ __forceinline__ void glds16(const u16* g, u16* l){
  __builtin_amdgcn_global_load_lds(
      (const __attribute__((address_space(1))) void*)g,
      (__attribute__((address_space(3))) void*)l,
      16, 0, 0);
}

// ---------------- embedding ----------------
__global__ __launch_bounds__(256) void k_embed(const int* __restrict__ x,
    const float* __restrict__ emb, float* __restrict__ h){
  int t = blockIdx.x;
  int d = threadIdx.x * 4;
  float4 v = *reinterpret_cast<const float4*>(emb + (size_t)x[t] * DM + d);
  *reinterpret_cast<float4*>(h + (size_t)t * DM + d) = v;
}

// ---------------- rmsnorm (split-bf16 out, or f32 out) ----------------
template<int OUTF32>
__global__ __launch_bounds__(256) void k_rmsnorm(const float* __restrict__ in,
    const float* __restrict__ w, u16* __restrict__ oh, u16* __restrict__ ol,
    float* __restrict__ of){
  int t = blockIdx.x;
  int d4 = threadIdx.x * 4;
  float4 xv = *reinterpret_cast<const float4*>(in + (size_t)t * DM + d4);
  float ss = xv.x*xv.x + xv.y*xv.y + xv.z*xv.z + xv.w*xv.w;
#pragma unroll
  for (int m = 1; m < 64; m <<= 1) ss += __shfl_xor(ss, m);
  __shared__ float sred[4];
  if ((threadIdx.x & 63) == 0) sred[threadIdx.x >> 6] = ss;
  __syncthreads();
  float tot = sred[0] + sred[1] + sred[2] + sred[3];
  float r = 1.0f / sqrtf(tot * (1.0f / DM) + 1e-5f);
  float vv[4] = {xv.x, xv.y, xv.z, xv.w};
#pragma unroll
  for (int jj = 0; jj < 4; jj++){
    float xn = (vv[jj] * r) * w[d4 + jj];
    size_t a = (size_t)t * DM + d4 + jj;
    if constexpr (OUTF32){
      of[a] = xn;
    } else {
      u16 hi = f2bf(xn);
      oh[a] = hi;
      ol[a] = f2bf(xn - bf2f(hi));
    }
  }
}

// ---------------- trig table (bit-identical to R8's in-rope math) ----------------
__global__ __launch_bounds__(256) void k_trig(float* __restrict__ ct, float* __restrict__ st){
  int idx = blockIdx.x * 256 + threadIdx.x;    // TT*32 entries
  int j = idx & 31;
  int s = idx >> 5;
  float xe = (float)j * 0.03125f;                 // exact: arange*2/64
  float yf = (float)pow(1.0e6, (double)xe);       // matches CR powf
  float fr = 1.0f / yf;
  float ang = (float)s * fr;                      // f32 mul like ref
  double ad = (double)ang;
  ct[idx] = (float)cos(ad);
  st[idx] = (float)sin(ad);
}

// ---------------- rope + split (table-driven) ----------------
template<int NHD>
__global__ __launch_bounds__(256) void k_rope(const float* __restrict__ in,
    const float* __restrict__ ct, const float* __restrict__ st,
    u16* __restrict__ oh, u16* __restrict__ ol){
  int idx = blockIdx.x * 256 + threadIdx.x;
  int j = idx & 31;
  int hd = (idx >> 5) % NHD;
  int s = idx / (32 * NHD);
  size_t base = ((size_t)s * NHD + hd) * 64 + 2 * j;
  float x1 = in[base], x2 = in[base + 1];
  int ti = (s << 5) | j;
  float c  = ct[ti];
  float sn = st[ti];
  float o1 = x1 * c - x2 * sn;
  float o2 = x1 * sn + x2 * c;
  u16 h1 = f2bf(o1), h2 = f2bf(o2);
  oh[base]     = h1; ol[base]     = f2bf(o1 - bf2f(h1));
  oh[base + 1] = h2; ol[base + 1] = f2bf(o2 - bf2f(h2));
}

// ---------------- plain f32 -> bf16 split ----------------
__global__ __launch_bounds__(256) void k_splitbuf(const float* __restrict__ in,
    u16* __restrict__ oh, u16* __restrict__ ol, int n){
  int i = blockIdx.x * 256 + threadIdx.x;
  if (i < n){
    float x = in[i];
    u16 hi = f2bf(x);
    oh[i] = hi;
    ol[i] = f2bf(x - bf2f(hi));
  }
}

// ---------------- gate + top2 ----------------
__global__ __launch_bounds__(256) void k_gate(const u16* __restrict__ xh,
    const u16* __restrict__ xl, const float* __restrict__ gw,
    int* __restrict__ topi, float* __restrict__ topw, int* __restrict__ cnt){
  int wv = threadIdx.x >> 6, lane = threadIdx.x & 63;
  int t = blockIdx.x * 4 + wv;
  float x[16];
#pragma unroll
  for (int i = 0; i < 16; i++){
    size_t a = (size_t)t * DM + lane + 64 * i;
    x[i] = bf2f(xh[a]) + bf2f(xl[a]);
  }
  float lgt[8];
#pragma unroll
  for (int e = 0; e < 8; e++){
    float s = 0.f;
#pragma unroll
    for (int i = 0; i < 16; i++) s += x[i] * gw[(size_t)e * DM + lane + 64 * i];
#pragma unroll
    for (int m = 1; m < 64; m <<= 1) s += __shfl_xor(s, m);
    lgt[e] = s;
  }
  float mx = lgt[0];
#pragma unroll
  for (int e = 1; e < 8; e++) mx = fmaxf(mx, lgt[e]);
  float p[8]; float sum = 0.f;
#pragma unroll
  for (int e = 0; e < 8; e++){ p[e] = expf(lgt[e] - mx); sum += p[e]; }
  float g[8];
#pragma unroll
  for (int e = 0; e < 8; e++) g[e] = p[e] / sum;   // match ref's top_k domain
  int t0 = 0; float b0 = g[0];
#pragma unroll
  for (int e = 1; e < 8; e++) if (g[e] > b0){ b0 = g[e]; t0 = e; }
  int t1 = -1; float b1 = -1.f;
#pragma unroll
  for (int e = 0; e < 8; e++) if (e != t0 && g[e] > b1){ b1 = g[e]; t1 = e; }
  float ssum = b0 + b1;
  float w0 = b0 / ssum, w1 = b1 / ssum;
  if (lane == 0 && t < TT){
    topi[2*t] = t0; topi[2*t+1] = t1;
    topw[2*t] = w0; topw[2*t+1] = w1;
    atomicAdd(&cnt[t0], 1);
    atomicAdd(&cnt[t1], 1);
  }
}

__global__ void k_zero8(int* cnt){ if (threadIdx.x < 8) cnt[threadIdx.x] = 0; }

__global__ void k_scan(const int* __restrict__ cnt, int* __restrict__ offp, int* __restrict__ cur){
  if (threadIdx.x == 0){
    int r = 0;
    for (int e = 0; e < 8; e++){ offp[e] = r; r += cnt[e]; }
  }
  if (threadIdx.x < 8) cur[threadIdx.x] = 0;
}

__global__ __launch_bounds__(256) void k_scatter(const int* __restrict__ topi,
    const float* __restrict__ topw, const int* __restrict__ offp, int* __restrict__ cur,
    int* __restrict__ ftok, float* __restrict__ fwt){
  int t = blockIdx.x * 256 + threadIdx.x;
  if (t < TT){
#pragma unroll
    for (int j = 0; j < 2; j++){
      int e = topi[2*t + j];
      int p = atomicAdd(&cur[e], 1);
      ftok[offp[e] + p] = t;
      fwt[offp[e] + p] = topw[2*t + j];
    }
  }
}

// ---------------- GEMM ----------------
// R11 raw-barrier schedule. DEEP=1 (SPLIT=0 only): two BK=32 sub-tiles per
// barrier pair (A LDS depth-4 rotation, B LDS double-tile, 2 B register sets)
// -> half the barriers, double the MFMA per barrier. SPLIT kernels: DEEP=0, R11 exact.
#define GLDSA(BUF, KK) do { \
    glds16(Ah + gaA0 + (KK), (u16*)&Ash[BUF][awr0][0]); \
    glds16(Ah + gaA1 + (KK), (u16*)&Ash[BUF][awr1][0]); \
    if constexpr (SPLIT){ \
      glds16(Al + gaA0 + (KK), (u16*)&Asl[BUF][awr0][0]); \
      glds16(Al + gaA1 + (KK), (u16*)&Asl[BUF][awr1][0]); \
    } \
  } while(0)

#define GPRELOADB(S, KK) do { \
    if constexpr (BLAYOUT == 0){ \
      const float* bp_ = Bw + (size_t)(n0 + br0) * K + (KK) + cb8; \
      S##B0 = *reinterpret_cast<const float4*>(bp_); \
      S##B1 = *reinterpret_cast<const float4*>(bp_ + 4); \
      if constexpr (TN == 128){ \
        const float* bp2_ = Bw + (size_t)(n0 + br1) * K + (KK) + cb8; \
        S##B2 = *reinterpret_cast<const float4*>(bp2_); \
        S##B3 = *reinterpret_cast<const float4*>(bp2_ + 4); \
      } \
      if constexpr (DUAL){ \
        const float* bq_ = B3w + (size_t)(n0 + br0) * K + (KK) + cb8; \
        S##B2 = *reinterpret_cast<const float4*>(bq_); \
        S##B3 = *reinterpret_cast<const float4*>(bq_ + 4); \
      } \
    } else { \
      S##B0 = *reinterpret_cast<const float4*>(Bw + (size_t)((KK) + kk1) * Nq + n0 + nn1); \
      S##B1 = *reinterpret_cast<const float4*>(Bw + (size_t)((KK) + 16 + kk1) * Nq + n0 + nn1); \
    } \
  } while(0)

#define GSTOREB(S, BB) do { \
    if constexpr (BLAYOUT == 0){ \
      *reinterpret_cast<uint4*>(&Bh1[BB][br0][swB0]) = packhi8v(S##B0, S##B1); \
      if constexpr (SPLIT) *reinterpret_cast<uint4*>(&Bl1[br0][swB0]) = packlo8v(S##B0, S##B1); \
      if constexpr (TN == 128){ \
        *reinterpret_cast<uint4*>(&Bh1[BB][br1][swB1]) = packhi8v(S##B2, S##B3); \
        if constexpr (SPLIT) *reinterpret_cast<uint4*>(&Bl1[br1][swB1]) = packlo8v(S##B2, S##B3); \
      } \
      if constexpr (DUAL){ \
        *reinterpret_cast<uint4*>(&Bh3[BB][br0][swB0]) = packhi8v(S##B2, S##B3); \
        if constexpr (SPLIT) *reinterpret_cast<uint4*>(&Bl3[br0][swB0]) = packlo8v(S##B2, S##B3); \
      } \
    } else { \
      const float* q0 = reinterpret_cast<const float*>(&S##B0); \
      const float* q1 = reinterpret_cast<const float*>(&S##B1); \
      const int ch0 = kk1 >> 3, off0 = kk1 & 7; \
      _Pragma("unroll") \
      for (int j = 0; j < 4; j++){ \
        int row = nn1 + j; \
        int c0 = SWC(row, ch0) + off0; \
        int c1 = SWC(row, ch0 + 2) + off0; \
        u16 h0 = f2bf(q0[j]); \
        Bh1[BB][row][c0] = h0; \
        if constexpr (SPLIT) Bl1[row][c0] = f2bf(q0[j] - bf2f(h0)); \
        u16 h1 = f2bf(q1[j]); \
        Bh1[BB][row][c1] = h1; \
        if constexpr (SPLIT) Bl1[row][c1] = f2bf(q1[j] - bf2f(h1)); \
      } \
    } \
  } while(0)

#define MFMA_PHASE(CURB, BB) do { \
    bf16x8 af[4], afl[4]; \
    _Pragma("unroll") \
    for (int m = 0; m < 4; m++){ \
      int Ra = wr*64 + m*16 + lr; \
      int sa = SWC(Ra, lg); \
      af[m] = *reinterpret_cast<const bf16x8*>(&Ash[CURB][Ra][sa]); \
      if constexpr (SPLIT) \
        afl[m] = *reinterpret_cast<const bf16x8*>(&Asl[CURB][Ra][sa]); \
    } \
    _Pragma("unroll") \
    for (int n = 0; n < NF; n++){ \
      int Rb = wc*(TN/2) + n*16 + lr; \
      int sb = SWC(Rb, lg); \
      bf16x8 b1 = *reinterpret_cast<const bf16x8*>(&Bh1[BB][Rb][sb]); \
      _Pragma("unroll") \
      for (int m = 0; m < 4; m++) acc[m][n] = mfma16(af[m], b1, acc[m][n]); \
      if constexpr (SPLIT){ \
        bf16x8 bl = *reinterpret_cast<const bf16x8*>(&Bl1[Rb][sb]); \
        _Pragma("unroll") \
        for (int m = 0; m < 4; m++){ \
          acc[m][n] = mfma16(af[m], bl, acc[m][n]); \
          acc[m][n] = mfma16(afl[m], b1, acc[m][n]); \
        } \
      } \
      if constexpr (DUAL){ \
        bf16x8 b3 = *reinterpret_cast<const bf16x8*>(&Bh3[BB][Rb][sb]); \
        _Pragma("unroll") \
        for (int m = 0; m < 4; m++) acc3[m][n] = mfma16(af[m], b3, acc3[m][n]); \
        if constexpr (SPLIT){ \
          bf16x8 b3l = *reinterpret_cast<const bf16x8*>(&Bl3[Rb][sb]); \
          _Pragma("unroll") \
          for (int m = 0; m < 4; m++){ \
            acc3[m][n] = mfma16(af[m], b3l, acc3[m][n]); \
            acc3[m][n] = mfma16(afl[m], b3, acc3[m][n]); \
          } \
        } \
      } \
    } \
  } while(0)

template<int BLAYOUT, int EPI, int SPLIT, int DUAL, int TN, int KS, int DEEP>
__global__ __launch_bounds__(256) void k_gemm(
    const u16* __restrict__ Ah, const u16* __restrict__ Al,
    const float* __restrict__ Bw, const float* __restrict__ B3w,
    const float* __restrict__ Bw2, const float* __restrict__ Bw3,
    size_t strideB, int N, int K,
    float* __restrict__ Cf, int ldc,
    float* __restrict__ Cf2, float* __restrict__ Cf3,
    u16* __restrict__ Ch, u16* __restrict__ Cl,
    const int* __restrict__ cntp, const int* __restrict__ offp,
    const int* __restrict__ ftok, const float* __restrict__ fwt)
{
  static_assert(!(DUAL && TN != 64), "DUAL uses TN=64");
  static_assert(!(BLAYOUT == 1 && TN != 64), "BLAYOUT=1 uses TN=64");
  static_assert(!(DEEP && SPLIT), "DEEP only for SPLIT=0 (A-LDS budget)");
  static_assert(!(DEEP && BLAYOUT == 1), "DEEP only for BLAYOUT=0");
  int cnt = TT, off = 0, ks = 0;
  if constexpr (EPI == 2 || EPI == 3){
    int e = blockIdx.z / KS;
    ks = blockIdx.z % KS;
    cnt = cntp[e]; off = offp[e];
    if ((int)blockIdx.y * 128 >= cnt) return;
    Bw += (size_t)e * strideB;
    if constexpr (DUAL) B3w += (size_t)e * strideB;
  } else if constexpr (KS > 1){
    ks = blockIdx.z;
  }
  __shared__ u16 Ash[DEEP ? 4 : 2][128][32];      // A hi (dbuf / depth-4 rotation)
  __shared__ u16 Asl[SPLIT ? 2 : 1][SPLIT ? 128 : 1][32];
  __shared__ u16 Bh1[DEEP ? 2 : 1][TN][32];
  __shared__ u16 Bl1[SPLIT ? TN : 1][32];
  __shared__ u16 Bh3[DEEP ? 2 : 1][DUAL ? TN : 1][32];
  __shared__ u16 Bl3[(DUAL && SPLIT) ? TN : 1][32];

  const int tid = threadIdx.x;
  const int m0 = blockIdx.y * 128;

  // output/N selection (fused QKV uses blockIdx.x ranges)
  int n0, Nq = N, ldq = ldc;
  float* Cq = Cf;
  if constexpr (EPI == 4){
    int bx = blockIdx.x;
    if (bx < 16){       n0 = bx * 64;        Nq = 1024; ldq = 1024; Cq = Cf;  }
    else if (bx < 24){  n0 = (bx - 16) * 64; Nq = 512;  ldq = 512;  Cq = Cf2; Bw = Bw2; }
    else {              n0 = (bx - 24) * 64; Nq = 512;  ldq = 512;  Cq = Cf3; Bw = Bw3; }
  } else {
    n0 = blockIdx.x * TN;
  }

  const int wid = tid >> 6, lane = tid & 63;
  const int wr = wid >> 1, wc = wid & 1;
  const int lr = lane & 15, lg = lane >> 4;
  constexpr int NF = TN / 32;

  // A gload_lds setup: wave wid stages rows [wid*32, wid*32+32), 2 instrs of 16 rows.
  const int awr0 = wid * 32;
  const int awr1 = wid * 32 + 16;
  const int rA0 = awr0 + (lane >> 2);
  const int rA1 = awr1 + (lane >> 2);
  const int cA0 = (lane & 3) ^ SWZR(rA0);
  const int cA1 = (lane & 3) ^ SWZR(rA1);
  int grA0, grA1;
  {
    int g0 = m0 + rA0, g1 = m0 + rA1;
    if constexpr (EPI == 2){
      grA0 = ftok[off + (g0 < cnt ? g0 : cnt - 1)];
      grA1 = ftok[off + (g1 < cnt ? g1 : cnt - 1)];
    } else if constexpr (EPI == 3){
      grA0 = off + (g0 < cnt ? g0 : cnt - 1);
      grA1 = off + (g1 < cnt ? g1 : cnt - 1);
    } else {
      grA0 = g0; grA1 = g1;
    }
  }
  const size_t gaA0 = (size_t)grA0 * K + cA0 * 8;
  const size_t gaA1 = (size_t)grA1 * K + cA1 * 8;

  // B staging (BLAYOUT=0)
  const int br0 = tid >> 2;
  const int br1 = br0 + 64;
  const int cb8 = (tid & 3) * 8;
  const int swB0 = SWC(br0, tid & 3), swB1 = SWC(br1, tid & 3);
  // BLAYOUT=1 indices
  const int kk1 = tid >> 4;
  const int nn1 = (tid & 15) * 4;

  f32x4 acc[4][NF];
  f32x4 acc3[DUAL ? 4 : 1][NF];
#pragma unroll
  for (int m = 0; m < 4; m++)
#pragma unroll
    for (int n = 0; n < NF; n++){
      acc[m][n] = f32x4{0.f,0.f,0.f,0.f};
      if constexpr (DUAL) acc3[m][n] = f32x4{0.f,0.f,0.f,0.f};
    }

  // named B staging sets (no arrays, no lambdas -> no scratch); set b only for DEEP
  float4 aB0{}, aB1{}, aB2{}, aB3{};
  float4 bB0{}, bB1{}, bB2{}, bB3{};

  const int kbeg = ks * (K / KS);
  const int kend = kbeg + (K / KS);

  if constexpr (DEEP){
    // two BK=32 sub-tiles per barrier pair; A rotates over 4 buffers
    GLDSA(0, kbeg);
    GLDSA(1, kbeg + 32);
    GPRELOADB(a, kbeg);
    GPRELOADB(b, kbeg + 32);
    int cur = 0;                      // A base buffer: 0 or 2
    for (int k0 = kbeg; k0 < kend; k0 += 64){
      GSTOREB(a, 0);
      GSTOREB(b, 1);
      asm volatile("s_waitcnt vmcnt(0) lgkmcnt(0)" ::: "memory");
      __builtin_amdgcn_s_barrier();
      if (k0 + 64 < kend){
        GLDSA(cur ^ 2, k0 + 64);      // A(k+2),A(k+3) stream during MFMA
        GLDSA((cur ^ 2) + 1, k0 + 96);
        GPRELOADB(a, k0 + 64);
        GPRELOADB(b, k0 + 96);
      }
      MFMA_PHASE(cur, 0);
      MFMA_PHASE(cur + 1, 1);
      __builtin_amdgcn_s_barrier();   // raw: prefetches stay in flight
      cur ^= 2;
    }
  } else {
    GLDSA(0, kbeg);          // A(k0) -> buf0 (async)
    GPRELOADB(a, kbeg);      // B(k0) -> regs
    int cur = 0;
    for (int k0 = kbeg; k0 < kend; k0 += 32){
      GSTOREB(a, 0);
      asm volatile("s_waitcnt vmcnt(0) lgkmcnt(0)" ::: "memory");
      __builtin_amdgcn_s_barrier();
      if (k0 + 32 < kend){
        GLDSA(cur ^ 1, k0 + 32);
        GPRELOADB(a, k0 + 32);
      }
      MFMA_PHASE(cur, 0);
      __builtin_amdgcn_s_barrier();
      cur ^= 1;
    }
  }

  // --- epilogue ---
#pragma unroll
  for (int m = 0; m < 4; m++)
#pragma unroll
    for (int n = 0; n < NF; n++)
#pragma unroll
      for (int r = 0; r < 4; r++){
        int row = m0 + wr*64 + m*16 + lg*4 + r;   // C/D: row=(lane>>4)*4+reg, col=lane&15 [m89]
        int col = n0 + wc*(TN/2) + n*16 + lr;
        float v = acc[m][n][r];
        if constexpr (EPI == 0){
          Cf[(size_t)row * ldc + col] = v;
        } else if constexpr (EPI == 1){
          if constexpr (KS > 1) atomicAdd(&Cf[(size_t)row * ldc + col], v);
          else                  Cf[(size_t)row * ldc + col] += v;
        } else if constexpr (EPI == 2){
          if (row < cnt){
            float a3 = acc3[m][n][r];
            float s = v / (1.0f + expf(-v));   // silu
            float y = s * a3;
            u16 hi = f2bf(y);
            size_t oa = (size_t)(off + row) * ldc + col;
            Ch[oa] = hi;
            Cl[oa] = f2bf(y - bf2f(hi));
          }
        } else if constexpr (EPI == 3){
          if (row < cnt){
            int tok = ftok[off + row];
            float wgt = fwt[off + row];
            atomicAdd(&Cf[(size_t)tok * ldc + col], wgt * v);
          }
        } else {
          if constexpr (KS > 1) atomicAdd(&Cq[(size_t)row * ldq + col], v);
          else                  Cq[(size_t)row * ldq + col] = v;
        }
      }
}

// ---------------- flash attention (split bf16x3) ----------------
__global__ __launch_bounds__(256) void k_attn(
    const u16* __restrict__ qh, const u16* __restrict__ ql,
    const u16* __restrict__ kh, const u16* __restrict__ kl,
    const u16* __restrict__ vh, const u16* __restrict__ vl,
    u16* __restrict__ aoh, u16* __restrict__ aol)
{
  const int h  = blockIdx.y;
  const int q0 = blockIdx.x * 64;
  const int hk = h >> 1;                 // GQA: repeat factor 2
  const int tid = threadIdx.x;
  const int wv = tid >> 6, lane = tid & 63;
  const int lr = lane & 15, lg = lane >> 4;
  const int qw0 = q0 + wv * 16;

  __shared__ u16 Khs[32][72], Kls[32][72];      // 144B rows, 16B aligned
  __shared__ u16 Vhs[64][40], Vls[64][40];      // transposed: [d][k], 80B rows
  __shared__ u16 Phs[4][16][40], Pls[4][16][40];

  bf16x8 qfh[2], qfl[2];
#pragma unroll
  for (int dc = 0; dc < 2; dc++){
    size_t qa = ((size_t)(qw0 + lr) * NH + h) * 64 + dc*32 + lg*8;
    qfh[dc] = *reinterpret_cast<const bf16x8*>(qh + qa);
    qfl[dc] = *reinterpret_cast<const bf16x8*>(ql + qa);
  }
  f32x4 oacc[4];
  float mrun[4], lrun[4];
#pragma unroll
  for (int r = 0; r < 4; r++){ mrun[r] = -1e30f; lrun[r] = 0.f; }
#pragma unroll
  for (int g = 0; g < 4; g++) oacc[g] = f32x4{0.f,0.f,0.f,0.f};

  const int nt = q0 / 32 + 2;
  for (int kt = 0; kt < nt; kt++){
    int kg = kt * 32;
    {
      int kk = tid >> 3, c8 = (tid & 7) * 8;
      size_t ka = ((size_t)(kg + kk) * NKV + hk) * 64 + c8;
      *reinterpret_cast<uint4*>(&Khs[kk][c8]) = *reinterpret_cast<const uint4*>(kh + ka);
      *reinterpret_cast<uint4*>(&Kls[kk][c8]) = *reinterpret_cast<const uint4*>(kl + ka);
      uint4 v1 = *reinterpret_cast<const uint4*>(vh + ka);
      uint4 v2 = *reinterpret_cast<const uint4*>(vl + ka);
      const u16* p1 = reinterpret_cast<const u16*>(&v1);
      const u16* p2 = reinterpret_cast<const u16*>(&v2);
#pragma unroll
      for (int j = 0; j < 8; j++){ Vhs[c8 + j][kk] = p1[j]; Vls[c8 + j][kk] = p2[j]; }
    }
    __syncthreads();

    f32x4 sc[2];
    sc[0] = f32x4{0.f,0.f,0.f,0.f};
    sc[1] = f32x4{0.f,0.f,0.f,0.f};
#pragma unroll
    for (int c = 0; c < 2; c++){
#pragma unroll
      for (int dc = 0; dc < 2; dc++){
        bf16x8 bh = *reinterpret_cast<const bf16x8*>(&Khs[c*16 + lr][dc*32 + lg*8]);
        bf16x8 bl = *reinterpret_cast<const bf16x8*>(&Kls[c*16 + lr][dc*32 + lg*8]);
        sc[c] = mfma16(qfh[dc], bh, sc[c]);
        sc[c] = mfma16(qfh[dc], bl, sc[c]);
        sc[c] = mfma16(qfl[dc], bh, sc[c]);
      }
    }
    float pnew[2][4], corr[4];
#pragma unroll
    for (int r = 0; r < 4; r++){
      int row = qw0 + lg*4 + r;
      float s0 = (kg + lr      <= row) ? sc[0][r] * 0.125f : -1e30f;
      float s1 = (kg + 16 + lr <= row) ? sc[1][r] * 0.125f : -1e30f;
      float tm = fmaxf(s0, s1);
#pragma unroll
      for (int m = 1; m < 16; m <<= 1) tm = fmaxf(tm, __shfl_xor(tm, m));
      float mnew = fmaxf(mrun[r], tm);
      corr[r] = expf(mrun[r] - mnew);
      float p0 = expf(s0 - mnew);
      float p1 = expf(s1 - mnew);
      pnew[0][r] = p0; pnew[1][r] = p1;
      float sm = p0 + p1;
#pragma unroll
      for (int m = 1; m < 16; m <<= 1) sm += __shfl_xor(sm, m);
      lrun[r] = lrun[r] * corr[r] + sm;
      mrun[r] = mnew;
    }
#pragma unroll
    for (int g = 0; g < 4; g++){
      f32x4 t = oacc[g];
#pragma unroll
      for (int r = 0; r < 4; r++) t[r] *= corr[r];
      oacc[g] = t;
    }
#pragma unroll
    for (int c = 0; c < 2; c++)
#pragma unroll
      for (int r = 0; r < 4; r++){
        float p = pnew[c][r];
        u16 hi = f2bf(p);
        Phs[wv][lg*4 + r][c*16 + lr] = hi;
        Pls[wv][lg*4 + r][c*16 + lr] = f2bf(p - bf2f(hi));
      }
    asm volatile("s_waitcnt lgkmcnt(0)" ::: "memory");
    __builtin_amdgcn_sched_barrier(0);
    bf16x8 pah = *reinterpret_cast<const bf16x8*>(&Phs[wv][lr][lg*8]);
    bf16x8 pal = *reinterpret_cast<const bf16x8*>(&Pls[wv][lr][lg*8]);
#pragma unroll
    for (int g = 0; g < 4; g++){
      bf16x8 vb1 = *reinterpret_cast<const bf16x8*>(&Vhs[g*16 + lr][lg*8]);
      bf16x8 vb2 = *reinterpret_cast<const bf16x8*>(&Vls[g*16 + lr][lg*8]);
      oacc[g] = mfma16(pah, vb1, oacc[g]);
      oacc[g] = mfma16(pah, vb2, oacc[g]);
      oacc[g] = mfma16(pal, vb1, oacc[g]);
    }
    __syncthreads();
  }
#pragma unroll
  for (int g = 0; g < 4; g++)
#pragma unroll
    for (int r = 0; r < 4; r++){
      int row = qw0 + lg*4 + r;
      float v = oacc[g][r] / lrun[r];
      u16 hi = f2bf(v);
      size_t oa = ((size_t)row * NH + h) * 64 + g*16 + lr;
      aoh[oa] = hi;
      aol[oa] = f2bf(v - bf2f(hi));
    }
}

// ---------------- launch ----------------
extern "C" void kernel_launch(void* const* d_in, const int* in_sizes, int n_in,
                              void* d_out, int out_size, void* d_ws, size_t ws_size,
                              hipStream_t stream){
  const int*   x     = (const int*)d_in[0];
  const float* emb   = (const float*)d_in[1];
  const float* lnw   = (const float*)d_in[2];
  const float* fflnw = (const float*)d_in[3];
  const float* wq    = (const float*)d_in[4];
  const float* wk    = (const float*)d_in[5];
  const float* wvp   = (const float*)d_in[6];
  const float* wo    = (const float*)d_in[7];
  const float* gw    = (const float*)d_in[8];
  const float* w1    = (const float*)d_in[9];
  const float* w2    = (const float*)d_in[10];
  const float* w3    = (const float*)d_in[11];
  const float* dnw   = (const float*)d_in[12];
  float* out = (float*)d_out;

  char* p = (char*)d_ws;
  auto alloc = [&](size_t bytes)->char*{
    char* r = p; p += (bytes + 255) & ~(size_t)255; return r;
  };
  float* h    = (float*)alloc((size_t)TT * DM * 4);
  float* qbuf = (float*)alloc((size_t)TT * 1024 * 4);
  float* kbuf = (float*)alloc((size_t)TT * 512 * 4);
  float* vbuf = (float*)alloc((size_t)TT * 512 * 4);
  u16* xnh = (u16*)alloc((size_t)TT * DM * 2);
  u16* xnl = (u16*)alloc((size_t)TT * DM * 2);
  u16* qhb = (u16*)alloc((size_t)TT * 1024 * 2);
  u16* qlb = (u16*)alloc((size_t)TT * 1024 * 2);
  u16* khb = (u16*)alloc((size_t)TT * 512 * 2);
  u16* klb = (u16*)alloc((size_t)TT * 512 * 2);
  u16* vhb = (u16*)alloc((size_t)TT * 512 * 2);
  u16* vlb = (u16*)alloc((size_t)TT * 512 * 2);
  u16* aoh = (u16*)alloc((size_t)TT * 1024 * 2);
  u16* aol = (u16*)alloc((size_t)TT * 1024 * 2);
  u16* acth = (u16*)alloc((size_t)2 * TT * FFD * 2);
  u16* actl = (u16*)alloc((size_t)2 * TT * FFD * 2);
  int*   topi = (int*)alloc((size_t)2 * TT * 4);
  float* topw = (float*)alloc((size_t)2 * TT * 4);
  int* cnt  = (int*)alloc(64);
  int* offe = (int*)alloc(64);
  int* cur  = (int*)alloc(64);
  int*   ftok = (int*)alloc((size_t)2 * TT * 4);
  float* fwt  = (float*)alloc((size_t)2 * TT * 4);
  // trig tables ALIASED into aoh/aol (dead during rope phase; attn rewrites them
  // later each layer, so recompute per layer). Keeps ws footprint == R8 (proven).
  float* ctab = (float*)aoh;
  float* stab = (float*)aol;

  k_embed<<<TT, 256, 0, stream>>>(x, emb, h);

  for (int i = 0; i < 2; i++){
    const float* wq_i = wq + (size_t)i * DM * 1024;
    const float* wk_i = wk + (size_t)i * DM * 512;
    const float* wv_i = wvp + (size_t)i * DM * 512;
    const float* wo_i = wo + (size_t)i * 1024 * DM;
    const float* w1_i = w1 + (size_t)i * NE * FFD * DM;
    const float* w2_i = w2 + (size_t)i * NE * DM * FFD;
    const float* w3_i = w3 + (size_t)i * NE * FFD * DM;

    k_rmsnorm<0><<<TT, 256, 0, stream>>>(h, lnw + i * DM, xnh, xnl, nullptr);

    // fused QKV with K-split 2: zero outputs, atomicAdd epilogue (1024 blocks)
    hipMemsetAsync(qbuf, 0, (size_t)TT * 1024 * 4, stream);
    hipMemsetAsync(kbuf, 0, (size_t)TT * 512 * 4, stream);
    hipMemsetAsync(vbuf, 0, (size_t)TT * 512 * 4, stream);
    k_gemm<1,4,1,0,64,2,0><<<dim3(32,16,2), 256, 0, stream>>>(xnh, xnl,
        wq_i, nullptr, wk_i, wv_i, 0, 1024, DM,
        qbuf, 1024, kbuf, vbuf, nullptr, nullptr, nullptr, nullptr, nullptr, nullptr);

    // trig tables into aoh/aol space (dead here; clobbered by attn below)
    k_trig<<<TT * 32 / 256, 256, 0, stream>>>(ctab, stab);
    k_rope<16><<<4096, 256, 0, stream>>>(qbuf, ctab, stab, qhb, qlb);
    k_rope<8><<<2048, 256, 0, stream>>>(kbuf, ctab, stab, khb, klb);
    k_splitbuf<<<4096, 256, 0, stream>>>(vbuf, vhb, vlb, TT * 512);

    k_attn<<<dim3(32,16,1), 256, 0, stream>>>(qhb, qlb, khb, klb, vhb, vlb, aoh, aol);

    // WO with K-split 2 (atomicAdd residual add)
    k_gemm<1,1,1,0,64,2,0><<<dim3(16,16,2), 256, 0, stream>>>(aoh, aol,
        wo_i, nullptr, nullptr, nullptr, 0, DM, 1024,
        h, DM, nullptr, nullptr, nullptr, nullptr, nullptr, nullptr, nullptr, nullptr);

    k_rmsnorm<0><<<TT, 256, 0, stream>>>(h, fflnw + i * DM, xnh, xnl, nullptr);

    k_zero8<<<1, 64, 0, stream>>>(cnt);
    k_gate<<<TT/4, 256, 0, stream>>>(xnh, xnl, gw + (size_t)i * NE * DM, topi, topw, cnt);
    k_scan<<<1, 64, 0, stream>>>(cnt, offe, cur);
    k_scatter<<<8, 256, 0, stream>>>(topi, topw, offe, cur, ftok, fwt);

    if (i == 0){
      k_gemm<0,2,1,1,64,1,0><<<dim3(FFD/64,16,8), 256, 0, stream>>>(xnh, xnl,
          w1_i, w3_i, nullptr, nullptr, (size_t)FFD * DM, FFD, DM,
          nullptr, FFD, nullptr, nullptr, acth, actl, cnt, offe, ftok, fwt);
      k_gemm<0,3,1,0,128,4,0><<<dim3(DM/128,16,32), 256, 0, stream>>>(acth, actl,
          w2_i, nullptr, nullptr, nullptr, (size_t)DM * FFD, DM, FFD,
          h, DM, nullptr, nullptr, nullptr, nullptr, cnt, offe, ftok, fwt);
    } else {
      // SPLIT=0 variants use DEEP=1: two K-halves per barrier pair
      k_gemm<0,2,0,1,64,1,1><<<dim3(FFD/64,16,8), 256, 0, stream>>>(xnh, xnl,
          w1_i, w3_i, nullptr, nullptr, (size_t)FFD * DM, FFD, DM,
          nullptr, FFD, nullptr, nullptr, acth, actl, cnt, offe, ftok, fwt);
      k_gemm<0,3,0,0,128,4,1><<<dim3(DM/128,16,32), 256, 0, stream>>>(acth, actl,
          w2_i, nullptr, nullptr, nullptr, (size_t)DM * FFD, DM, FFD,
          h, DM, nullptr, nullptr, nullptr, nullptr, cnt, offe, ftok, fwt);
    }
  }

  k_rmsnorm<1><<<TT, 256, 0, stream>>>(h, dnw, nullptr, nullptr, out);
}

// Round 15
// 1423.351 us; speedup vs baseline: 1.1883x; 1.0324x over previous
//
#include <hip/hip_runtime.h>

using u16 = unsigned short;
using u32 = unsigned int;

#define TT 2048
#define DM 1024
#define NH 16
#define NKV 8
#define DHD 64
#define FFD 3584
#define NE 8

typedef __bf16 bf16x8 __attribute__((ext_vector_type(8)));
typedef float f32x4 __attribute__((ext_vector_type(4)));

// native casts -> v_cvt_pk_bf16_f32 (RNE, same results as bit trick)
__device__ __forceinline__ u16 f2bf(float x){
  return __builtin_bit_cast(u16, (__bf16)x);
}
__device__ __forceinline__ float bf2f(u16 h){
  return (float)__builtin_bit_cast(__bf16, h);
}
__device__ __forceinline__ f32x4 mfma16(bf16x8 a, bf16x8 b, f32x4 c){
  return __builtin_amdgcn_mfma_f32_16x16x32_bf16(a, b, c, 0, 0, 0);
}
__device__ __forceinline__ uint4 packhi8v(float4 a, float4 b){
  u16 h0=f2bf(a.x),h1=f2bf(a.y),h2=f2bf(a.z),h3=f2bf(a.w);
  u16 h4=f2bf(b.x),h5=f2bf(b.y),h6=f2bf(b.z),h7=f2bf(b.w);
  return make_uint4((u32)h0|((u32)h1<<16),(u32)h2|((u32)h3<<16),
                    (u32)h4|((u32)h5<<16),(u32)h6|((u32)h7<<16));
}
__device__ __forceinline__ uint4 packlo8v(float4 a, float4 b){
  u16 l0=f2bf(a.x-bf2f(f2bf(a.x))),l1=f2bf(a.y-bf2f(f2bf(a.y)));
  u16 l2=f2bf(a.z-bf2f(f2bf(a.z))),l3=f2bf(a.w-bf2f(f2bf(a.w)));
  u16 l4=f2bf(b.x-bf2f(f2bf(b.x))),l5=f2bf(b.y-bf2f(f2bf(b.y)));
  u16 l6=f2bf(b.z-bf2f(f2bf(b.z))),l7=f2bf(b.w-bf2f(f2bf(b.w)));
  return make_uint4((u32)l0|((u32)l1<<16),(u32)l2|((u32)l3<<16),
                    (u32)l4|((u32)l5<<16),(u32)l6|((u32)l7<<16));
}

// chunk-XOR swizzle: 16B chunk c (0..3) of row r stored at u16-offset SWC(r,c).
#define SWZR(r) ((((r)>>1) ^ ((r)>>3)) & 3)
#define SWC(r,c) ((((c) ^ SWZR(r))) * 8)

// async global->LDS, 16B per lane, LDS dest = wave-uniform base + lane*16
__device__ __forceinline__ void glds16(const u16* g, u16* l){
  __builtin_amdgcn_global_load_lds(
      (const __attribute__((address_space(1))) void*)g,
      (__attribute__((address_space(3))) void*)l,
      16, 0, 0);
}

// ---------------- embedding ----------------
__global__ __launch_bounds__(256) void k_embed(const int* __restrict__ x,
    const float* __restrict__ emb, float* __restrict__ h){
  int t = blockIdx.x;
  int d = threadIdx.x * 4;
  float4 v = *reinterpret_cast<const float4*>(emb + (size_t)x[t] * DM + d);
  *reinterpret_cast<float4*>(h + (size_t)t * DM + d) = v;
}

// ---------------- rmsnorm (split-bf16 out, or f32 out; optional cnt zeroing) ----------------
template<int OUTF32>
__global__ __launch_bounds__(256) void k_rmsnorm(const float* __restrict__ in,
    const float* __restrict__ w, u16* __restrict__ oh, u16* __restrict__ ol,
    float* __restrict__ of, int* __restrict__ cntz){
  if (cntz && blockIdx.x == 0 && threadIdx.x < 8) cntz[threadIdx.x] = 0;
  int t = blockIdx.x;
  int d4 = threadIdx.x * 4;
  float4 xv = *reinterpret_cast<const float4*>(in + (size_t)t * DM + d4);
  float ss = xv.x*xv.x + xv.y*xv.y + xv.z*xv.z + xv.w*xv.w;
#pragma unroll
  for (int m = 1; m < 64; m <<= 1) ss += __shfl_xor(ss, m);
  __shared__ float sred[4];
  if ((threadIdx.x & 63) == 0) sred[threadIdx.x >> 6] = ss;
  __syncthreads();
  float tot = sred[0] + sred[1] + sred[2] + sred[3];
  float r = 1.0f / sqrtf(tot * (1.0f / DM) + 1e-5f);
  float vv[4] = {xv.x, xv.y, xv.z, xv.w};
#pragma unroll
  for (int jj = 0; jj < 4; jj++){
    float xn = (vv[jj] * r) * w[d4 + jj];
    size_t a = (size_t)t * DM + d4 + jj;
    if constexpr (OUTF32){
      of[a] = xn;
    } else {
      u16 hi = f2bf(xn);
      oh[a] = hi;
      ol[a] = f2bf(xn - bf2f(hi));
    }
  }
}

// ---------------- trig table (bit-identical to R8's in-rope math) ----------------
__global__ __launch_bounds__(256) void k_trig(float* __restrict__ ct, float* __restrict__ st){
  int idx = blockIdx.x * 256 + threadIdx.x;    // TT*32 entries
  int j = idx & 31;
  int s = idx >> 5;
  float xe = (float)j * 0.03125f;                 // exact: arange*2/64
  float yf = (float)pow(1.0e6, (double)xe);       // matches CR powf
  float fr = 1.0f / yf;
  float ang = (float)s * fr;                      // f32 mul like ref
  double ad = (double)ang;
  ct[idx] = (float)cos(ad);
  st[idx] = (float)sin(ad);
}

// ---------------- fused rope(Q) + rope(K) + split(V) ----------------
template<int NHD>
__device__ __forceinline__ void rope_body(int idx, const float* __restrict__ in,
    const float* __restrict__ ct, const float* __restrict__ st,
    u16* __restrict__ oh, u16* __restrict__ ol){
  int j = idx & 31;
  int hd = (idx >> 5) & (NHD - 1);
  int s = idx / (32 * NHD);
  size_t base = ((size_t)s * NHD + hd) * 64 + 2 * j;
  float x1 = in[base], x2 = in[base + 1];
  int ti = (s << 5) | j;
  float c  = ct[ti];
  float sn = st[ti];
  float o1 = x1 * c - x2 * sn;
  float o2 = x1 * sn + x2 * c;
  u16 h1 = f2bf(o1), h2 = f2bf(o2);
  oh[base]     = h1; ol[base]     = f2bf(o1 - bf2f(h1));
  oh[base + 1] = h2; ol[base + 1] = f2bf(o2 - bf2f(h2));
}

__global__ __launch_bounds__(256) void k_ropeall(
    const float* __restrict__ qbuf, const float* __restrict__ kbuf,
    const float* __restrict__ vbuf,
    const float* __restrict__ ct, const float* __restrict__ st,
    u16* __restrict__ qhb, u16* __restrict__ qlb,
    u16* __restrict__ khb, u16* __restrict__ klb,
    u16* __restrict__ vhb, u16* __restrict__ vlb){
  int b = blockIdx.x;
  if (b < 4096){                       // rope Q: TT*32*16 = 1M elems
    rope_body<16>(b * 256 + threadIdx.x, qbuf, ct, st, qhb, qlb);
  } else if (b < 6144){                // rope K: TT*32*8 = 0.5M elems
    rope_body<8>((b - 4096) * 256 + threadIdx.x, kbuf, ct, st, khb, klb);
  } else {                             // split V: TT*512 = 1M elems
    int i = (b - 6144) * 256 + threadIdx.x;
    float x = vbuf[i];
    u16 hi = f2bf(x);
    vhb[i] = hi;
    vlb[i] = f2bf(x - bf2f(hi));
  }
}

// ---------------- gate + top2 ----------------
__global__ __launch_bounds__(256) void k_gate(const u16* __restrict__ xh,
    const u16* __restrict__ xl, const float* __restrict__ gw,
    int* __restrict__ topi, float* __restrict__ topw, int* __restrict__ cnt){
  int wv = threadIdx.x >> 6, lane = threadIdx.x & 63;
  int t = blockIdx.x * 4 + wv;
  float x[16];
#pragma unroll
  for (int i = 0; i < 16; i++){
    size_t a = (size_t)t * DM + lane + 64 * i;
    x[i] = bf2f(xh[a]) + bf2f(xl[a]);
  }
  float lgt[8];
#pragma unroll
  for (int e = 0; e < 8; e++){
    float s = 0.f;
#pragma unroll
    for (int i = 0; i < 16; i++) s += x[i] * gw[(size_t)e * DM + lane + 64 * i];
#pragma unroll
    for (int m = 1; m < 64; m <<= 1) s += __shfl_xor(s, m);
    lgt[e] = s;
  }
  float mx = lgt[0];
#pragma unroll
  for (int e = 1; e < 8; e++) mx = fmaxf(mx, lgt[e]);
  float p[8]; float sum = 0.f;
#pragma unroll
  for (int e = 0; e < 8; e++){ p[e] = expf(lgt[e] - mx); sum += p[e]; }
  float g[8];
#pragma unroll
  for (int e = 0; e < 8; e++) g[e] = p[e] / sum;   // match ref's top_k domain
  int t0 = 0; float b0 = g[0];
#pragma unroll
  for (int e = 1; e < 8; e++) if (g[e] > b0){ b0 = g[e]; t0 = e; }
  int t1 = -1; float b1 = -1.f;
#pragma unroll
  for (int e = 0; e < 8; e++) if (e != t0 && g[e] > b1){ b1 = g[e]; t1 = e; }
  float ssum = b0 + b1;
  float w0 = b0 / ssum, w1 = b1 / ssum;
  if (lane == 0 && t < TT){
    topi[2*t] = t0; topi[2*t+1] = t1;
    topw[2*t] = w0; topw[2*t+1] = w1;
    atomicAdd(&cnt[t0], 1);
    atomicAdd(&cnt[t1], 1);
  }
}

// ---------------- fused scan + scatter: 8 blocks, block e builds expert e's list ----------------
__global__ __launch_bounds__(256) void k_build(const int* __restrict__ cnt,
    const int* __restrict__ topi, const float* __restrict__ topw,
    int* __restrict__ offp, int* __restrict__ ftok, float* __restrict__ fwt){
  int e = blockIdx.x;
  int off = 0;
  for (int i = 0; i < e; i++) off += cnt[i];
  __shared__ int pos;
  if (threadIdx.x == 0){ offp[e] = off; pos = 0; }
  __syncthreads();
  for (int t0 = 0; t0 < TT; t0 += 256){
    int t = t0 + threadIdx.x;
    int i0 = topi[2*t], i1 = topi[2*t+1];
    if (i0 == e){ int p = atomicAdd(&pos, 1); ftok[off+p] = t; fwt[off+p] = topw[2*t]; }
    if (i1 == e){ int p = atomicAdd(&pos, 1); ftok[off+p] = t; fwt[off+p] = topw[2*t+1]; }
  }
}

// ---------------- GEMM ----------------
// R11 raw-barrier schedule. DEEP=1 (SPLIT=0 only): two BK=32 sub-tiles per
// barrier pair (A LDS depth-4 rotation, B LDS double-tile, 2 B register sets)
// -> half the barriers, double the MFMA per barrier. SPLIT kernels: DEEP=0.
#define GLDSA(BUF, KK) do { \
    glds16(Ah + gaA0 + (KK), (u16*)&Ash[BUF][awr0][0]); \
    glds16(Ah + gaA1 + (KK), (u16*)&Ash[BUF][awr1][0]); \
    if constexpr (SPLIT){ \
      glds16(Al + gaA0 + (KK), (u16*)&Asl[BUF][awr0][0]); \
      glds16(Al + gaA1 + (KK), (u16*)&Asl[BUF][awr1][0]); \
    } \
  } while(0)

#define GPRELOADB(S, KK) do { \
    if constexpr (BLAYOUT == 0){ \
      const float* bp_ = Bw + (size_t)(n0 + br0) * K + (KK) + cb8; \
      S##B0 = *reinterpret_cast<const float4*>(bp_); \
      S##B1 = *reinterpret_cast<const float4*>(bp_ + 4); \
      if constexpr (TN == 128){ \
        const float* bp2_ = Bw + (size_t)(n0 + br1) * K + (KK) + cb8; \
        S##B2 = *reinterpret_cast<const float4*>(bp2_); \
        S##B3 = *reinterpret_cast<const float4*>(bp2_ + 4); \
      } \
      if constexpr (DUAL){ \
        const float* bq_ = B3w + (size_t)(n0 + br0) * K + (KK) + cb8; \
        S##B2 = *reinterpret_cast<const float4*>(bq_); \
        S##B3 = *reinterpret_cast<const float4*>(bq_ + 4); \
      } \
    } else { \
      S##B0 = *reinterpret_cast<const float4*>(Bw + (size_t)((KK) + kk1) * Nq + n0 + nn1); \
      S##B1 = *reinterpret_cast<const float4*>(Bw + (size_t)((KK) + 16 + kk1) * Nq + n0 + nn1); \
    } \
  } while(0)

#define GSTOREB(S, BB) do { \
    if constexpr (BLAYOUT == 0){ \
      *reinterpret_cast<uint4*>(&Bh1[BB][br0][swB0]) = packhi8v(S##B0, S##B1); \
      if constexpr (SPLIT) *reinterpret_cast<uint4*>(&Bl1[br0][swB0]) = packlo8v(S##B0, S##B1); \
      if constexpr (TN == 128){ \
        *reinterpret_cast<uint4*>(&Bh1[BB][br1][swB1]) = packhi8v(S##B2, S##B3); \
        if constexpr (SPLIT) *reinterpret_cast<uint4*>(&Bl1[br1][swB1]) = packlo8v(S##B2, S##B3); \
      } \
      if constexpr (DUAL){ \
        *reinterpret_cast<uint4*>(&Bh3[BB][br0][swB0]) = packhi8v(S##B2, S##B3); \
        if constexpr (SPLIT) *reinterpret_cast<uint4*>(&Bl3[br0][swB0]) = packlo8v(S##B2, S##B3); \
      } \
    } else { \
      const float* q0 = reinterpret_cast<const float*>(&S##B0); \
      const float* q1 = reinterpret_cast<const float*>(&S##B1); \
      const int ch0 = kk1 >> 3, off0 = kk1 & 7; \
      _Pragma("unroll") \
      for (int j = 0; j < 4; j++){ \
        int row = nn1 + j; \
        int c0 = SWC(row, ch0) + off0; \
        int c1 = SWC(row, ch0 + 2) + off0; \
        u16 h0 = f2bf(q0[j]); \
        Bh1[BB][row][c0] = h0; \
        if constexpr (SPLIT) Bl1[row][c0] = f2bf(q0[j] - bf2f(h0)); \
        u16 h1 = f2bf(q1[j]); \
        Bh1[BB][row][c1] = h1; \
        if constexpr (SPLIT) Bl1[row][c1] = f2bf(q1[j] - bf2f(h1)); \
      } \
    } \
  } while(0)

#define MFMA_PHASE(CURB, BB) do { \
    bf16x8 af[4], afl[4]; \
    _Pragma("unroll") \
    for (int m = 0; m < 4; m++){ \
      int Ra = wr*64 + m*16 + lr; \
      int sa = SWC(Ra, lg); \
      af[m] = *reinterpret_cast<const bf16x8*>(&Ash[CURB][Ra][sa]); \
      if constexpr (SPLIT) \
        afl[m] = *reinterpret_cast<const bf16x8*>(&Asl[CURB][Ra][sa]); \
    } \
    _Pragma("unroll") \
    for (int n = 0; n < NF; n++){ \
      int Rb = wc*(TN/2) + n*16 + lr; \
      int sb = SWC(Rb, lg); \
      bf16x8 b1 = *reinterpret_cast<const bf16x8*>(&Bh1[BB][Rb][sb]); \
      _Pragma("unroll") \
      for (int m = 0; m < 4; m++) acc[m][n] = mfma16(af[m], b1, acc[m][n]); \
      if constexpr (SPLIT){ \
        bf16x8 bl = *reinterpret_cast<const bf16x8*>(&Bl1[Rb][sb]); \
        _Pragma("unroll") \
        for (int m = 0; m < 4; m++){ \
          acc[m][n] = mfma16(af[m], bl, acc[m][n]); \
          acc[m][n] = mfma16(afl[m], b1, acc[m][n]); \
        } \
      } \
      if constexpr (DUAL){ \
        bf16x8 b3 = *reinterpret_cast<const bf16x8*>(&Bh3[BB][Rb][sb]); \
        _Pragma("unroll") \
        for (int m = 0; m < 4; m++) acc3[m][n] = mfma16(af[m], b3, acc3[m][n]); \
        if constexpr (SPLIT){ \
          bf16x8 b3l = *reinterpret_cast<const bf16x8*>(&Bl3[Rb][sb]); \
          _Pragma("unroll") \
          for (int m = 0; m < 4; m++){ \
            acc3[m][n] = mfma16(af[m], b3l, acc3[m][n]); \
            acc3[m][n] = mfma16(afl[m], b3, acc3[m][n]); \
          } \
        } \
      } \
    } \
  } while(0)

template<int BLAYOUT, int EPI, int SPLIT, int DUAL, int TN, int KS, int DEEP>
__global__ __launch_bounds__(256) void k_gemm(
    const u16* __restrict__ Ah, const u16* __restrict__ Al,
    const float* __restrict__ Bw, const float* __restrict__ B3w,
    const float* __restrict__ Bw2, const float* __restrict__ Bw3,
    size_t strideB, int N, int K,
    float* __restrict__ Cf, int ldc,
    float* __restrict__ Cf2, float* __restrict__ Cf3,
    u16* __restrict__ Ch, u16* __restrict__ Cl,
    const int* __restrict__ cntp, const int* __restrict__ offp,
    const int* __restrict__ ftok, const float* __restrict__ fwt)
{
  static_assert(!(DUAL && TN != 64), "DUAL uses TN=64");
  static_assert(!(BLAYOUT == 1 && TN != 64), "BLAYOUT=1 uses TN=64");
  static_assert(!(DEEP && SPLIT), "DEEP only for SPLIT=0 (A-LDS budget)");
  static_assert(!(DEEP && BLAYOUT == 1), "DEEP only for BLAYOUT=0");
  int cnt = TT, off = 0, ks = 0;
  if constexpr (EPI == 2 || EPI == 3){
    int e = blockIdx.z / KS;
    ks = blockIdx.z % KS;
    cnt = cntp[e]; off = offp[e];
    if ((int)blockIdx.y * 128 >= cnt) return;
    Bw += (size_t)e * strideB;
    if constexpr (DUAL) B3w += (size_t)e * strideB;
  } else if constexpr (KS > 1){
    ks = blockIdx.z;
  }
  __shared__ u16 Ash[DEEP ? 4 : 2][128][32];      // A hi (dbuf / depth-4 rotation)
  __shared__ u16 Asl[SPLIT ? 2 : 1][SPLIT ? 128 : 1][32];
  __shared__ u16 Bh1[DEEP ? 2 : 1][TN][32];
  __shared__ u16 Bl1[SPLIT ? TN : 1][32];
  __shared__ u16 Bh3[DEEP ? 2 : 1][DUAL ? TN : 1][32];
  __shared__ u16 Bl3[(DUAL && SPLIT) ? TN : 1][32];

  const int tid = threadIdx.x;
  const int m0 = blockIdx.y * 128;

  // output/N selection (fused QKV uses blockIdx.x ranges)
  int n0, Nq = N, ldq = ldc;
  float* Cq = Cf;
  if constexpr (EPI == 4){
    int bx = blockIdx.x;
    if (bx < 16){       n0 = bx * 64;        Nq = 1024; ldq = 1024; Cq = Cf;  }
    else if (bx < 24){  n0 = (bx - 16) * 64; Nq = 512;  ldq = 512;  Cq = Cf2; Bw = Bw2; }
    else {              n0 = (bx - 24) * 64; Nq = 512;  ldq = 512;  Cq = Cf3; Bw = Bw3; }
  } else {
    n0 = blockIdx.x * TN;
  }

  const int wid = tid >> 6, lane = tid & 63;
  const int wr = wid >> 1, wc = wid & 1;
  const int lr = lane & 15, lg = lane >> 4;
  constexpr int NF = TN / 32;

  // A gload_lds setup: wave wid stages rows [wid*32, wid*32+32), 2 instrs of 16 rows.
  const int awr0 = wid * 32;
  const int awr1 = wid * 32 + 16;
  const int rA0 = awr0 + (lane >> 2);
  const int rA1 = awr1 + (lane >> 2);
  const int cA0 = (lane & 3) ^ SWZR(rA0);
  const int cA1 = (lane & 3) ^ SWZR(rA1);
  int grA0, grA1;
  {
    int g0 = m0 + rA0, g1 = m0 + rA1;
    if constexpr (EPI == 2){
      grA0 = ftok[off + (g0 < cnt ? g0 : cnt - 1)];
      grA1 = ftok[off + (g1 < cnt ? g1 : cnt - 1)];
    } else if constexpr (EPI == 3){
      grA0 = off + (g0 < cnt ? g0 : cnt - 1);
      grA1 = off + (g1 < cnt ? g1 : cnt - 1);
    } else {
      grA0 = g0; grA1 = g1;
    }
  }
  const size_t gaA0 = (size_t)grA0 * K + cA0 * 8;
  const size_t gaA1 = (size_t)grA1 * K + cA1 * 8;

  // B staging (BLAYOUT=0)
  const int br0 = tid >> 2;
  const int br1 = br0 + 64;
  const int cb8 = (tid & 3) * 8;
  const int swB0 = SWC(br0, tid & 3), swB1 = SWC(br1, tid & 3);
  // BLAYOUT=1 indices
  const int kk1 = tid >> 4;
  const int nn1 = (tid & 15) * 4;

  f32x4 acc[4][NF];
  f32x4 acc3[DUAL ? 4 : 1][NF];
#pragma unroll
  for (int m = 0; m < 4; m++)
#pragma unroll
    for (int n = 0; n < NF; n++){
      acc[m][n] = f32x4{0.f,0.f,0.f,0.f};
      if constexpr (DUAL) acc3[m][n] = f32x4{0.f,0.f,0.f,0.f};
    }

  // named B staging sets (no arrays, no lambdas -> no scratch); set b only for DEEP
  float4 aB0{}, aB1{}, aB2{}, aB3{};
  float4 bB0{}, bB1{}, bB2{}, bB3{};

  const int kbeg = ks * (K / KS);
  const int kend = kbeg + (K / KS);

  if constexpr (DEEP){
    // two BK=32 sub-tiles per barrier pair; A rotates over 4 buffers
    GLDSA(0, kbeg);
    GLDSA(1, kbeg + 32);
    GPRELOADB(a, kbeg);
    GPRELOADB(b, kbeg + 32);
    int cur = 0;                      // A base buffer: 0 or 2
    for (int k0 = kbeg; k0 < kend; k0 += 64){
      GSTOREB(a, 0);
      GSTOREB(b, 1);
      asm volatile("s_waitcnt vmcnt(0) lgkmcnt(0)" ::: "memory");
      __builtin_amdgcn_s_barrier();
      if (k0 + 64 < kend){
        GLDSA(cur ^ 2, k0 + 64);      // A(k+2),A(k+3) stream during MFMA
        GLDSA((cur ^ 2) + 1, k0 + 96);
        GPRELOADB(a, k0 + 64);
        GPRELOADB(b, k0 + 96);
      }
      MFMA_PHASE(cur, 0);
      MFMA_PHASE(cur + 1, 1);
      __builtin_amdgcn_s_barrier();   // raw: prefetches stay in flight
      cur ^= 2;
    }
  } else {
    GLDSA(0, kbeg);          // A(k0) -> buf0 (async)
    GPRELOADB(a, kbeg);      // B(k0) -> regs
    int cur = 0;
    for (int k0 = kbeg; k0 < kend; k0 += 32){
      GSTOREB(a, 0);
      asm volatile("s_waitcnt vmcnt(0) lgkmcnt(0)" ::: "memory");
      __builtin_amdgcn_s_barrier();
      if (k0 + 32 < kend){
        GLDSA(cur ^ 1, k0 + 32);
        GPRELOADB(a, k0 + 32);
      }
      MFMA_PHASE(cur, 0);
      __builtin_amdgcn_s_barrier();
      cur ^= 1;
    }
  }

  // --- epilogue ---
#pragma unroll
  for (int m = 0; m < 4; m++)
#pragma unroll
    for (int n = 0; n < NF; n++)
#pragma unroll
      for (int r = 0; r < 4; r++){
        int row = m0 + wr*64 + m*16 + lg*4 + r;   // C/D: row=(lane>>4)*4+reg, col=lane&15 [m89]
        int col = n0 + wc*(TN/2) + n*16 + lr;
        float v = acc[m][n][r];
        if constexpr (EPI == 0){
          Cf[(size_t)row * ldc + col] = v;
        } else if constexpr (EPI == 1){
          if constexpr (KS > 1) atomicAdd(&Cf[(size_t)row * ldc + col], v);
          else                  Cf[(size_t)row * ldc + col] += v;
        } else if constexpr (EPI == 2){
          if (row < cnt){
            float a3 = acc3[m][n][r];
            float s = v / (1.0f + expf(-v));   // silu
            float y = s * a3;
            u16 hi = f2bf(y);
            size_t oa = (size_t)(off + row) * ldc + col;
            Ch[oa] = hi;
            Cl[oa] = f2bf(y - bf2f(hi));
          }
        } else if constexpr (EPI == 3){
          if (row < cnt){
            int tok = ftok[off + row];
            float wgt = fwt[off + row];
            atomicAdd(&Cf[(size_t)tok * ldc + col], wgt * v);
          }
        } else {
          if constexpr (KS > 1) atomicAdd(&Cq[(size_t)row * ldq + col], v);
          else                  Cq[(size_t)row * ldq + col] = v;
        }
      }
}

// ---------------- flash attention (split bf16x3) ----------------
__global__ __launch_bounds__(256) void k_attn(
    const u16* __restrict__ qh, const u16* __restrict__ ql,
    const u16* __restrict__ kh, const u16* __restrict__ kl,
    const u16* __restrict__ vh, const u16* __restrict__ vl,
    u16* __restrict__ aoh, u16* __restrict__ aol)
{
  const int h  = blockIdx.y;
  const int q0 = blockIdx.x * 64;
  const int hk = h >> 1;                 // GQA: repeat factor 2
  const int tid = threadIdx.x;
  const int wv = tid >> 6, lane = tid & 63;
  const int lr = lane & 15, lg = lane >> 4;
  const int qw0 = q0 + wv * 16;

  __shared__ u16 Khs[32][72], Kls[32][72];      // 144B rows, 16B aligned
  __shared__ u16 Vhs[64][40], Vls[64][40];      // transposed: [d][k], 80B rows
  __shared__ u16 Phs[4][16][40], Pls[4][16][40];

  bf16x8 qfh[2], qfl[2];
#pragma unroll
  for (int dc = 0; dc < 2; dc++){
    size_t qa = ((size_t)(qw0 + lr) * NH + h) * 64 + dc*32 + lg*8;
    qfh[dc] = *reinterpret_cast<const bf16x8*>(qh + qa);
    qfl[dc] = *reinterpret_cast<const bf16x8*>(ql + qa);
  }
  f32x4 oacc[4];
  float mrun[4], lrun[4];
#pragma unroll
  for (int r = 0; r < 4; r++){ mrun[r] = -1e30f; lrun[r] = 0.f; }
#pragma unroll
  for (int g = 0; g < 4; g++) oacc[g] = f32x4{0.f,0.f,0.f,0.f};

  const int nt = q0 / 32 + 2;
  for (int kt = 0; kt < nt; kt++){
    int kg = kt * 32;
    {
      int kk = tid >> 3, c8 = (tid & 7) * 8;
      size_t ka = ((size_t)(kg + kk) * NKV + hk) * 64 + c8;
      *reinterpret_cast<uint4*>(&Khs[kk][c8]) = *reinterpret_cast<const uint4*>(kh + ka);
      *reinterpret_cast<uint4*>(&Kls[kk][c8]) = *reinterpret_cast<const uint4*>(kl + ka);
      uint4 v1 = *reinterpret_cast<const uint4*>(vh + ka);
      uint4 v2 = *reinterpret_cast<const uint4*>(vl + ka);
      const u16* p1 = reinterpret_cast<const u16*>(&v1);
      const u16* p2 = reinterpret_cast<const u16*>(&v2);
#pragma unroll
      for (int j = 0; j < 8; j++){ Vhs[c8 + j][kk] = p1[j]; Vls[c8 + j][kk] = p2[j]; }
    }
    __syncthreads();

    f32x4 sc[2];
    sc[0] = f32x4{0.f,0.f,0.f,0.f};
    sc[1] = f32x4{0.f,0.f,0.f,0.f};
#pragma unroll
    for (int c = 0; c < 2; c++){
#pragma unroll
      for (int dc = 0; dc < 2; dc++){
        bf16x8 bh = *reinterpret_cast<const bf16x8*>(&Khs[c*16 + lr][dc*32 + lg*8]);
        bf16x8 bl = *reinterpret_cast<const bf16x8*>(&Kls[c*16 + lr][dc*32 + lg*8]);
        sc[c] = mfma16(qfh[dc], bh, sc[c]);
        sc[c] = mfma16(qfh[dc], bl, sc[c]);
        sc[c] = mfma16(qfl[dc], bh, sc[c]);
      }
    }
    float pnew[2][4], corr[4];
#pragma unroll
    for (int r = 0; r < 4; r++){
      int row = qw0 + lg*4 + r;
      float s0 = (kg + lr      <= row) ? sc[0][r] * 0.125f : -1e30f;
      float s1 = (kg + 16 + lr <= row) ? sc[1][r] * 0.125f : -1e30f;
      float tm = fmaxf(s0, s1);
#pragma unroll
      for (int m = 1; m < 16; m <<= 1) tm = fmaxf(tm, __shfl_xor(tm, m));
      float mnew = fmaxf(mrun[r], tm);
      corr[r] = expf(mrun[r] - mnew);
      float p0 = expf(s0 - mnew);
      float p1 = expf(s1 - mnew);
      pnew[0][r] = p0; pnew[1][r] = p1;
      float sm = p0 + p1;
#pragma unroll
      for (int m = 1; m < 16; m <<= 1) sm += __shfl_xor(sm, m);
      lrun[r] = lrun[r] * corr[r] + sm;
      mrun[r] = mnew;
    }
#pragma unroll
    for (int g = 0; g < 4; g++){
      f32x4 t = oacc[g];
#pragma unroll
      for (int r = 0; r < 4; r++) t[r] *= corr[r];
      oacc[g] = t;
    }
#pragma unroll
    for (int c = 0; c < 2; c++)
#pragma unroll
      for (int r = 0; r < 4; r++){
        float p = pnew[c][r];
        u16 hi = f2bf(p);
        Phs[wv][lg*4 + r][c*16 + lr] = hi;
        Pls[wv][lg*4 + r][c*16 + lr] = f2bf(p - bf2f(hi));
      }
    asm volatile("s_waitcnt lgkmcnt(0)" ::: "memory");
    __builtin_amdgcn_sched_barrier(0);
    bf16x8 pah = *reinterpret_cast<const bf16x8*>(&Phs[wv][lr][lg*8]);
    bf16x8 pal = *reinterpret_cast<const bf16x8*>(&Pls[wv][lr][lg*8]);
#pragma unroll
    for (int g = 0; g < 4; g++){
      bf16x8 vb1 = *reinterpret_cast<const bf16x8*>(&Vhs[g*16 + lr][lg*8]);
      bf16x8 vb2 = *reinterpret_cast<const bf16x8*>(&Vls[g*16 + lr][lg*8]);
      oacc[g] = mfma16(pah, vb1, oacc[g]);
      oacc[g] = mfma16(pah, vb2, oacc[g]);
      oacc[g] = mfma16(pal, vb1, oacc[g]);
    }
    __syncthreads();
  }
#pragma unroll
  for (int g = 0; g < 4; g++)
#pragma unroll
    for (int r = 0; r < 4; r++){
      int row = qw0 + lg*4 + r;
      float v = oacc[g][r] / lrun[r];
      u16 hi = f2bf(v);
      size_t oa = ((size_t)row * NH + h) * 64 + g*16 + lr;
      aoh[oa] = hi;
      aol[oa] = f2bf(v - bf2f(hi));
    }
}

// ---------------- launch ----------------
extern "C" void kernel_launch(void* const* d_in, const int* in_sizes, int n_in,
                              void* d_out, int out_size, void* d_ws, size_t ws_size,
                              hipStream_t stream){
  const int*   x     = (const int*)d_in[0];
  const float* emb   = (const float*)d_in[1];
  const float* lnw   = (const float*)d_in[2];
  const float* fflnw = (const float*)d_in[3];
  const float* wq    = (const float*)d_in[4];
  const float* wk    = (const float*)d_in[5];
  const float* wvp   = (const float*)d_in[6];
  const float* wo    = (const float*)d_in[7];
  const float* gw    = (const float*)d_in[8];
  const float* w1    = (const float*)d_in[9];
  const float* w2    = (const float*)d_in[10];
  const float* w3    = (const float*)d_in[11];
  const float* dnw   = (const float*)d_in[12];
  float* out = (float*)d_out;

  char* p = (char*)d_ws;
  auto alloc = [&](size_t bytes)->char*{
    char* r = p; p += (bytes + 255) & ~(size_t)255; return r;
  };
  float* h    = (float*)alloc((size_t)TT * DM * 4);
  float* qbuf = (float*)alloc((size_t)TT * 1024 * 4);
  float* kbuf = (float*)alloc((size_t)TT * 512 * 4);
  float* vbuf = (float*)alloc((size_t)TT * 512 * 4);
  u16* xnh = (u16*)alloc((size_t)TT * DM * 2);
  u16* xnl = (u16*)alloc((size_t)TT * DM * 2);
  u16* qhb = (u16*)alloc((size_t)TT * 1024 * 2);
  u16* qlb = (u16*)alloc((size_t)TT * 1024 * 2);
  u16* khb = (u16*)alloc((size_t)TT * 512 * 2);
  u16* klb = (u16*)alloc((size_t)TT * 512 * 2);
  u16* vhb = (u16*)alloc((size_t)TT * 512 * 2);
  u16* vlb = (u16*)alloc((size_t)TT * 512 * 2);
  u16* aoh = (u16*)alloc((size_t)TT * 1024 * 2);
  u16* aol = (u16*)alloc((size_t)TT * 1024 * 2);
  u16* acth = (u16*)alloc((size_t)2 * TT * FFD * 2);
  u16* actl = (u16*)alloc((size_t)2 * TT * FFD * 2);
  int*   topi = (int*)alloc((size_t)2 * TT * 4);
  float* topw = (float*)alloc((size_t)2 * TT * 4);
  int* cnt  = (int*)alloc(64);
  int* offe = (int*)alloc(64);
  int* cur  = (int*)alloc(64);
  int*   ftok = (int*)alloc((size_t)2 * TT * 4);
  float* fwt  = (float*)alloc((size_t)2 * TT * 4);
  // trig tables ALIASED into aoh/aol (dead during rope phase; attn rewrites them
  // later each layer, so recompute per layer). Keeps ws footprint == proven level.
  float* ctab = (float*)aoh;
  float* stab = (float*)aol;
  (void)cur;

  k_embed<<<TT, 256, 0, stream>>>(x, emb, h);

  for (int i = 0; i < 2; i++){
    const float* wq_i = wq + (size_t)i * DM * 1024;
    const float* wk_i = wk + (size_t)i * DM * 512;
    const float* wv_i = wvp + (size_t)i * DM * 512;
    const float* wo_i = wo + (size_t)i * 1024 * DM;
    const float* w1_i = w1 + (size_t)i * NE * FFD * DM;
    const float* w2_i = w2 + (size_t)i * NE * DM * FFD;
    const float* w3_i = w3 + (size_t)i * NE * FFD * DM;

    k_rmsnorm<0><<<TT, 256, 0, stream>>>(h, lnw + i * DM, xnh, xnl, nullptr, nullptr);

    // fused QKV with K-split 2: zero outputs (one contiguous 16 MB memset), atomicAdd epilogue
    hipMemsetAsync(qbuf, 0, (size_t)TT * 2048 * 4, stream);   // covers qbuf+kbuf+vbuf (contiguous)
    k_gemm<1,4,1,0,64,2,0><<<dim3(32,16,2), 256, 0, stream>>>(xnh, xnl,
        wq_i, nullptr, wk_i, wv_i, 0, 1024, DM,
        qbuf, 1024, kbuf, vbuf, nullptr, nullptr, nullptr, nullptr, nullptr, nullptr);

    // trig tables into aoh/aol space (dead here; clobbered by attn below)
    k_trig<<<TT * 32 / 256, 256, 0, stream>>>(ctab, stab);
    // fused rope(Q)+rope(K)+split(V)
    k_ropeall<<<4096 + 2048 + 4096, 256, 0, stream>>>(qbuf, kbuf, vbuf,
        ctab, stab, qhb, qlb, khb, klb, vhb, vlb);

    k_attn<<<dim3(32,16,1), 256, 0, stream>>>(qhb, qlb, khb, klb, vhb, vlb, aoh, aol);

    // WO with K-split 2 (atomicAdd residual add)
    k_gemm<1,1,1,0,64,2,0><<<dim3(16,16,2), 256, 0, stream>>>(aoh, aol,
        wo_i, nullptr, nullptr, nullptr, 0, DM, 1024,
        h, DM, nullptr, nullptr, nullptr, nullptr, nullptr, nullptr, nullptr, nullptr);

    // ffln rmsnorm; block 0 also zeroes cnt for the gate
    k_rmsnorm<0><<<TT, 256, 0, stream>>>(h, fflnw + i * DM, xnh, xnl, nullptr, cnt);

    k_gate<<<TT/4, 256, 0, stream>>>(xnh, xnl, gw + (size_t)i * NE * DM, topi, topw, cnt);
    k_build<<<8, 256, 0, stream>>>(cnt, topi, topw, offe, ftok, fwt);

    if (i == 0){
      k_gemm<0,2,1,1,64,1,0><<<dim3(FFD/64,16,8), 256, 0, stream>>>(xnh, xnl,
          w1_i, w3_i, nullptr, nullptr, (size_t)FFD * DM, FFD, DM,
          nullptr, FFD, nullptr, nullptr, acth, actl, cnt, offe, ftok, fwt);
      k_gemm<0,3,1,0,128,4,0><<<dim3(DM/128,16,32), 256, 0, stream>>>(acth, actl,
          w2_i, nullptr, nullptr, nullptr, (size_t)DM * FFD, DM, FFD,
          h, DM, nullptr, nullptr, nullptr, nullptr, cnt, offe, ftok, fwt);
    } else {
      // SPLIT=0 variants use DEEP=1: two K-halves per barrier pair
      k_gemm<0,2,0,1,64,1,1><<<dim3(FFD/64,16,8), 256, 0, stream>>>(xnh, xnl,
          w1_i, w3_i, nullptr, nullptr, (size_t)FFD * DM, FFD, DM,
          nullptr, FFD, nullptr, nullptr, acth, actl, cnt, offe, ftok, fwt);
      k_gemm<0,3,0,0,128,4,1><<<dim3(DM/128,16,32), 256, 0, stream>>>(acth, actl,
          w2_i, nullptr, nullptr, nullptr, (size_t)DM * FFD, DM, FFD,
          h, DM, nullptr, nullptr, nullptr, nullptr, cnt, offe, ftok, fwt);
    }
  }

  k_rmsnorm<1><<<TT, 256, 0, stream>>>(h, dnw, nullptr, nullptr, out, nullptr);
}

// Round 16
// 1414.843 us; speedup vs baseline: 1.1955x; 1.0060x over previous
//
#include <hip/hip_runtime.h>

using u16 = unsigned short;
using u32 = unsigned int;

#define TT 2048
#define DM 1024
#define NH 16
#define NKV 8
#define DHD 64
#define FFD 3584
#define NE 8

typedef __bf16 bf16x8 __attribute__((ext_vector_type(8)));
typedef float f32x4 __attribute__((ext_vector_type(4)));

// native casts -> v_cvt_pk_bf16_f32 (RNE, same results as bit trick)
__device__ __forceinline__ u16 f2bf(float x){
  return __builtin_bit_cast(u16, (__bf16)x);
}
__device__ __forceinline__ float bf2f(u16 h){
  return (float)__builtin_bit_cast(__bf16, h);
}
__device__ __forceinline__ f32x4 mfma16(bf16x8 a, bf16x8 b, f32x4 c){
  return __builtin_amdgcn_mfma_f32_16x16x32_bf16(a, b, c, 0, 0, 0);
}
__device__ __forceinline__ uint4 packhi8v(float4 a, float4 b){
  u16 h0=f2bf(a.x),h1=f2bf(a.y),h2=f2bf(a.z),h3=f2bf(a.w);
  u16 h4=f2bf(b.x),h5=f2bf(b.y),h6=f2bf(b.z),h7=f2bf(b.w);
  return make_uint4((u32)h0|((u32)h1<<16),(u32)h2|((u32)h3<<16),
                    (u32)h4|((u32)h5<<16),(u32)h6|((u32)h7<<16));
}
__device__ __forceinline__ uint4 packlo8v(float4 a, float4 b){
  u16 l0=f2bf(a.x-bf2f(f2bf(a.x))),l1=f2bf(a.y-bf2f(f2bf(a.y)));
  u16 l2=f2bf(a.z-bf2f(f2bf(a.z))),l3=f2bf(a.w-bf2f(f2bf(a.w)));
  u16 l4=f2bf(b.x-bf2f(f2bf(b.x))),l5=f2bf(b.y-bf2f(f2bf(b.y)));
  u16 l6=f2bf(b.z-bf2f(f2bf(b.z))),l7=f2bf(b.w-bf2f(f2bf(b.w)));
  return make_uint4((u32)l0|((u32)l1<<16),(u32)l2|((u32)l3<<16),
                    (u32)l4|((u32)l5<<16),(u32)l6|((u32)l7<<16));
}

// chunk-XOR swizzle: 16B chunk c (0..3) of row r stored at u16-offset SWC(r,c).
#define SWZR(r) ((((r)>>1) ^ ((r)>>3)) & 3)
#define SWC(r,c) ((((c) ^ SWZR(r))) * 8)

// async global->LDS, 16B per lane, LDS dest = wave-uniform base + lane*16
__device__ __forceinline__ void glds16(const u16* g, u16* l){
  __builtin_amdgcn_global_load_lds(
      (const __attribute__((address_space(1))) void*)g,
      (__attribute__((address_space(3))) void*)l,
      16, 0, 0);
}

// ---------------- embedding ----------------
__global__ __launch_bounds__(256) void k_embed(const int* __restrict__ x,
    const float* __restrict__ emb, float* __restrict__ h){
  int t = blockIdx.x;
  int d = threadIdx.x * 4;
  float4 v = *reinterpret_cast<const float4*>(emb + (size_t)x[t] * DM + d);
  *reinterpret_cast<float4*>(h + (size_t)t * DM + d) = v;
}

// ---------------- rmsnorm (split-bf16 out or f32 out; GATE=1 fuses MoE top-2 gate) ----------------
template<int OUTF32, int GATE>
__global__ __launch_bounds__(256) void k_rmsnorm(const float* __restrict__ in,
    const float* __restrict__ w, u16* __restrict__ oh, u16* __restrict__ ol,
    float* __restrict__ of,
    const float* __restrict__ gw, int* __restrict__ topi,
    float* __restrict__ topw, int* __restrict__ cnt){
  int t = blockIdx.x;
  int d4 = threadIdx.x * 4;
  float4 xv = *reinterpret_cast<const float4*>(in + (size_t)t * DM + d4);
  float ss = xv.x*xv.x + xv.y*xv.y + xv.z*xv.z + xv.w*xv.w;
#pragma unroll
  for (int m = 1; m < 64; m <<= 1) ss += __shfl_xor(ss, m);
  __shared__ float sred[4];
  if ((threadIdx.x & 63) == 0) sred[threadIdx.x >> 6] = ss;
  __syncthreads();
  float tot = sred[0] + sred[1] + sred[2] + sred[3];
  float r = 1.0f / sqrtf(tot * (1.0f / DM) + 1e-5f);
  float vv[4] = {xv.x, xv.y, xv.z, xv.w};
  float xnv[4];
#pragma unroll
  for (int jj = 0; jj < 4; jj++){
    float xn = (vv[jj] * r) * w[d4 + jj];
    xnv[jj] = xn;
    size_t a = (size_t)t * DM + d4 + jj;
    if constexpr (OUTF32){
      of[a] = xn;
    } else {
      u16 hi = f2bf(xn);
      oh[a] = hi;
      ol[a] = f2bf(xn - bf2f(hi));
    }
  }
  if constexpr (GATE){
    float part[8];
#pragma unroll
    for (int e = 0; e < 8; e++){
      float s = 0.f;
#pragma unroll
      for (int jj = 0; jj < 4; jj++) s += xnv[jj] * gw[(size_t)e * DM + d4 + jj];
#pragma unroll
      for (int m = 1; m < 64; m <<= 1) s += __shfl_xor(s, m);
      part[e] = s;
    }
    __shared__ float gred[4][8];
    if ((threadIdx.x & 63) == 0){
#pragma unroll
      for (int e = 0; e < 8; e++) gred[threadIdx.x >> 6][e] = part[e];
    }
    __syncthreads();
    if (threadIdx.x == 0){
      float lgt[8];
#pragma unroll
      for (int e = 0; e < 8; e++)
        lgt[e] = gred[0][e] + gred[1][e] + gred[2][e] + gred[3][e];
      float mx = lgt[0];
#pragma unroll
      for (int e = 1; e < 8; e++) mx = fmaxf(mx, lgt[e]);
      float pe[8]; float sum = 0.f;
#pragma unroll
      for (int e = 0; e < 8; e++){ pe[e] = expf(lgt[e] - mx); sum += pe[e]; }
      float g[8];
#pragma unroll
      for (int e = 0; e < 8; e++) g[e] = pe[e] / sum;
      int t0 = 0; float b0 = g[0];
#pragma unroll
      for (int e = 1; e < 8; e++) if (g[e] > b0){ b0 = g[e]; t0 = e; }
      int t1 = -1; float b1 = -1.f;
#pragma unroll
      for (int e = 0; e < 8; e++) if (e != t0 && g[e] > b1){ b1 = g[e]; t1 = e; }
      float ssum = b0 + b1;
      topi[2*t] = t0; topi[2*t+1] = t1;
      topw[2*t] = b0 / ssum; topw[2*t+1] = b1 / ssum;
      atomicAdd(&cnt[t0], 1);
      atomicAdd(&cnt[t1], 1);
    }
  }
}

// ---------------- trig table (bit-identical to R8's in-rope math) ----------------
__global__ __launch_bounds__(256) void k_trig(float* __restrict__ ct, float* __restrict__ st){
  int idx = blockIdx.x * 256 + threadIdx.x;    // TT*32 entries
  int j = idx & 31;
  int s = idx >> 5;
  float xe = (float)j * 0.03125f;                 // exact: arange*2/64
  float yf = (float)pow(1.0e6, (double)xe);       // matches CR powf
  float fr = 1.0f / yf;
  float ang = (float)s * fr;                      // f32 mul like ref
  double ad = (double)ang;
  ct[idx] = (float)cos(ad);
  st[idx] = (float)sin(ad);
}

// ---------------- fused rope(Q) + rope(K) + split(V) ----------------
template<int NHD>
__device__ __forceinline__ void rope_body(int idx, const float* __restrict__ in,
    const float* __restrict__ ct, const float* __restrict__ st,
    u16* __restrict__ oh, u16* __restrict__ ol){
  int j = idx & 31;
  int hd = (idx >> 5) & (NHD - 1);
  int s = idx / (32 * NHD);
  size_t base = ((size_t)s * NHD + hd) * 64 + 2 * j;
  float x1 = in[base], x2 = in[base + 1];
  int ti = (s << 5) | j;
  float c  = ct[ti];
  float sn = st[ti];
  float o1 = x1 * c - x2 * sn;
  float o2 = x1 * sn + x2 * c;
  u16 h1 = f2bf(o1), h2 = f2bf(o2);
  oh[base]     = h1; ol[base]     = f2bf(o1 - bf2f(h1));
  oh[base + 1] = h2; ol[base + 1] = f2bf(o2 - bf2f(h2));
}

__global__ __launch_bounds__(256) void k_ropeall(
    const float* __restrict__ qbuf, const float* __restrict__ kbuf,
    const float* __restrict__ vbuf,
    const float* __restrict__ ct, const float* __restrict__ st,
    u16* __restrict__ qhb, u16* __restrict__ qlb,
    u16* __restrict__ khb, u16* __restrict__ klb,
    u16* __restrict__ vhb, u16* __restrict__ vlb){
  int b = blockIdx.x;
  if (b < 4096){                       // rope Q: TT*32*16 = 1M elems
    rope_body<16>(b * 256 + threadIdx.x, qbuf, ct, st, qhb, qlb);
  } else if (b < 6144){                // rope K: TT*32*8 = 0.5M elems
    rope_body<8>((b - 4096) * 256 + threadIdx.x, kbuf, ct, st, khb, klb);
  } else {                             // split V: TT*512 = 1M elems
    int i = (b - 6144) * 256 + threadIdx.x;
    float x = vbuf[i];
    u16 hi = f2bf(x);
    vhb[i] = hi;
    vlb[i] = f2bf(x - bf2f(hi));
  }
}

// ---------------- fused scan + scatter: 8 blocks, block e builds expert e's list ----------------
__global__ __launch_bounds__(256) void k_build(const int* __restrict__ cnt,
    const int* __restrict__ topi, const float* __restrict__ topw,
    int* __restrict__ offp, int* __restrict__ ftok, float* __restrict__ fwt){
  int e = blockIdx.x;
  int off = 0;
  for (int i = 0; i < e; i++) off += cnt[i];
  __shared__ int pos;
  if (threadIdx.x == 0){ offp[e] = off; pos = 0; }
  __syncthreads();
  for (int t0 = 0; t0 < TT; t0 += 256){
    int t = t0 + threadIdx.x;
    int i0 = topi[2*t], i1 = topi[2*t+1];
    if (i0 == e){ int p = atomicAdd(&pos, 1); ftok[off+p] = t; fwt[off+p] = topw[2*t]; }
    if (i1 == e){ int p = atomicAdd(&pos, 1); ftok[off+p] = t; fwt[off+p] = topw[2*t+1]; }
  }
}

// ---------------- GEMM ----------------
// R11 raw-barrier schedule. DEEP=1 (SPLIT=0 only): two BK=32 sub-tiles per
// barrier pair (A LDS depth-4 rotation, B LDS double-tile, 2 B register sets)
// -> half the barriers, double the MFMA per barrier. SPLIT kernels: DEEP=0.
#define GLDSA(BUF, KK) do { \
    glds16(Ah + gaA0 + (KK), (u16*)&Ash[BUF][awr0][0]); \
    glds16(Ah + gaA1 + (KK), (u16*)&Ash[BUF][awr1][0]); \
    if constexpr (SPLIT){ \
      glds16(Al + gaA0 + (KK), (u16*)&Asl[BUF][awr0][0]); \
      glds16(Al + gaA1 + (KK), (u16*)&Asl[BUF][awr1][0]); \
    } \
  } while(0)

#define GPRELOADB(S, KK) do { \
    if constexpr (BLAYOUT == 0){ \
      const float* bp_ = Bw + (size_t)(n0 + br0) * K + (KK) + cb8; \
      S##B0 = *reinterpret_cast<const float4*>(bp_); \
      S##B1 = *reinterpret_cast<const float4*>(bp_ + 4); \
      if constexpr (TN == 128){ \
        const float* bp2_ = Bw + (size_t)(n0 + br1) * K + (KK) + cb8; \
        S##B2 = *reinterpret_cast<const float4*>(bp2_); \
        S##B3 = *reinterpret_cast<const float4*>(bp2_ + 4); \
      } \
      if constexpr (DUAL){ \
        const float* bq_ = B3w + (size_t)(n0 + br0) * K + (KK) + cb8; \
        S##B2 = *reinterpret_cast<const float4*>(bq_); \
        S##B3 = *reinterpret_cast<const float4*>(bq_ + 4); \
      } \
    } else { \
      S##B0 = *reinterpret_cast<const float4*>(Bw + (size_t)((KK) + kk1) * Nq + n0 + nn1); \
      S##B1 = *reinterpret_cast<const float4*>(Bw + (size_t)((KK) + 16 + kk1) * Nq + n0 + nn1); \
    } \
  } while(0)

#define GSTOREB(S, BB) do { \
    if constexpr (BLAYOUT == 0){ \
      *reinterpret_cast<uint4*>(&Bh1[BB][br0][swB0]) = packhi8v(S##B0, S##B1); \
      if constexpr (SPLIT) *reinterpret_cast<uint4*>(&Bl1[br0][swB0]) = packlo8v(S##B0, S##B1); \
      if constexpr (TN == 128){ \
        *reinterpret_cast<uint4*>(&Bh1[BB][br1][swB1]) = packhi8v(S##B2, S##B3); \
        if constexpr (SPLIT) *reinterpret_cast<uint4*>(&Bl1[br1][swB1]) = packlo8v(S##B2, S##B3); \
      } \
      if constexpr (DUAL){ \
        *reinterpret_cast<uint4*>(&Bh3[BB][br0][swB0]) = packhi8v(S##B2, S##B3); \
        if constexpr (SPLIT) *reinterpret_cast<uint4*>(&Bl3[br0][swB0]) = packlo8v(S##B2, S##B3); \
      } \
    } else { \
      const float* q0 = reinterpret_cast<const float*>(&S##B0); \
      const float* q1 = reinterpret_cast<const float*>(&S##B1); \
      const int ch0 = kk1 >> 3, off0 = kk1 & 7; \
      _Pragma("unroll") \
      for (int j = 0; j < 4; j++){ \
        int row = nn1 + j; \
        int c0 = SWC(row, ch0) + off0; \
        int c1 = SWC(row, ch0 + 2) + off0; \
        u16 h0 = f2bf(q0[j]); \
        Bh1[BB][row][c0] = h0; \
        if constexpr (SPLIT) Bl1[row][c0] = f2bf(q0[j] - bf2f(h0)); \
        u16 h1 = f2bf(q1[j]); \
        Bh1[BB][row][c1] = h1; \
        if constexpr (SPLIT) Bl1[row][c1] = f2bf(q1[j] - bf2f(h1)); \
      } \
    } \
  } while(0)

#define MFMA_PHASE(CURB, BB) do { \
    bf16x8 af[4], afl[4]; \
    _Pragma("unroll") \
    for (int m = 0; m < 4; m++){ \
      int Ra = wr*64 + m*16 + lr; \
      int sa = SWC(Ra, lg); \
      af[m] = *reinterpret_cast<const bf16x8*>(&Ash[CURB][Ra][sa]); \
      if constexpr (SPLIT) \
        afl[m] = *reinterpret_cast<const bf16x8*>(&Asl[CURB][Ra][sa]); \
    } \
    _Pragma("unroll") \
    for (int n = 0; n < NF; n++){ \
      int Rb = wc*(TN/2) + n*16 + lr; \
      int sb = SWC(Rb, lg); \
      bf16x8 b1 = *reinterpret_cast<const bf16x8*>(&Bh1[BB][Rb][sb]); \
      _Pragma("unroll") \
      for (int m = 0; m < 4; m++) acc[m][n] = mfma16(af[m], b1, acc[m][n]); \
      if constexpr (SPLIT){ \
        bf16x8 bl = *reinterpret_cast<const bf16x8*>(&Bl1[Rb][sb]); \
        _Pragma("unroll") \
        for (int m = 0; m < 4; m++){ \
          acc[m][n] = mfma16(af[m], bl, acc[m][n]); \
          acc[m][n] = mfma16(afl[m], b1, acc[m][n]); \
        } \
      } \
      if constexpr (DUAL){ \
        bf16x8 b3 = *reinterpret_cast<const bf16x8*>(&Bh3[BB][Rb][sb]); \
        _Pragma("unroll") \
        for (int m = 0; m < 4; m++) acc3[m][n] = mfma16(af[m], b3, acc3[m][n]); \
        if constexpr (SPLIT){ \
          bf16x8 b3l = *reinterpret_cast<const bf16x8*>(&Bl3[Rb][sb]); \
          _Pragma("unroll") \
          for (int m = 0; m < 4; m++){ \
            acc3[m][n] = mfma16(af[m], b3l, acc3[m][n]); \
            acc3[m][n] = mfma16(afl[m], b3, acc3[m][n]); \
          } \
        } \
      } \
    } \
  } while(0)

template<int BLAYOUT, int EPI, int SPLIT, int DUAL, int TN, int KS, int DEEP>
__global__ __launch_bounds__(256) void k_gemm(
    const u16* __restrict__ Ah, const u16* __restrict__ Al,
    const float* __restrict__ Bw, const float* __restrict__ B3w,
    const float* __restrict__ Bw2, const float* __restrict__ Bw3,
    size_t strideB, int N, int K,
    float* __restrict__ Cf, int ldc,
    float* __restrict__ Cf2, float* __restrict__ Cf3,
    u16* __restrict__ Ch, u16* __restrict__ Cl,
    const int* __restrict__ cntp, const int* __restrict__ offp,
    const int* __restrict__ ftok, const float* __restrict__ fwt)
{
  static_assert(!(DUAL && TN != 64), "DUAL uses TN=64");
  static_assert(!(BLAYOUT == 1 && TN != 64), "BLAYOUT=1 uses TN=64");
  static_assert(!(DEEP && SPLIT), "DEEP only for SPLIT=0 (A-LDS budget)");
  static_assert(!(DEEP && BLAYOUT == 1), "DEEP only for BLAYOUT=0");
  int cnt = TT, off = 0, ks = 0;
  if constexpr (EPI == 2 || EPI == 3){
    int e = blockIdx.z / KS;
    ks = blockIdx.z % KS;
    cnt = cntp[e]; off = offp[e];
    if ((int)blockIdx.y * 128 >= cnt) return;
    Bw += (size_t)e * strideB;
    if constexpr (DUAL) B3w += (size_t)e * strideB;
  } else if constexpr (KS > 1){
    ks = blockIdx.z;
  }
  __shared__ u16 Ash[DEEP ? 4 : 2][128][32];      // A hi (dbuf / depth-4 rotation)
  __shared__ u16 Asl[SPLIT ? 2 : 1][SPLIT ? 128 : 1][32];
  __shared__ u16 Bh1[DEEP ? 2 : 1][TN][32];
  __shared__ u16 Bl1[SPLIT ? TN : 1][32];
  __shared__ u16 Bh3[DEEP ? 2 : 1][DUAL ? TN : 1][32];
  __shared__ u16 Bl3[(DUAL && SPLIT) ? TN : 1][32];

  const int tid = threadIdx.x;
  const int m0 = blockIdx.y * 128;

  // output/N selection (fused QKV uses blockIdx.x ranges)
  int n0, Nq = N, ldq = ldc;
  float* Cq = Cf;
  if constexpr (EPI == 4){
    int bx = blockIdx.x;
    if (bx < 16){       n0 = bx * 64;        Nq = 1024; ldq = 1024; Cq = Cf;  }
    else if (bx < 24){  n0 = (bx - 16) * 64; Nq = 512;  ldq = 512;  Cq = Cf2; Bw = Bw2; }
    else {              n0 = (bx - 24) * 64; Nq = 512;  ldq = 512;  Cq = Cf3; Bw = Bw3; }
  } else {
    n0 = blockIdx.x * TN;
  }

  const int wid = tid >> 6, lane = tid & 63;
  const int wr = wid >> 1, wc = wid & 1;
  const int lr = lane & 15, lg = lane >> 4;
  constexpr int NF = TN / 32;

  // A gload_lds setup: wave wid stages rows [wid*32, wid*32+32), 2 instrs of 16 rows.
  const int awr0 = wid * 32;
  const int awr1 = wid * 32 + 16;
  const int rA0 = awr0 + (lane >> 2);
  const int rA1 = awr1 + (lane >> 2);
  const int cA0 = (lane & 3) ^ SWZR(rA0);
  const int cA1 = (lane & 3) ^ SWZR(rA1);
  int grA0, grA1;
  {
    int g0 = m0 + rA0, g1 = m0 + rA1;
    if constexpr (EPI == 2){
      grA0 = ftok[off + (g0 < cnt ? g0 : cnt - 1)];
      grA1 = ftok[off + (g1 < cnt ? g1 : cnt - 1)];
    } else if constexpr (EPI == 3){
      grA0 = off + (g0 < cnt ? g0 : cnt - 1);
      grA1 = off + (g1 < cnt ? g1 : cnt - 1);
    } else {
      grA0 = g0; grA1 = g1;
    }
  }
  const size_t gaA0 = (size_t)grA0 * K + cA0 * 8;
  const size_t gaA1 = (size_t)grA1 * K + cA1 * 8;

  // B staging (BLAYOUT=0)
  const int br0 = tid >> 2;
  const int br1 = br0 + 64;
  const int cb8 = (tid & 3) * 8;
  const int swB0 = SWC(br0, tid & 3), swB1 = SWC(br1, tid & 3);
  // BLAYOUT=1 indices
  const int kk1 = tid >> 4;
  const int nn1 = (tid & 15) * 4;

  f32x4 acc[4][NF];
  f32x4 acc3[DUAL ? 4 : 1][NF];
#pragma unroll
  for (int m = 0; m < 4; m++)
#pragma unroll
    for (int n = 0; n < NF; n++){
      acc[m][n] = f32x4{0.f,0.f,0.f,0.f};
      if constexpr (DUAL) acc3[m][n] = f32x4{0.f,0.f,0.f,0.f};
    }

  // named B staging sets (no arrays, no lambdas -> no scratch); set b only for DEEP
  float4 aB0{}, aB1{}, aB2{}, aB3{};
  float4 bB0{}, bB1{}, bB2{}, bB3{};

  const int kbeg = ks * (K / KS);
  const int kend = kbeg + (K / KS);

  if constexpr (DEEP){
    // two BK=32 sub-tiles per barrier pair; A rotates over 4 buffers
    GLDSA(0, kbeg);
    GLDSA(1, kbeg + 32);
    GPRELOADB(a, kbeg);
    GPRELOADB(b, kbeg + 32);
    int cur = 0;                      // A base buffer: 0 or 2
    for (int k0 = kbeg; k0 < kend; k0 += 64){
      GSTOREB(a, 0);
      GSTOREB(b, 1);
      asm volatile("s_waitcnt vmcnt(0) lgkmcnt(0)" ::: "memory");
      __builtin_amdgcn_s_barrier();
      if (k0 + 64 < kend){
        GLDSA(cur ^ 2, k0 + 64);      // A(k+2),A(k+3) stream during MFMA
        GLDSA((cur ^ 2) + 1, k0 + 96);
        GPRELOADB(a, k0 + 64);
        GPRELOADB(b, k0 + 96);
      }
      MFMA_PHASE(cur, 0);
      MFMA_PHASE(cur + 1, 1);
      __builtin_amdgcn_s_barrier();   // raw: prefetches stay in flight
      cur ^= 2;
    }
  } else {
    GLDSA(0, kbeg);          // A(k0) -> buf0 (async)
    GPRELOADB(a, kbeg);      // B(k0) -> regs
    int cur = 0;
    for (int k0 = kbeg; k0 < kend; k0 += 32){
      GSTOREB(a, 0);
      asm volatile("s_waitcnt vmcnt(0) lgkmcnt(0)" ::: "memory");
      __builtin_amdgcn_s_barrier();
      if (k0 + 32 < kend){
        GLDSA(cur ^ 1, k0 + 32);
        GPRELOADB(a, k0 + 32);
      }
      MFMA_PHASE(cur, 0);
      __builtin_amdgcn_s_barrier();
      cur ^= 1;
    }
  }

  // --- epilogue ---
#pragma unroll
  for (int m = 0; m < 4; m++)
#pragma unroll
    for (int n = 0; n < NF; n++)
#pragma unroll
      for (int r = 0; r < 4; r++){
        int row = m0 + wr*64 + m*16 + lg*4 + r;   // C/D: row=(lane>>4)*4+reg, col=lane&15 [m89]
        int col = n0 + wc*(TN/2) + n*16 + lr;
        float v = acc[m][n][r];
        if constexpr (EPI == 0){
          Cf[(size_t)row * ldc + col] = v;
        } else if constexpr (EPI == 1){
          if constexpr (KS > 1) atomicAdd(&Cf[(size_t)row * ldc + col], v);
          else                  Cf[(size_t)row * ldc + col] += v;
        } else if constexpr (EPI == 2){
          if (row < cnt){
            float a3 = acc3[m][n][r];
            float s = v / (1.0f + expf(-v));   // silu
            float y = s * a3;
            u16 hi = f2bf(y);
            size_t oa = (size_t)(off + row) * ldc + col;
            Ch[oa] = hi;
            Cl[oa] = f2bf(y - bf2f(hi));
          }
        } else if constexpr (EPI == 3){
          if (row < cnt){
            int tok = ftok[off + row];
            float wgt = fwt[off + row];
            atomicAdd(&Cf[(size_t)tok * ldc + col], wgt * v);
          }
        } else {
          if constexpr (KS > 1) atomicAdd(&Cq[(size_t)row * ldq + col], v);
          else                  Cq[(size_t)row * ldq + col] = v;
        }
      }
}

// ---------------- flash attention (split bf16x3; longest q-blocks first) ----------------
__global__ __launch_bounds__(256) void k_attn(
    const u16* __restrict__ qh, const u16* __restrict__ ql,
    const u16* __restrict__ kh, const u16* __restrict__ kl,
    const u16* __restrict__ vh, const u16* __restrict__ vl,
    u16* __restrict__ aoh, u16* __restrict__ aol, int* __restrict__ cntz)
{
  if (blockIdx.x == 0 && blockIdx.y == 0 && threadIdx.x < 8) cntz[threadIdx.x] = 0;
  const int h  = blockIdx.y;
  const int q0 = (int)(gridDim.x - 1 - blockIdx.x) * 64;   // longest first
  const int hk = h >> 1;                 // GQA: repeat factor 2
  const int tid = threadIdx.x;
  const int wv = tid >> 6, lane = tid & 63;
  const int lr = lane & 15, lg = lane >> 4;
  const int qw0 = q0 + wv * 16;

  __shared__ u16 Khs[32][72], Kls[32][72];      // 144B rows, 16B aligned
  __shared__ u16 Vhs[64][40], Vls[64][40];      // transposed: [d][k], 80B rows
  __shared__ u16 Phs[4][16][40], Pls[4][16][40];

  bf16x8 qfh[2], qfl[2];
#pragma unroll
  for (int dc = 0; dc < 2; dc++){
    size_t qa = ((size_t)(qw0 + lr) * NH + h) * 64 + dc*32 + lg*8;
    qfh[dc] = *reinterpret_cast<const bf16x8*>(qh + qa);
    qfl[dc] = *reinterpret_cast<const bf16x8*>(ql + qa);
  }
  f32x4 oacc[4];
  float mrun[4], lrun[4];
#pragma unroll
  for (int r = 0; r < 4; r++){ mrun[r] = -1e30f; lrun[r] = 0.f; }
#pragma unroll
  for (int g = 0; g < 4; g++) oacc[g] = f32x4{0.f,0.f,0.f,0.f};

  const int nt = q0 / 32 + 2;
  for (int kt = 0; kt < nt; kt++){
    int kg = kt * 32;
    {
      int kk = tid >> 3, c8 = (tid & 7) * 8;
      size_t ka = ((size_t)(kg + kk) * NKV + hk) * 64 + c8;
      *reinterpret_cast<uint4*>(&Khs[kk][c8]) = *reinterpret_cast<const uint4*>(kh + ka);
      *reinterpret_cast<uint4*>(&Kls[kk][c8]) = *reinterpret_cast<const uint4*>(kl + ka);
      uint4 v1 = *reinterpret_cast<const uint4*>(vh + ka);
      uint4 v2 = *reinterpret_cast<const uint4*>(vl + ka);
      const u16* p1 = reinterpret_cast<const u16*>(&v1);
      const u16* p2 = reinterpret_cast<const u16*>(&v2);
#pragma unroll
      for (int j = 0; j < 8; j++){ Vhs[c8 + j][kk] = p1[j]; Vls[c8 + j][kk] = p2[j]; }
    }
    __syncthreads();

    f32x4 sc[2];
    sc[0] = f32x4{0.f,0.f,0.f,0.f};
    sc[1] = f32x4{0.f,0.f,0.f,0.f};
#pragma unroll
    for (int c = 0; c < 2; c++){
#pragma unroll
      for (int dc = 0; dc < 2; dc++){
        bf16x8 bh = *reinterpret_cast<const bf16x8*>(&Khs[c*16 + lr][dc*32 + lg*8]);
        bf16x8 bl = *reinterpret_cast<const bf16x8*>(&Kls[c*16 + lr][dc*32 + lg*8]);
        sc[c] = mfma16(qfh[dc], bh, sc[c]);
        sc[c] = mfma16(qfh[dc], bl, sc[c]);
        sc[c] = mfma16(qfl[dc], bh, sc[c]);
      }
    }
    float pnew[2][4], corr[4];
#pragma unroll
    for (int r = 0; r < 4; r++){
      int row = qw0 + lg*4 + r;
      float s0 = (kg + lr      <= row) ? sc[0][r] * 0.125f : -1e30f;
      float s1 = (kg + 16 + lr <= row) ? sc[1][r] * 0.125f : -1e30f;
      float tm = fmaxf(s0, s1);
#pragma unroll
      for (int m = 1; m < 16; m <<= 1) tm = fmaxf(tm, __shfl_xor(tm, m));
      float mnew = fmaxf(mrun[r], tm);
      corr[r] = expf(mrun[r] - mnew);
      float p0 = expf(s0 - mnew);
      float p1 = expf(s1 - mnew);
      pnew[0][r] = p0; pnew[1][r] = p1;
      float sm = p0 + p1;
#pragma unroll
      for (int m = 1; m < 16; m <<= 1) sm += __shfl_xor(sm, m);
      lrun[r] = lrun[r] * corr[r] + sm;
      mrun[r] = mnew;
    }
#pragma unroll
    for (int g = 0; g < 4; g++){
      f32x4 t = oacc[g];
#pragma unroll
      for (int r = 0; r < 4; r++) t[r] *= corr[r];
      oacc[g] = t;
    }
#pragma unroll
    for (int c = 0; c < 2; c++)
#pragma unroll
      for (int r = 0; r < 4; r++){
        float p = pnew[c][r];
        u16 hi = f2bf(p);
        Phs[wv][lg*4 + r][c*16 + lr] = hi;
        Pls[wv][lg*4 + r][c*16 + lr] = f2bf(p - bf2f(hi));
      }
    asm volatile("s_waitcnt lgkmcnt(0)" ::: "memory");
    __builtin_amdgcn_sched_barrier(0);
    bf16x8 pah = *reinterpret_cast<const bf16x8*>(&Phs[wv][lr][lg*8]);
    bf16x8 pal = *reinterpret_cast<const bf16x8*>(&Pls[wv][lr][lg*8]);
#pragma unroll
    for (int g = 0; g < 4; g++){
      bf16x8 vb1 = *reinterpret_cast<const bf16x8*>(&Vhs[g*16 + lr][lg*8]);
      bf16x8 vb2 = *reinterpret_cast<const bf16x8*>(&Vls[g*16 + lr][lg*8]);
      oacc[g] = mfma16(pah, vb1, oacc[g]);
      oacc[g] = mfma16(pah, vb2, oacc[g]);
      oacc[g] = mfma16(pal, vb1, oacc[g]);
    }
    __syncthreads();
  }
#pragma unroll
  for (int g = 0; g < 4; g++)
#pragma unroll
    for (int r = 0; r < 4; r++){
      int row = qw0 + lg*4 + r;
      float v = oacc[g][r] / lrun[r];
      u16 hi = f2bf(v);
      size_t oa = ((size_t)row * NH + h) * 64 + g*16 + lr;
      aoh[oa] = hi;
      aol[oa] = f2bf(v - bf2f(hi));
    }
}

// ---------------- launch ----------------
extern "C" void kernel_launch(void* const* d_in, const int* in_sizes, int n_in,
                              void* d_out, int out_size, void* d_ws, size_t ws_size,
                              hipStream_t stream){
  const int*   x     = (const int*)d_in[0];
  const float* emb   = (const float*)d_in[1];
  const float* lnw   = (const float*)d_in[2];
  const float* fflnw = (const float*)d_in[3];
  const float* wq    = (const float*)d_in[4];
  const float* wk    = (const float*)d_in[5];
  const float* wvp   = (const float*)d_in[6];
  const float* wo    = (const float*)d_in[7];
  const float* gw    = (const float*)d_in[8];
  const float* w1    = (const float*)d_in[9];
  const float* w2    = (const float*)d_in[10];
  const float* w3    = (const float*)d_in[11];
  const float* dnw   = (const float*)d_in[12];
  float* out = (float*)d_out;

  char* p = (char*)d_ws;
  auto alloc = [&](size_t bytes)->char*{
    char* r = p; p += (bytes + 255) & ~(size_t)255; return r;
  };
  float* h    = (float*)alloc((size_t)TT * DM * 4);
  float* qbuf = (float*)alloc((size_t)TT * 1024 * 4);
  float* kbuf = (float*)alloc((size_t)TT * 512 * 4);
  float* vbuf = (float*)alloc((size_t)TT * 512 * 4);
  u16* xnh = (u16*)alloc((size_t)TT * DM * 2);
  u16* xnl = (u16*)alloc((size_t)TT * DM * 2);
  u16* qhb = (u16*)alloc((size_t)TT * 1024 * 2);
  u16* qlb = (u16*)alloc((size_t)TT * 1024 * 2);
  u16* khb = (u16*)alloc((size_t)TT * 512 * 2);
  u16* klb = (u16*)alloc((size_t)TT * 512 * 2);
  u16* vhb = (u16*)alloc((size_t)TT * 512 * 2);
  u16* vlb = (u16*)alloc((size_t)TT * 512 * 2);
  u16* aoh = (u16*)alloc((size_t)TT * 1024 * 2);
  u16* aol = (u16*)alloc((size_t)TT * 1024 * 2);
  u16* acth = (u16*)alloc((size_t)2 * TT * FFD * 2);
  u16* actl = (u16*)alloc((size_t)2 * TT * FFD * 2);
  int*   topi = (int*)alloc((size_t)2 * TT * 4);
  float* topw = (float*)alloc((size_t)2 * TT * 4);
  int* cnt  = (int*)alloc(64);
  int* offe = (int*)alloc(64);
  int* cur  = (int*)alloc(64);
  int*   ftok = (int*)alloc((size_t)2 * TT * 4);
  float* fwt  = (float*)alloc((size_t)2 * TT * 4);
  // trig tables ALIASED into aoh/aol (dead during rope phase; attn rewrites them
  // later each layer, so recompute per layer). Keeps ws footprint == proven level.
  float* ctab = (float*)aoh;
  float* stab = (float*)aol;
  (void)cur;

  k_embed<<<TT, 256, 0, stream>>>(x, emb, h);

  for (int i = 0; i < 2; i++){
    const float* wq_i = wq + (size_t)i * DM * 1024;
    const float* wk_i = wk + (size_t)i * DM * 512;
    const float* wv_i = wvp + (size_t)i * DM * 512;
    const float* wo_i = wo + (size_t)i * 1024 * DM;
    const float* gw_i = gw + (size_t)i * NE * DM;
    const float* w1_i = w1 + (size_t)i * NE * FFD * DM;
    const float* w2_i = w2 + (size_t)i * NE * DM * FFD;
    const float* w3_i = w3 + (size_t)i * NE * FFD * DM;

    k_rmsnorm<0,0><<<TT, 256, 0, stream>>>(h, lnw + i * DM, xnh, xnl, nullptr,
        nullptr, nullptr, nullptr, nullptr);

    // fused QKV with K-split 2: zero outputs (one contiguous 16 MB memset), atomicAdd epilogue
    hipMemsetAsync(qbuf, 0, (size_t)TT * 2048 * 4, stream);   // covers qbuf+kbuf+vbuf (contiguous)
    k_gemm<1,4,1,0,64,2,0><<<dim3(32,16,2), 256, 0, stream>>>(xnh, xnl,
        wq_i, nullptr, wk_i, wv_i, 0, 1024, DM,
        qbuf, 1024, kbuf, vbuf, nullptr, nullptr, nullptr, nullptr, nullptr, nullptr);

    // trig tables into aoh/aol space (dead here; clobbered by attn below)
    k_trig<<<TT * 32 / 256, 256, 0, stream>>>(ctab, stab);
    // fused rope(Q)+rope(K)+split(V)
    k_ropeall<<<4096 + 2048 + 4096, 256, 0, stream>>>(qbuf, kbuf, vbuf,
        ctab, stab, qhb, qlb, khb, klb, vhb, vlb);

    // attention (longest q-blocks first); block (0,0) zeroes cnt for the fused gate
    k_attn<<<dim3(32,16,1), 256, 0, stream>>>(qhb, qlb, khb, klb, vhb, vlb, aoh, aol, cnt);

    // WO with K-split 2 (atomicAdd residual add)
    k_gemm<1,1,1,0,64,2,0><<<dim3(16,16,2), 256, 0, stream>>>(aoh, aol,
        wo_i, nullptr, nullptr, nullptr, 0, DM, 1024,
        h, DM, nullptr, nullptr, nullptr, nullptr, nullptr, nullptr, nullptr, nullptr);

    // ffln rmsnorm + fused MoE gate (exact f32 xn -> logits -> top2 -> cnt)
    k_rmsnorm<0,1><<<TT, 256, 0, stream>>>(h, fflnw + i * DM, xnh, xnl, nullptr,
        gw_i, topi, topw, cnt);

    k_build<<<8, 256, 0, stream>>>(cnt, topi, topw, offe, ftok, fwt);

    if (i == 0){
      k_gemm<0,2,1,1,64,1,0><<<dim3(FFD/64,16,8), 256, 0, stream>>>(xnh, xnl,
          w1_i, w3_i, nullptr, nullptr, (size_t)FFD * DM, FFD, DM,
          nullptr, FFD, nullptr, nullptr, acth, actl, cnt, offe, ftok, fwt);
      k_gemm<0,3,1,0,128,4,0><<<dim3(DM/128,16,32), 256, 0, stream>>>(acth, actl,
          w2_i, nullptr, nullptr, nullptr, (size_t)DM * FFD, DM, FFD,
          h, DM, nullptr, nullptr, nullptr, nullptr, cnt, offe, ftok, fwt);
    } else {
      // SPLIT=0 variants use DEEP=1: two K-halves per barrier pair
      k_gemm<0,2,0,1,64,1,1><<<dim3(FFD/64,16,8), 256, 0, stream>>>(xnh, xnl,
          w1_i, w3_i, nullptr, nullptr, (size_t)FFD * DM, FFD, DM,
          nullptr, FFD, nullptr, nullptr, acth, actl, cnt, offe, ftok, fwt);
      k_gemm<0,3,0,0,128,4,1><<<dim3(DM/128,16,32), 256, 0, stream>>>(acth, actl,
          w2_i, nullptr, nullptr, nullptr, (size_t)DM * FFD, DM, FFD,
          h, DM, nullptr, nullptr, nullptr, nullptr, cnt, offe, ftok, fwt);
    }
  }

  k_rmsnorm<1,0><<<TT, 256, 0, stream>>>(h, dnw, nullptr, nullptr, out,
      nullptr, nullptr, nullptr, nullptr);
}

// Round 17
// 1409.413 us; speedup vs baseline: 1.2001x; 1.0039x over previous
//
#include <hip/hip_runtime.h>

using u16 = unsigned short;
using u32 = unsigned int;

#define TT 2048
#define DM 1024
#define NH 16
#define NKV 8
#define DHD 64
#define FFD 3584
#define NE 8

typedef __bf16 bf16x8 __attribute__((ext_vector_type(8)));
typedef float f32x4 __attribute__((ext_vector_type(4)));

// native casts -> v_cvt_pk_bf16_f32 (RNE, same results as bit trick)
__device__ __forceinline__ u16 f2bf(float x){
  return __builtin_bit_cast(u16, (__bf16)x);
}
__device__ __forceinline__ float bf2f(u16 h){
  return (float)__builtin_bit_cast(__bf16, h);
}
__device__ __forceinline__ f32x4 mfma16(bf16x8 a, bf16x8 b, f32x4 c){
  return __builtin_amdgcn_mfma_f32_16x16x32_bf16(a, b, c, 0, 0, 0);
}
__device__ __forceinline__ uint4 packhi8v(float4 a, float4 b){
  u16 h0=f2bf(a.x),h1=f2bf(a.y),h2=f2bf(a.z),h3=f2bf(a.w);
  u16 h4=f2bf(b.x),h5=f2bf(b.y),h6=f2bf(b.z),h7=f2bf(b.w);
  return make_uint4((u32)h0|((u32)h1<<16),(u32)h2|((u32)h3<<16),
                    (u32)h4|((u32)h5<<16),(u32)h6|((u32)h7<<16));
}
__device__ __forceinline__ uint4 packlo8v(float4 a, float4 b){
  u16 l0=f2bf(a.x-bf2f(f2bf(a.x))),l1=f2bf(a.y-bf2f(f2bf(a.y)));
  u16 l2=f2bf(a.z-bf2f(f2bf(a.z))),l3=f2bf(a.w-bf2f(f2bf(a.w)));
  u16 l4=f2bf(b.x-bf2f(f2bf(b.x))),l5=f2bf(b.y-bf2f(f2bf(b.y)));
  u16 l6=f2bf(b.z-bf2f(f2bf(b.z))),l7=f2bf(b.w-bf2f(f2bf(b.w)));
  return make_uint4((u32)l0|((u32)l1<<16),(u32)l2|((u32)l3<<16),
                    (u32)l4|((u32)l5<<16),(u32)l6|((u32)l7<<16));
}

// chunk-XOR swizzle: 16B chunk c (0..3) of row r stored at u16-offset SWC(r,c).
#define SWZR(r) ((((r)>>1) ^ ((r)>>3)) & 3)
#define SWC(r,c) ((((c) ^ SWZR(r))) * 8)

// async global->LDS, 16B per lane, LDS dest = wave-uniform base + lane*16
__device__ __forceinline__ void glds16(const u16* g, u16* l){
  __builtin_amdgcn_global_load_lds(
      (const __attribute__((address_space(1))) void*)g,
      (__attribute__((address_space(3))) void*)l,
      16, 0, 0);
}

// ---------------- rmsnorm (split-bf16 out or f32 out; GATE fuses MoE top-2 gate;
//                  EMB reads emb[x[t]] and also materializes h) ----------------
template<int OUTF32, int GATE, int EMB>
__global__ __launch_bounds__(256) void k_rmsnorm(const float* __restrict__ in,
    const float* __restrict__ w, u16* __restrict__ oh, u16* __restrict__ ol,
    float* __restrict__ of,
    const float* __restrict__ gw, int* __restrict__ topi,
    float* __restrict__ topw, int* __restrict__ cnt,
    const int* __restrict__ xi, const float* __restrict__ embp,
    float* __restrict__ hout){
  int t = blockIdx.x;
  int d4 = threadIdx.x * 4;
  float4 xv;
  if constexpr (EMB){
    xv = *reinterpret_cast<const float4*>(embp + (size_t)xi[t] * DM + d4);
    *reinterpret_cast<float4*>(hout + (size_t)t * DM + d4) = xv;   // h = emb[x]
  } else {
    xv = *reinterpret_cast<const float4*>(in + (size_t)t * DM + d4);
  }
  float ss = xv.x*xv.x + xv.y*xv.y + xv.z*xv.z + xv.w*xv.w;
#pragma unroll
  for (int m = 1; m < 64; m <<= 1) ss += __shfl_xor(ss, m);
  __shared__ float sred[4];
  if ((threadIdx.x & 63) == 0) sred[threadIdx.x >> 6] = ss;
  __syncthreads();
  float tot = sred[0] + sred[1] + sred[2] + sred[3];
  float r = 1.0f / sqrtf(tot * (1.0f / DM) + 1e-5f);
  float vv[4] = {xv.x, xv.y, xv.z, xv.w};
  float xnv[4];
#pragma unroll
  for (int jj = 0; jj < 4; jj++){
    float xn = (vv[jj] * r) * w[d4 + jj];
    xnv[jj] = xn;
    size_t a = (size_t)t * DM + d4 + jj;
    if constexpr (OUTF32){
      of[a] = xn;
    } else {
      u16 hi = f2bf(xn);
      oh[a] = hi;
      ol[a] = f2bf(xn - bf2f(hi));
    }
  }
  if constexpr (GATE){
    float part[8];
#pragma unroll
    for (int e = 0; e < 8; e++){
      float s = 0.f;
#pragma unroll
      for (int jj = 0; jj < 4; jj++) s += xnv[jj] * gw[(size_t)e * DM + d4 + jj];
#pragma unroll
      for (int m = 1; m < 64; m <<= 1) s += __shfl_xor(s, m);
      part[e] = s;
    }
    __shared__ float gred[4][8];
    if ((threadIdx.x & 63) == 0){
#pragma unroll
      for (int e = 0; e < 8; e++) gred[threadIdx.x >> 6][e] = part[e];
    }
    __syncthreads();
    if (threadIdx.x == 0){
      float lgt[8];
#pragma unroll
      for (int e = 0; e < 8; e++)
        lgt[e] = gred[0][e] + gred[1][e] + gred[2][e] + gred[3][e];
      float mx = lgt[0];
#pragma unroll
      for (int e = 1; e < 8; e++) mx = fmaxf(mx, lgt[e]);
      float pe[8]; float sum = 0.f;
#pragma unroll
      for (int e = 0; e < 8; e++){ pe[e] = expf(lgt[e] - mx); sum += pe[e]; }
      float g[8];
#pragma unroll
      for (int e = 0; e < 8; e++) g[e] = pe[e] / sum;
      int t0 = 0; float b0 = g[0];
#pragma unroll
      for (int e = 1; e < 8; e++) if (g[e] > b0){ b0 = g[e]; t0 = e; }
      int t1 = -1; float b1 = -1.f;
#pragma unroll
      for (int e = 0; e < 8; e++) if (e != t0 && g[e] > b1){ b1 = g[e]; t1 = e; }
      float ssum = b0 + b1;
      topi[2*t] = t0; topi[2*t+1] = t1;
      topw[2*t] = b0 / ssum; topw[2*t+1] = b1 / ssum;
      atomicAdd(&cnt[t0], 1);
      atomicAdd(&cnt[t1], 1);
    }
  }
}

// ---------------- fused rope(Q) + rope(K) + split(V), trig computed in-block ----------------
// Each rope block spans exactly ONE position s (Q: s=b>>1, K: s=b-4096), so 32
// lanes compute the 32 (bit-identical to the old k_trig) cos/sin values in LDS.
template<int NHD>
__device__ __forceinline__ void rope_body(int idx, const float* __restrict__ in,
    const float* __restrict__ cs, const float* __restrict__ sn,
    u16* __restrict__ oh, u16* __restrict__ ol){
  int j = idx & 31;
  int hd = (idx >> 5) & (NHD - 1);
  int s = idx / (32 * NHD);
  size_t base = ((size_t)s * NHD + hd) * 64 + 2 * j;
  float x1 = in[base], x2 = in[base + 1];
  float c  = cs[j];
  float snv = sn[j];
  float o1 = x1 * c - x2 * snv;
  float o2 = x1 * snv + x2 * c;
  u16 h1 = f2bf(o1), h2 = f2bf(o2);
  oh[base]     = h1; ol[base]     = f2bf(o1 - bf2f(h1));
  oh[base + 1] = h2; ol[base + 1] = f2bf(o2 - bf2f(h2));
}

__global__ __launch_bounds__(256) void k_ropeall(
    const float* __restrict__ qbuf, const float* __restrict__ kbuf,
    const float* __restrict__ vbuf,
    u16* __restrict__ qhb, u16* __restrict__ qlb,
    u16* __restrict__ khb, u16* __restrict__ klb,
    u16* __restrict__ vhb, u16* __restrict__ vlb){
  int b = blockIdx.x;
  __shared__ float cs[32], sn[32];
  int s = -1;
  if (b < 4096)      s = b >> 1;        // Q block: one s (NHD=16, 256 thr = half row set)
  else if (b < 6144) s = b - 4096;      // K block: one s (NHD=8)
  if (s >= 0){
    if (threadIdx.x < 32){
      int j = threadIdx.x;
      float xe = (float)j * 0.03125f;               // exact: arange*2/64
      float yf = (float)pow(1.0e6, (double)xe);     // matches CR powf
      float fr = 1.0f / yf;
      float ang = (float)s * fr;                    // f32 mul like ref
      double ad = (double)ang;
      cs[j] = (float)cos(ad);
      sn[j] = (float)sin(ad);
    }
    __syncthreads();
  }
  if (b < 4096){                       // rope Q: TT*32*16 = 1M elems
    rope_body<16>(b * 256 + threadIdx.x, qbuf, cs, sn, qhb, qlb);
  } else if (b < 6144){                // rope K: TT*32*8 = 0.5M elems
    rope_body<8>((b - 4096) * 256 + threadIdx.x, kbuf, cs, sn, khb, klb);
  } else {                             // split V: TT*512 = 1M elems
    int i = (b - 6144) * 256 + threadIdx.x;
    float x = vbuf[i];
    u16 hi = f2bf(x);
    vhb[i] = hi;
    vlb[i] = f2bf(x - bf2f(hi));
  }
}

// ---------------- fused scan + scatter: 8 blocks, block e builds expert e's list ----------------
__global__ __launch_bounds__(256) void k_build(const int* __restrict__ cnt,
    const int* __restrict__ topi, const float* __restrict__ topw,
    int* __restrict__ offp, int* __restrict__ ftok, float* __restrict__ fwt){
  int e = blockIdx.x;
  int off = 0;
  for (int i = 0; i < e; i++) off += cnt[i];
  __shared__ int pos;
  if (threadIdx.x == 0){ offp[e] = off; pos = 0; }
  __syncthreads();
  for (int t0 = 0; t0 < TT; t0 += 256){
    int t = t0 + threadIdx.x;
    int i0 = topi[2*t], i1 = topi[2*t+1];
    if (i0 == e){ int p = atomicAdd(&pos, 1); ftok[off+p] = t; fwt[off+p] = topw[2*t]; }
    if (i1 == e){ int p = atomicAdd(&pos, 1); ftok[off+p] = t; fwt[off+p] = topw[2*t+1]; }
  }
}

// ---------------- GEMM ----------------
// R11 raw-barrier schedule. DEEP=1 (SPLIT=0 only): two BK=32 sub-tiles per
// barrier pair (A LDS depth-4 rotation, B LDS double-tile, 2 B register sets)
// -> half the barriers, double the MFMA per barrier. SPLIT kernels: DEEP=0.
#define GLDSA(BUF, KK) do { \
    glds16(Ah + gaA0 + (KK), (u16*)&Ash[BUF][awr0][0]); \
    glds16(Ah + gaA1 + (KK), (u16*)&Ash[BUF][awr1][0]); \
    if constexpr (SPLIT){ \
      glds16(Al + gaA0 + (KK), (u16*)&Asl[BUF][awr0][0]); \
      glds16(Al + gaA1 + (KK), (u16*)&Asl[BUF][awr1][0]); \
    } \
  } while(0)

#define GPRELOADB(S, KK) do { \
    if constexpr (BLAYOUT == 0){ \
      const float* bp_ = Bw + (size_t)(n0 + br0) * K + (KK) + cb8; \
      S##B0 = *reinterpret_cast<const float4*>(bp_); \
      S##B1 = *reinterpret_cast<const float4*>(bp_ + 4); \
      if constexpr (TN == 128){ \
        const float* bp2_ = Bw + (size_t)(n0 + br1) * K + (KK) + cb8; \
        S##B2 = *reinterpret_cast<const float4*>(bp2_); \
        S##B3 = *reinterpret_cast<const float4*>(bp2_ + 4); \
      } \
      if constexpr (DUAL){ \
        const float* bq_ = B3w + (size_t)(n0 + br0) * K + (KK) + cb8; \
        S##B2 = *reinterpret_cast<const float4*>(bq_); \
        S##B3 = *reinterpret_cast<const float4*>(bq_ + 4); \
      } \
    } else { \
      S##B0 = *reinterpret_cast<const float4*>(Bw + (size_t)((KK) + kk1) * Nq + n0 + nn1); \
      S##B1 = *reinterpret_cast<const float4*>(Bw + (size_t)((KK) + 16 + kk1) * Nq + n0 + nn1); \
    } \
  } while(0)

#define GSTOREB(S, BB) do { \
    if constexpr (BLAYOUT == 0){ \
      *reinterpret_cast<uint4*>(&Bh1[BB][br0][swB0]) = packhi8v(S##B0, S##B1); \
      if constexpr (SPLIT) *reinterpret_cast<uint4*>(&Bl1[br0][swB0]) = packlo8v(S##B0, S##B1); \
      if constexpr (TN == 128){ \
        *reinterpret_cast<uint4*>(&Bh1[BB][br1][swB1]) = packhi8v(S##B2, S##B3); \
        if constexpr (SPLIT) *reinterpret_cast<uint4*>(&Bl1[br1][swB1]) = packlo8v(S##B2, S##B3); \
      } \
      if constexpr (DUAL){ \
        *reinterpret_cast<uint4*>(&Bh3[BB][br0][swB0]) = packhi8v(S##B2, S##B3); \
        if constexpr (SPLIT) *reinterpret_cast<uint4*>(&Bl3[br0][swB0]) = packlo8v(S##B2, S##B3); \
      } \
    } else { \
      const float* q0 = reinterpret_cast<const float*>(&S##B0); \
      const float* q1 = reinterpret_cast<const float*>(&S##B1); \
      const int ch0 = kk1 >> 3, off0 = kk1 & 7; \
      _Pragma("unroll") \
      for (int j = 0; j < 4; j++){ \
        int row = nn1 + j; \
        int c0 = SWC(row, ch0) + off0; \
        int c1 = SWC(row, ch0 + 2) + off0; \
        u16 h0 = f2bf(q0[j]); \
        Bh1[BB][row][c0] = h0; \
        if constexpr (SPLIT) Bl1[row][c0] = f2bf(q0[j] - bf2f(h0)); \
        u16 h1 = f2bf(q1[j]); \
        Bh1[BB][row][c1] = h1; \
        if constexpr (SPLIT) Bl1[row][c1] = f2bf(q1[j] - bf2f(h1)); \
      } \
    } \
  } while(0)

#define MFMA_PHASE(CURB, BB) do { \
    bf16x8 af[4], afl[4]; \
    _Pragma("unroll") \
    for (int m = 0; m < 4; m++){ \
      int Ra = wr*64 + m*16 + lr; \
      int sa = SWC(Ra, lg); \
      af[m] = *reinterpret_cast<const bf16x8*>(&Ash[CURB][Ra][sa]); \
      if constexpr (SPLIT) \
        afl[m] = *reinterpret_cast<const bf16x8*>(&Asl[CURB][Ra][sa]); \
    } \
    _Pragma("unroll") \
    for (int n = 0; n < NF; n++){ \
      int Rb = wc*(TN/2) + n*16 + lr; \
      int sb = SWC(Rb, lg); \
      bf16x8 b1 = *reinterpret_cast<const bf16x8*>(&Bh1[BB][Rb][sb]); \
      _Pragma("unroll") \
      for (int m = 0; m < 4; m++) acc[m][n] = mfma16(af[m], b1, acc[m][n]); \
      if constexpr (SPLIT){ \
        bf16x8 bl = *reinterpret_cast<const bf16x8*>(&Bl1[Rb][sb]); \
        _Pragma("unroll") \
        for (int m = 0; m < 4; m++){ \
          acc[m][n] = mfma16(af[m], bl, acc[m][n]); \
          acc[m][n] = mfma16(afl[m], b1, acc[m][n]); \
        } \
      } \
      if constexpr (DUAL){ \
        bf16x8 b3 = *reinterpret_cast<const bf16x8*>(&Bh3[BB][Rb][sb]); \
        _Pragma("unroll") \
        for (int m = 0; m < 4; m++) acc3[m][n] = mfma16(af[m], b3, acc3[m][n]); \
        if constexpr (SPLIT){ \
          bf16x8 b3l = *reinterpret_cast<const bf16x8*>(&Bl3[Rb][sb]); \
          _Pragma("unroll") \
          for (int m = 0; m < 4; m++){ \
            acc3[m][n] = mfma16(af[m], b3l, acc3[m][n]); \
            acc3[m][n] = mfma16(afl[m], b3, acc3[m][n]); \
          } \
        } \
      } \
    } \
  } while(0)

template<int BLAYOUT, int EPI, int SPLIT, int DUAL, int TN, int KS, int DEEP>
__global__ __launch_bounds__(256) void k_gemm(
    const u16* __restrict__ Ah, const u16* __restrict__ Al,
    const float* __restrict__ Bw, const float* __restrict__ B3w,
    const float* __restrict__ Bw2, const float* __restrict__ Bw3,
    size_t strideB, int N, int K,
    float* __restrict__ Cf, int ldc,
    float* __restrict__ Cf2, float* __restrict__ Cf3,
    u16* __restrict__ Ch, u16* __restrict__ Cl,
    const int* __restrict__ cntp, const int* __restrict__ offp,
    const int* __restrict__ ftok, const float* __restrict__ fwt)
{
  static_assert(!(DUAL && TN != 64), "DUAL uses TN=64");
  static_assert(!(BLAYOUT == 1 && TN != 64), "BLAYOUT=1 uses TN=64");
  static_assert(!(DEEP && SPLIT), "DEEP only for SPLIT=0 (A-LDS budget)");
  static_assert(!(DEEP && BLAYOUT == 1), "DEEP only for BLAYOUT=0");
  int cnt = TT, off = 0, ks = 0;
  if constexpr (EPI == 2 || EPI == 3){
    int e = blockIdx.z / KS;
    ks = blockIdx.z % KS;
    cnt = cntp[e]; off = offp[e];
    if ((int)blockIdx.y * 128 >= cnt) return;
    Bw += (size_t)e * strideB;
    if constexpr (DUAL) B3w += (size_t)e * strideB;
  } else if constexpr (KS > 1){
    ks = blockIdx.z;
  }
  __shared__ u16 Ash[DEEP ? 4 : 2][128][32];      // A hi (dbuf / depth-4 rotation)
  __shared__ u16 Asl[SPLIT ? 2 : 1][SPLIT ? 128 : 1][32];
  __shared__ u16 Bh1[DEEP ? 2 : 1][TN][32];
  __shared__ u16 Bl1[SPLIT ? TN : 1][32];
  __shared__ u16 Bh3[DEEP ? 2 : 1][DUAL ? TN : 1][32];
  __shared__ u16 Bl3[(DUAL && SPLIT) ? TN : 1][32];

  const int tid = threadIdx.x;
  const int m0 = blockIdx.y * 128;

  // output/N selection (fused QKV uses blockIdx.x ranges)
  int n0, Nq = N, ldq = ldc;
  float* Cq = Cf;
  if constexpr (EPI == 4){
    int bx = blockIdx.x;
    if (bx < 16){       n0 = bx * 64;        Nq = 1024; ldq = 1024; Cq = Cf;  }
    else if (bx < 24){  n0 = (bx - 16) * 64; Nq = 512;  ldq = 512;  Cq = Cf2; Bw = Bw2; }
    else {              n0 = (bx - 24) * 64; Nq = 512;  ldq = 512;  Cq = Cf3; Bw = Bw3; }
  } else {
    n0 = blockIdx.x * TN;
  }

  const int wid = tid >> 6, lane = tid & 63;
  const int wr = wid >> 1, wc = wid & 1;
  const int lr = lane & 15, lg = lane >> 4;
  constexpr int NF = TN / 32;

  // A gload_lds setup: wave wid stages rows [wid*32, wid*32+32), 2 instrs of 16 rows.
  const int awr0 = wid * 32;
  const int awr1 = wid * 32 + 16;
  const int rA0 = awr0 + (lane >> 2);
  const int rA1 = awr1 + (lane >> 2);
  const int cA0 = (lane & 3) ^ SWZR(rA0);
  const int cA1 = (lane & 3) ^ SWZR(rA1);
  int grA0, grA1;
  {
    int g0 = m0 + rA0, g1 = m0 + rA1;
    if constexpr (EPI == 2){
      grA0 = ftok[off + (g0 < cnt ? g0 : cnt - 1)];
      grA1 = ftok[off + (g1 < cnt ? g1 : cnt - 1)];
    } else if constexpr (EPI == 3){
      grA0 = off + (g0 < cnt ? g0 : cnt - 1);
      grA1 = off + (g1 < cnt ? g1 : cnt - 1);
    } else {
      grA0 = g0; grA1 = g1;
    }
  }
  const size_t gaA0 = (size_t)grA0 * K + cA0 * 8;
  const size_t gaA1 = (size_t)grA1 * K + cA1 * 8;

  // B staging (BLAYOUT=0)
  const int br0 = tid >> 2;
  const int br1 = br0 + 64;
  const int cb8 = (tid & 3) * 8;
  const int swB0 = SWC(br0, tid & 3), swB1 = SWC(br1, tid & 3);
  // BLAYOUT=1 indices
  const int kk1 = tid >> 4;
  const int nn1 = (tid & 15) * 4;

  f32x4 acc[4][NF];
  f32x4 acc3[DUAL ? 4 : 1][NF];
#pragma unroll
  for (int m = 0; m < 4; m++)
#pragma unroll
    for (int n = 0; n < NF; n++){
      acc[m][n] = f32x4{0.f,0.f,0.f,0.f};
      if constexpr (DUAL) acc3[m][n] = f32x4{0.f,0.f,0.f,0.f};
    }

  // named B staging sets (no arrays, no lambdas -> no scratch); set b only for DEEP
  float4 aB0{}, aB1{}, aB2{}, aB3{};
  float4 bB0{}, bB1{}, bB2{}, bB3{};

  const int kbeg = ks * (K / KS);
  const int kend = kbeg + (K / KS);

  if constexpr (DEEP){
    // two BK=32 sub-tiles per barrier pair; A rotates over 4 buffers
    GLDSA(0, kbeg);
    GLDSA(1, kbeg + 32);
    GPRELOADB(a, kbeg);
    GPRELOADB(b, kbeg + 32);
    int cur = 0;                      // A base buffer: 0 or 2
    for (int k0 = kbeg; k0 < kend; k0 += 64){
      GSTOREB(a, 0);
      GSTOREB(b, 1);
      asm volatile("s_waitcnt vmcnt(0) lgkmcnt(0)" ::: "memory");
      __builtin_amdgcn_s_barrier();
      if (k0 + 64 < kend){
        GLDSA(cur ^ 2, k0 + 64);      // A(k+2),A(k+3) stream during MFMA
        GLDSA((cur ^ 2) + 1, k0 + 96);
        GPRELOADB(a, k0 + 64);
        GPRELOADB(b, k0 + 96);
      }
      MFMA_PHASE(cur, 0);
      MFMA_PHASE(cur + 1, 1);
      __builtin_amdgcn_s_barrier();   // raw: prefetches stay in flight
      cur ^= 2;
    }
  } else {
    GLDSA(0, kbeg);          // A(k0) -> buf0 (async)
    GPRELOADB(a, kbeg);      // B(k0) -> regs
    int cur = 0;
    for (int k0 = kbeg; k0 < kend; k0 += 32){
      GSTOREB(a, 0);
      asm volatile("s_waitcnt vmcnt(0) lgkmcnt(0)" ::: "memory");
      __builtin_amdgcn_s_barrier();
      if (k0 + 32 < kend){
        GLDSA(cur ^ 1, k0 + 32);
        GPRELOADB(a, k0 + 32);
      }
      MFMA_PHASE(cur, 0);
      __builtin_amdgcn_s_barrier();
      cur ^= 1;
    }
  }

  // --- epilogue ---
#pragma unroll
  for (int m = 0; m < 4; m++)
#pragma unroll
    for (int n = 0; n < NF; n++)
#pragma unroll
      for (int r = 0; r < 4; r++){
        int row = m0 + wr*64 + m*16 + lg*4 + r;   // C/D: row=(lane>>4)*4+reg, col=lane&15 [m89]
        int col = n0 + wc*(TN/2) + n*16 + lr;
        float v = acc[m][n][r];
        if constexpr (EPI == 0){
          Cf[(size_t)row * ldc + col] = v;
        } else if constexpr (EPI == 1){
          if constexpr (KS > 1) atomicAdd(&Cf[(size_t)row * ldc + col], v);
          else                  Cf[(size_t)row * ldc + col] += v;
        } else if constexpr (EPI == 2){
          if (row < cnt){
            float a3 = acc3[m][n][r];
            float s = v / (1.0f + expf(-v));   // silu
            float y = s * a3;
            u16 hi = f2bf(y);
            size_t oa = (size_t)(off + row) * ldc + col;
            Ch[oa] = hi;
            Cl[oa] = f2bf(y - bf2f(hi));
          }
        } else if constexpr (EPI == 3){
          if (row < cnt){
            int tok = ftok[off + row];
            float wgt = fwt[off + row];
            atomicAdd(&Cf[(size_t)tok * ldc + col], wgt * v);
          }
        } else {
          if constexpr (KS > 1) atomicAdd(&Cq[(size_t)row * ldq + col], v);
          else                  Cq[(size_t)row * ldq + col] = v;
        }
      }
}

// ---------------- flash attention (split bf16x3; longest q-blocks first) ----------------
__global__ __launch_bounds__(256) void k_attn(
    const u16* __restrict__ qh, const u16* __restrict__ ql,
    const u16* __restrict__ kh, const u16* __restrict__ kl,
    const u16* __restrict__ vh, const u16* __restrict__ vl,
    u16* __restrict__ aoh, u16* __restrict__ aol, int* __restrict__ cntz)
{
  if (blockIdx.x == 0 && blockIdx.y == 0 && threadIdx.x < 8) cntz[threadIdx.x] = 0;
  const int h  = blockIdx.y;
  const int q0 = (int)(gridDim.x - 1 - blockIdx.x) * 64;   // longest first
  const int hk = h >> 1;                 // GQA: repeat factor 2
  const int tid = threadIdx.x;
  const int wv = tid >> 6, lane = tid & 63;
  const int lr = lane & 15, lg = lane >> 4;
  const int qw0 = q0 + wv * 16;

  __shared__ u16 Khs[32][72], Kls[32][72];      // 144B rows, 16B aligned
  __shared__ u16 Vhs[64][40], Vls[64][40];      // transposed: [d][k], 80B rows
  __shared__ u16 Phs[4][16][40], Pls[4][16][40];

  bf16x8 qfh[2], qfl[2];
#pragma unroll
  for (int dc = 0; dc < 2; dc++){
    size_t qa = ((size_t)(qw0 + lr) * NH + h) * 64 + dc*32 + lg*8;
    qfh[dc] = *reinterpret_cast<const bf16x8*>(qh + qa);
    qfl[dc] = *reinterpret_cast<const bf16x8*>(ql + qa);
  }
  f32x4 oacc[4];
  float mrun[4], lrun[4];
#pragma unroll
  for (int r = 0; r < 4; r++){ mrun[r] = -1e30f; lrun[r] = 0.f; }
#pragma unroll
  for (int g = 0; g < 4; g++) oacc[g] = f32x4{0.f,0.f,0.f,0.f};

  const int nt = q0 / 32 + 2;
  for (int kt = 0; kt < nt; kt++){
    int kg = kt * 32;
    {
      int kk = tid >> 3, c8 = (tid & 7) * 8;
      size_t ka = ((size_t)(kg + kk) * NKV + hk) * 64 + c8;
      *reinterpret_cast<uint4*>(&Khs[kk][c8]) = *reinterpret_cast<const uint4*>(kh + ka);
      *reinterpret_cast<uint4*>(&Kls[kk][c8]) = *reinterpret_cast<const uint4*>(kl + ka);
      uint4 v1 = *reinterpret_cast<const uint4*>(vh + ka);
      uint4 v2 = *reinterpret_cast<const uint4*>(vl + ka);
      const u16* p1 = reinterpret_cast<const u16*>(&v1);
      const u16* p2 = reinterpret_cast<const u16*>(&v2);
#pragma unroll
      for (int j = 0; j < 8; j++){ Vhs[c8 + j][kk] = p1[j]; Vls[c8 + j][kk] = p2[j]; }
    }
    __syncthreads();

    f32x4 sc[2];
    sc[0] = f32x4{0.f,0.f,0.f,0.f};
    sc[1] = f32x4{0.f,0.f,0.f,0.f};
#pragma unroll
    for (int c = 0; c < 2; c++){
#pragma unroll
      for (int dc = 0; dc < 2; dc++){
        bf16x8 bh = *reinterpret_cast<const bf16x8*>(&Khs[c*16 + lr][dc*32 + lg*8]);
        bf16x8 bl = *reinterpret_cast<const bf16x8*>(&Kls[c*16 + lr][dc*32 + lg*8]);
        sc[c] = mfma16(qfh[dc], bh, sc[c]);
        sc[c] = mfma16(qfh[dc], bl, sc[c]);
        sc[c] = mfma16(qfl[dc], bh, sc[c]);
      }
    }
    float pnew[2][4], corr[4];
#pragma unroll
    for (int r = 0; r < 4; r++){
      int row = qw0 + lg*4 + r;
      float s0 = (kg + lr      <= row) ? sc[0][r] * 0.125f : -1e30f;
      float s1 = (kg + 16 + lr <= row) ? sc[1][r] * 0.125f : -1e30f;
      float tm = fmaxf(s0, s1);
#pragma unroll
      for (int m = 1; m < 16; m <<= 1) tm = fmaxf(tm, __shfl_xor(tm, m));
      float mnew = fmaxf(mrun[r], tm);
      corr[r] = expf(mrun[r] - mnew);
      float p0 = expf(s0 - mnew);
      float p1 = expf(s1 - mnew);
      pnew[0][r] = p0; pnew[1][r] = p1;
      float sm = p0 + p1;
#pragma unroll
      for (int m = 1; m < 16; m <<= 1) sm += __shfl_xor(sm, m);
      lrun[r] = lrun[r] * corr[r] + sm;
      mrun[r] = mnew;
    }
#pragma unroll
    for (int g = 0; g < 4; g++){
      f32x4 t = oacc[g];
#pragma unroll
      for (int r = 0; r < 4; r++) t[r] *= corr[r];
      oacc[g] = t;
    }
#pragma unroll
    for (int c = 0; c < 2; c++)
#pragma unroll
      for (int r = 0; r < 4; r++){
        float p = pnew[c][r];
        u16 hi = f2bf(p);
        Phs[wv][lg*4 + r][c*16 + lr] = hi;
        Pls[wv][lg*4 + r][c*16 + lr] = f2bf(p - bf2f(hi));
      }
    asm volatile("s_waitcnt lgkmcnt(0)" ::: "memory");
    __builtin_amdgcn_sched_barrier(0);
    bf16x8 pah = *reinterpret_cast<const bf16x8*>(&Phs[wv][lr][lg*8]);
    bf16x8 pal = *reinterpret_cast<const bf16x8*>(&Pls[wv][lr][lg*8]);
#pragma unroll
    for (int g = 0; g < 4; g++){
      bf16x8 vb1 = *reinterpret_cast<const bf16x8*>(&Vhs[g*16 + lr][lg*8]);
      bf16x8 vb2 = *reinterpret_cast<const bf16x8*>(&Vls[g*16 + lr][lg*8]);
      oacc[g] = mfma16(pah, vb1, oacc[g]);
      oacc[g] = mfma16(pah, vb2, oacc[g]);
      oacc[g] = mfma16(pal, vb1, oacc[g]);
    }
    __syncthreads();
  }
#pragma unroll
  for (int g = 0; g < 4; g++)
#pragma unroll
    for (int r = 0; r < 4; r++){
      int row = qw0 + lg*4 + r;
      float v = oacc[g][r] / lrun[r];
      u16 hi = f2bf(v);
      size_t oa = ((size_t)row * NH + h) * 64 + g*16 + lr;
      aoh[oa] = hi;
      aol[oa] = f2bf(v - bf2f(hi));
    }
}

// ---------------- launch ----------------
extern "C" void kernel_launch(void* const* d_in, const int* in_sizes, int n_in,
                              void* d_out, int out_size, void* d_ws, size_t ws_size,
                              hipStream_t stream){
  const int*   x     = (const int*)d_in[0];
  const float* emb   = (const float*)d_in[1];
  const float* lnw   = (const float*)d_in[2];
  const float* fflnw = (const float*)d_in[3];
  const float* wq    = (const float*)d_in[4];
  const float* wk    = (const float*)d_in[5];
  const float* wvp   = (const float*)d_in[6];
  const float* wo    = (const float*)d_in[7];
  const float* gw    = (const float*)d_in[8];
  const float* w1    = (const float*)d_in[9];
  const float* w2    = (const float*)d_in[10];
  const float* w3    = (const float*)d_in[11];
  const float* dnw   = (const float*)d_in[12];
  float* out = (float*)d_out;

  char* p = (char*)d_ws;
  auto alloc = [&](size_t bytes)->char*{
    char* r = p; p += (bytes + 255) & ~(size_t)255; return r;
  };
  float* h    = (float*)alloc((size_t)TT * DM * 4);
  float* qbuf = (float*)alloc((size_t)TT * 1024 * 4);
  float* kbuf = (float*)alloc((size_t)TT * 512 * 4);
  float* vbuf = (float*)alloc((size_t)TT * 512 * 4);
  u16* xnh = (u16*)alloc((size_t)TT * DM * 2);
  u16* xnl = (u16*)alloc((size_t)TT * DM * 2);
  u16* qhb = (u16*)alloc((size_t)TT * 1024 * 2);
  u16* qlb = (u16*)alloc((size_t)TT * 1024 * 2);
  u16* khb = (u16*)alloc((size_t)TT * 512 * 2);
  u16* klb = (u16*)alloc((size_t)TT * 512 * 2);
  u16* vhb = (u16*)alloc((size_t)TT * 512 * 2);
  u16* vlb = (u16*)alloc((size_t)TT * 512 * 2);
  u16* aoh = (u16*)alloc((size_t)TT * 1024 * 2);
  u16* aol = (u16*)alloc((size_t)TT * 1024 * 2);
  u16* acth = (u16*)alloc((size_t)2 * TT * FFD * 2);
  u16* actl = (u16*)alloc((size_t)2 * TT * FFD * 2);
  int*   topi = (int*)alloc((size_t)2 * TT * 4);
  float* topw = (float*)alloc((size_t)2 * TT * 4);
  int* cnt  = (int*)alloc(64);
  int* offe = (int*)alloc(64);
  int* cur  = (int*)alloc(64);
  int*   ftok = (int*)alloc((size_t)2 * TT * 4);
  float* fwt  = (float*)alloc((size_t)2 * TT * 4);
  (void)cur;

  for (int i = 0; i < 2; i++){
    const float* wq_i = wq + (size_t)i * DM * 1024;
    const float* wk_i = wk + (size_t)i * DM * 512;
    const float* wv_i = wvp + (size_t)i * DM * 512;
    const float* wo_i = wo + (size_t)i * 1024 * DM;
    const float* gw_i = gw + (size_t)i * NE * DM;
    const float* w1_i = w1 + (size_t)i * NE * FFD * DM;
    const float* w2_i = w2 + (size_t)i * NE * DM * FFD;
    const float* w3_i = w3 + (size_t)i * NE * FFD * DM;

    if (i == 0){
      // fused embed + rmsnorm: reads emb[x[t]], writes h AND split xn
      k_rmsnorm<0,0,1><<<TT, 256, 0, stream>>>(nullptr, lnw, xnh, xnl, nullptr,
          nullptr, nullptr, nullptr, nullptr, x, emb, h);
    } else {
      k_rmsnorm<0,0,0><<<TT, 256, 0, stream>>>(h, lnw + i * DM, xnh, xnl, nullptr,
          nullptr, nullptr, nullptr, nullptr, nullptr, nullptr, nullptr);
    }

    // fused QKV with K-split 2: zero outputs (one contiguous 16 MB memset), atomicAdd epilogue
    hipMemsetAsync(qbuf, 0, (size_t)TT * 2048 * 4, stream);   // covers qbuf+kbuf+vbuf (contiguous)
    k_gemm<1,4,1,0,64,2,0><<<dim3(32,16,2), 256, 0, stream>>>(xnh, xnl,
        wq_i, nullptr, wk_i, wv_i, 0, 1024, DM,
        qbuf, 1024, kbuf, vbuf, nullptr, nullptr, nullptr, nullptr, nullptr, nullptr);

    // fused rope(Q)+rope(K)+split(V), per-block in-LDS trig (bit-identical math)
    k_ropeall<<<4096 + 2048 + 4096, 256, 0, stream>>>(qbuf, kbuf, vbuf,
        qhb, qlb, khb, klb, vhb, vlb);

    // attention (longest q-blocks first); block (0,0) zeroes cnt for the fused gate
    k_attn<<<dim3(32,16,1), 256, 0, stream>>>(qhb, qlb, khb, klb, vhb, vlb, aoh, aol, cnt);

    // WO with K-split 2 (atomicAdd residual add)
    k_gemm<1,1,1,0,64,2,0><<<dim3(16,16,2), 256, 0, stream>>>(aoh, aol,
        wo_i, nullptr, nullptr, nullptr, 0, DM, 1024,
        h, DM, nullptr, nullptr, nullptr, nullptr, nullptr, nullptr, nullptr, nullptr);

    // ffln rmsnorm + fused MoE gate (exact f32 xn -> logits -> top2 -> cnt)
    k_rmsnorm<0,1,0><<<TT, 256, 0, stream>>>(h, fflnw + i * DM, xnh, xnl, nullptr,
        gw_i, topi, topw, cnt, nullptr, nullptr, nullptr);

    k_build<<<8, 256, 0, stream>>>(cnt, topi, topw, offe, ftok, fwt);

    if (i == 0){
      k_gemm<0,2,1,1,64,1,0><<<dim3(FFD/64,16,8), 256, 0, stream>>>(xnh, xnl,
          w1_i, w3_i, nullptr, nullptr, (size_t)FFD * DM, FFD, DM,
          nullptr, FFD, nullptr, nullptr, acth, actl, cnt, offe, ftok, fwt);
      k_gemm<0,3,1,0,128,4,0><<<dim3(DM/128,16,32), 256, 0, stream>>>(acth, actl,
          w2_i, nullptr, nullptr, nullptr, (size_t)DM * FFD, DM, FFD,
          h, DM, nullptr, nullptr, nullptr, nullptr, cnt, offe, ftok, fwt);
    } else {
      // SPLIT=0 variants use DEEP=1: two K-halves per barrier pair
      k_gemm<0,2,0,1,64,1,1><<<dim3(FFD/64,16,8), 256, 0, stream>>>(xnh, xnl,
          w1_i, w3_i, nullptr, nullptr, (size_t)FFD * DM, FFD, DM,
          nullptr, FFD, nullptr, nullptr, acth, actl, cnt, offe, ftok, fwt);
      k_gemm<0,3,0,0,128,4,1><<<dim3(DM/128,16,32), 256, 0, stream>>>(acth, actl,
          w2_i, nullptr, nullptr, nullptr, (size_t)DM * FFD, DM, FFD,
          h, DM, nullptr, nullptr, nullptr, nullptr, cnt, offe, ftok, fwt);
    }
  }

  k_rmsnorm<1,0,0><<<TT, 256, 0, stream>>>(h, dnw, nullptr, nullptr, out,
      nullptr, nullptr, nullptr, nullptr, nullptr, nullptr, nullptr);
}